// Round 1
// baseline (4579.141 us; speedup 1.0000x reference)
//
#include <hip/hip_runtime.h>
#include <cstdint>
#include <cstddef>

// Problem constants
#define BATCHN 32
#define LSEQ   196     // (224/16)^2
#define DMODEL 512
#define DINNER 1024    // 2*DM
#define PDIM   768     // 3*16*16
#define NSTATE 16
#define RRANK  32
#define NLAYER 6

// ---------------------------------------------------------------------------
// Generic NT GEMM: C[M,N] = A[M,K] @ W[N,K]^T (+bias) (+act)
// A row stride = lda, W row stride = K, C row stride = ldc.
// Requires M%64==0, N%64==0, K%16==0 (true for all shapes here).
// act: 0 = none, 1 = softplus
// ---------------------------------------------------------------------------
__global__ __launch_bounds__(256) void gemm_nt(
    const float* __restrict__ A, int lda,
    const float* __restrict__ W,
    float* __restrict__ C, int ldc,
    const float* __restrict__ bias,
    int M, int N, int K, int act)
{
    __shared__ float As[16][64];
    __shared__ float Ws[16][64];
    const int bm = blockIdx.y * 64;
    const int bn = blockIdx.x * 64;
    const int tid = threadIdx.x;
    const int tx = tid & 15;
    const int ty = tid >> 4;
    const int r   = tid >> 2;         // 0..63
    const int kk4 = (tid & 3) << 2;   // 0,4,8,12

    float acc[4][4];
    #pragma unroll
    for (int i = 0; i < 4; ++i)
        #pragma unroll
        for (int j = 0; j < 4; ++j) acc[i][j] = 0.f;

    for (int k0 = 0; k0 < K; k0 += 16) {
        float4 va = *(const float4*)(A + (size_t)(bm + r) * lda + k0 + kk4);
        float4 vw = *(const float4*)(W + (size_t)(bn + r) * K   + k0 + kk4);
        __syncthreads();   // previous iteration's reads complete
        As[kk4 + 0][r] = va.x; As[kk4 + 1][r] = va.y;
        As[kk4 + 2][r] = va.z; As[kk4 + 3][r] = va.w;
        Ws[kk4 + 0][r] = vw.x; Ws[kk4 + 1][r] = vw.y;
        Ws[kk4 + 2][r] = vw.z; Ws[kk4 + 3][r] = vw.w;
        __syncthreads();
        #pragma unroll
        for (int kk = 0; kk < 16; ++kk) {
            float4 a = *(const float4*)&As[kk][ty << 2];
            float4 b = *(const float4*)&Ws[kk][tx << 2];
            acc[0][0] += a.x * b.x; acc[0][1] += a.x * b.y;
            acc[0][2] += a.x * b.z; acc[0][3] += a.x * b.w;
            acc[1][0] += a.y * b.x; acc[1][1] += a.y * b.y;
            acc[1][2] += a.y * b.z; acc[1][3] += a.y * b.w;
            acc[2][0] += a.z * b.x; acc[2][1] += a.z * b.y;
            acc[2][2] += a.z * b.z; acc[2][3] += a.z * b.w;
            acc[3][0] += a.w * b.x; acc[3][1] += a.w * b.y;
            acc[3][2] += a.w * b.z; acc[3][3] += a.w * b.w;
        }
    }

    #pragma unroll
    for (int i = 0; i < 4; ++i) {
        const int m = bm + (ty << 2) + i;
        #pragma unroll
        for (int j = 0; j < 4; ++j) {
            const int n = bn + (tx << 2) + j;
            float v = acc[i][j];
            if (bias) v += bias[n];
            if (act == 1) {          // softplus, numerically safe
                v = (v > 20.f) ? v : log1pf(expf(v));
            }
            C[(size_t)m * ldc + n] = v;
        }
    }
}

// ---------------------------------------------------------------------------
// Patchify: x (B,3,224,224) -> tp (B, 196, 768), pd = c*256 + p1*16 + p2
// ---------------------------------------------------------------------------
__global__ __launch_bounds__(256) void patchify_kernel(
    const float* __restrict__ x, float* __restrict__ tp)
{
    int idx = blockIdx.x * 256 + threadIdx.x;   // B*L*PD = 4,816,896
    int pd = idx % PDIM;
    int bl = idx / PDIM;
    int l = bl % LSEQ, b = bl / LSEQ;
    int c = pd >> 8, rem = pd & 255, p1 = rem >> 4, p2 = rem & 15;
    int gh = l / 14, gw = l % 14;
    int hh = gh * 16 + p1, ww = gw * 16 + p2;
    tp[idx] = x[(((size_t)b * 3 + c) * 224 + hh) * 224 + ww];
}

// ---------------------------------------------------------------------------
// LayerNorm over last dim W (512 or 768). Optional residual (out = LN(in+res)).
// One block (256 threads) per row; in-place safe.
// ---------------------------------------------------------------------------
__global__ __launch_bounds__(256) void ln_kernel(
    const float* __restrict__ in, const float* __restrict__ res,
    const float* __restrict__ g, const float* __restrict__ bt,
    float* __restrict__ out, int W)
{
    __shared__ float red[4];
    const int row = blockIdx.x;
    const size_t base = (size_t)row * W;
    const int nper = W >> 8;      // 2 or 3
    float vals[3];
    float s = 0.f;
    for (int j = 0; j < nper; ++j) {
        int c = (j << 8) + threadIdx.x;
        float v = in[base + c];
        if (res) v += res[base + c];
        vals[j] = v;
        s += v;
    }
    int lane = threadIdx.x & 63, wid = threadIdx.x >> 6;
    #pragma unroll
    for (int o = 32; o > 0; o >>= 1) s += __shfl_down(s, o);
    if (lane == 0) red[wid] = s;
    __syncthreads();
    float mu = (red[0] + red[1] + red[2] + red[3]) / (float)W;
    __syncthreads();
    float vs = 0.f;
    for (int j = 0; j < nper; ++j) { float d = vals[j] - mu; vs += d * d; }
    #pragma unroll
    for (int o = 32; o > 0; o >>= 1) vs += __shfl_down(vs, o);
    if (lane == 0) red[wid] = vs;
    __syncthreads();
    float var = (red[0] + red[1] + red[2] + red[3]) / (float)W;
    float rstd = rsqrtf(var + 1e-5f);
    for (int j = 0; j < nper; ++j) {
        int c = (j << 8) + threadIdx.x;
        out[base + c] = (vals[j] - mu) * rstd * g[c] + bt[c];
    }
}

// ---------------------------------------------------------------------------
// Causal depthwise conv (K=4) + SiLU.  xs = first half of xz (stride 2048).
// xc[b,l,d] = silu( sum_k cw[d,k]*xs[b, l-3+k, d] + cb[d] )
// ---------------------------------------------------------------------------
__global__ __launch_bounds__(256) void conv_silu_kernel(
    const float* __restrict__ xz, const float* __restrict__ cw,
    const float* __restrict__ cb, float* __restrict__ xc)
{
    int idx = blockIdx.x * 256 + threadIdx.x;  // B*L*DI = 6,422,528
    int d = idx & (DINNER - 1);
    int bl = idx >> 10;
    int l = bl % LSEQ, b = bl / LSEQ;
    float acc = cb[d];
    #pragma unroll
    for (int k = 0; k < 4; ++k) {
        int ls = l + k - 3;
        if (ls >= 0)
            acc += cw[(d << 2) + k] * xz[((size_t)(b * LSEQ + ls) << 11) + d];
    }
    xc[idx] = acc / (1.f + expf(-acc));
}

// ---------------------------------------------------------------------------
// Selective scan. One thread per (b,d); 16 states in registers.
// Fuses: y = (scan + xc*D) * silu(z).  Grid = B*DI/256 = 128 blocks.
// ---------------------------------------------------------------------------
__global__ __launch_bounds__(256) void scan_kernel(
    const float* __restrict__ xc, const float* __restrict__ dt,
    const float* __restrict__ xdbl, const float* __restrict__ A_log,
    const float* __restrict__ Dv, const float* __restrict__ xz,
    float* __restrict__ y)
{
    const int b = blockIdx.x >> 2;
    const int d = ((blockIdx.x & 3) << 8) + threadIdx.x;
    float A[NSTATE], h[NSTATE];
    const float Dval = Dv[d];
    #pragma unroll
    for (int n = 0; n < NSTATE; ++n) {
        A[n] = -expf(A_log[d * NSTATE + n]);
        h[n] = 0.f;
    }
    __shared__ float sB[14][NSTATE];
    __shared__ float sC[14][NSTATE];
    const float* xrow = xdbl + (size_t)b * LSEQ * 64;

    for (int c0 = 0; c0 < LSEQ; c0 += 14) {
        __syncthreads();
        if (threadIdx.x < 224) {
            int rr = threadIdx.x >> 4, nn = threadIdx.x & 15;
            sB[rr][nn] = xrow[(c0 + rr) * 64 + 32 + nn];
            sC[rr][nn] = xrow[(c0 + rr) * 64 + 48 + nn];
        }
        __syncthreads();
        for (int j = 0; j < 14; ++j) {
            const size_t base = (size_t)b * LSEQ + (c0 + j);
            float dtv = dt[base * DINNER + d];
            float xv  = xc[base * DINNER + d];
            float zv  = xz[(base << 11) + DINNER + d];
            float dtx = dtv * xv;
            float acc = 0.f;
            #pragma unroll
            for (int n = 0; n < NSTATE; ++n) {
                float dA = expf(dtv * A[n]);
                h[n] = dA * h[n] + dtx * sB[j][n];
                acc += h[n] * sC[j][n];
            }
            float yv = acc + xv * Dval;
            float sz = zv / (1.f + expf(-zv));
            y[base * DINNER + d] = yv * sz;
        }
    }
}

// ---------------------------------------------------------------------------
// Mean pool over L, then (tiny) classifier head.
// ---------------------------------------------------------------------------
__global__ __launch_bounds__(256) void pool_kernel(
    const float* __restrict__ t, float* __restrict__ pooled)
{
    int idx = blockIdx.x * 256 + threadIdx.x;   // 32*512 = 16384
    int dm = idx & (DMODEL - 1);
    int b = idx >> 9;
    float s = 0.f;
    for (int l = 0; l < LSEQ; ++l)
        s += t[((size_t)(b * LSEQ + l) << 9) + dm];
    pooled[idx] = s * (1.f / (float)LSEQ);
}

__global__ __launch_bounds__(320) void head_kernel(
    const float* __restrict__ pooled, const float* __restrict__ Wh,
    const float* __restrict__ bh, float* __restrict__ out)
{
    int tid = threadIdx.x;
    if (tid >= 320) return;
    int b = tid / 10, o = tid % 10;
    float s = bh[o];
    for (int k = 0; k < DMODEL; ++k)
        s += pooled[b * DMODEL + k] * Wh[o * DMODEL + k];
    out[b * 10 + o] = s;
}

// ---------------------------------------------------------------------------
extern "C" void kernel_launch(void* const* d_in, const int* in_sizes, int n_in,
                              void* d_out, int out_size, void* d_ws, size_t ws_size,
                              hipStream_t stream)
{
    const float* x         = (const float*)d_in[0];
    const float* ln0_g     = (const float*)d_in[1];
    const float* ln0_b     = (const float*)d_in[2];
    const float* W_emb     = (const float*)d_in[3];
    const float* b_emb     = (const float*)d_in[4];
    const float* ln1_g     = (const float*)d_in[5];
    const float* ln1_b     = (const float*)d_in[6];
    const float* in_proj_w = (const float*)d_in[7];
    const float* conv_w    = (const float*)d_in[8];
    const float* conv_b    = (const float*)d_in[9];
    const float* x_proj_w  = (const float*)d_in[10];
    const float* dt_proj_w = (const float*)d_in[11];
    const float* dt_proj_b = (const float*)d_in[12];
    const float* A_log     = (const float*)d_in[13];
    const float* D_p       = (const float*)d_in[14];
    const float* out_proj_w= (const float*)d_in[15];
    const float* blk_ln_g  = (const float*)d_in[16];
    const float* blk_ln_b  = (const float*)d_in[17];
    const float* W_head    = (const float*)d_in[18];
    const float* b_head    = (const float*)d_in[19];

    const int M = BATCHN * LSEQ;   // 6272 rows

    char* ws = (char*)d_ws;
    size_t off = 0;
    auto alloc = [&](size_t bytes) -> float* {
        float* p = (float*)(ws + off);
        off += (bytes + 255) & ~(size_t)255;
        return p;
    };
    float* tp     = alloc((size_t)M * PDIM  * 4);   // patch tokens
    float* t      = alloc((size_t)M * DMODEL * 4);  // residual stream
    float* xz     = alloc((size_t)M * 2 * DINNER * 4);
    float* xc     = alloc((size_t)M * DINNER * 4);
    float* xdbl   = alloc((size_t)M * 64 * 4);
    float* dtbuf  = alloc((size_t)M * DINNER * 4);
    float* ybuf   = alloc((size_t)M * DINNER * 4);
    float* yout   = alloc((size_t)M * DMODEL * 4);
    float* pooled = alloc((size_t)BATCHN * DMODEL * 4);
    (void)ws_size; (void)in_sizes; (void)n_in; (void)out_size;

    // --- stem ---
    patchify_kernel<<<(M * PDIM) / 256, 256, 0, stream>>>(x, tp);
    ln_kernel<<<M, 256, 0, stream>>>(tp, nullptr, ln0_g, ln0_b, tp, PDIM);
    gemm_nt<<<dim3(DMODEL / 64, M / 64), 256, 0, stream>>>(
        tp, PDIM, W_emb, t, DMODEL, b_emb, M, DMODEL, PDIM, 0);
    ln_kernel<<<M, 256, 0, stream>>>(t, nullptr, ln1_g, ln1_b, t, DMODEL);

    // --- mamba layers ---
    for (int i = 0; i < NLAYER; ++i) {
        const float* inW  = in_proj_w + (size_t)i * 2 * DINNER * DMODEL;
        const float* cw   = conv_w    + (size_t)i * DINNER * 4;
        const float* cb   = conv_b    + (size_t)i * DINNER;
        const float* xpW  = x_proj_w  + (size_t)i * 64 * DINNER;
        const float* dtW  = dt_proj_w + (size_t)i * DINNER * RRANK;
        const float* dtB  = dt_proj_b + (size_t)i * DINNER;
        const float* Ali  = A_log     + (size_t)i * DINNER * NSTATE;
        const float* Di   = D_p       + (size_t)i * DINNER;
        const float* outW = out_proj_w+ (size_t)i * DMODEL * DINNER;
        const float* bg   = blk_ln_g  + (size_t)i * DMODEL;
        const float* bb   = blk_ln_b  + (size_t)i * DMODEL;

        // xz = t @ inW^T                       (6272 x 2048, K=512)
        gemm_nt<<<dim3((2 * DINNER) / 64, M / 64), 256, 0, stream>>>(
            t, DMODEL, inW, xz, 2 * DINNER, nullptr, M, 2 * DINNER, DMODEL, 0);
        // xc = silu(causal depthwise conv(xs))
        conv_silu_kernel<<<(M * DINNER) / 256, 256, 0, stream>>>(xz, cw, cb, xc);
        // x_dbl = xc @ xpW^T                   (6272 x 64, K=1024)
        gemm_nt<<<dim3(64 / 64, M / 64), 256, 0, stream>>>(
            xc, DINNER, xpW, xdbl, 64, nullptr, M, 64, DINNER, 0);
        // dt = softplus(x_dbl[:, :32] @ dtW^T + dtB)   (6272 x 1024, K=32)
        gemm_nt<<<dim3(DINNER / 64, M / 64), 256, 0, stream>>>(
            xdbl, 64, dtW, dtbuf, DINNER, dtB, M, DINNER, RRANK, 1);
        // selective scan + D skip + silu(z) gating
        scan_kernel<<<(BATCHN * DINNER) / 256, 256, 0, stream>>>(
            xc, dtbuf, xdbl, Ali, Di, xz, ybuf);
        // yout = y @ outW^T                    (6272 x 512, K=1024)
        gemm_nt<<<dim3(DMODEL / 64, M / 64), 256, 0, stream>>>(
            ybuf, DINNER, outW, yout, DMODEL, nullptr, M, DMODEL, DINNER, 0);
        // t = LN(yout + t)
        ln_kernel<<<M, 256, 0, stream>>>(yout, t, bg, bb, t, DMODEL);
    }

    // --- pool + head ---
    pool_kernel<<<(BATCHN * DMODEL) / 256, 256, 0, stream>>>(t, pooled);
    head_kernel<<<1, 320, 0, stream>>>(pooled, W_head, b_head, (float*)d_out);
}

// Round 2
// 3541.690 us; speedup vs baseline: 1.2929x; 1.2929x over previous
//
#include <hip/hip_runtime.h>
#include <cstdint>
#include <cstddef>

// Problem constants
#define BATCHN 32
#define LSEQ   196     // (224/16)^2
#define DMODEL 512
#define DINNER 1024    // 2*DM
#define PDIM   768     // 3*16*16
#define NSTATE 16
#define RRANK  32
#define NLAYER 6

// ---------------------------------------------------------------------------
// Generic NT GEMM: C[M,N] = A[M,K] @ W[N,K]^T (+bias) (+act)
// A row stride = lda, W row stride = K, C row stride = ldc.
// Requires M%64==0, N%64==0, K%16==0 (true for all shapes here).
// act: 0 = none, 1 = softplus
// ---------------------------------------------------------------------------
__global__ __launch_bounds__(256) void gemm_nt(
    const float* __restrict__ A, int lda,
    const float* __restrict__ W,
    float* __restrict__ C, int ldc,
    const float* __restrict__ bias,
    int M, int N, int K, int act)
{
    __shared__ float As[16][64];
    __shared__ float Ws[16][64];
    const int bm = blockIdx.y * 64;
    const int bn = blockIdx.x * 64;
    const int tid = threadIdx.x;
    const int tx = tid & 15;
    const int ty = tid >> 4;
    const int r   = tid >> 2;         // 0..63
    const int kk4 = (tid & 3) << 2;   // 0,4,8,12

    float acc[4][4];
    #pragma unroll
    for (int i = 0; i < 4; ++i)
        #pragma unroll
        for (int j = 0; j < 4; ++j) acc[i][j] = 0.f;

    for (int k0 = 0; k0 < K; k0 += 16) {
        float4 va = *(const float4*)(A + (size_t)(bm + r) * lda + k0 + kk4);
        float4 vw = *(const float4*)(W + (size_t)(bn + r) * K   + k0 + kk4);
        __syncthreads();   // previous iteration's reads complete
        As[kk4 + 0][r] = va.x; As[kk4 + 1][r] = va.y;
        As[kk4 + 2][r] = va.z; As[kk4 + 3][r] = va.w;
        Ws[kk4 + 0][r] = vw.x; Ws[kk4 + 1][r] = vw.y;
        Ws[kk4 + 2][r] = vw.z; Ws[kk4 + 3][r] = vw.w;
        __syncthreads();
        #pragma unroll
        for (int kk = 0; kk < 16; ++kk) {
            float4 a = *(const float4*)&As[kk][ty << 2];
            float4 b = *(const float4*)&Ws[kk][tx << 2];
            acc[0][0] += a.x * b.x; acc[0][1] += a.x * b.y;
            acc[0][2] += a.x * b.z; acc[0][3] += a.x * b.w;
            acc[1][0] += a.y * b.x; acc[1][1] += a.y * b.y;
            acc[1][2] += a.y * b.z; acc[1][3] += a.y * b.w;
            acc[2][0] += a.z * b.x; acc[2][1] += a.z * b.y;
            acc[2][2] += a.z * b.z; acc[2][3] += a.z * b.w;
            acc[3][0] += a.w * b.x; acc[3][1] += a.w * b.y;
            acc[3][2] += a.w * b.z; acc[3][3] += a.w * b.w;
        }
    }

    #pragma unroll
    for (int i = 0; i < 4; ++i) {
        const int m = bm + (ty << 2) + i;
        #pragma unroll
        for (int j = 0; j < 4; ++j) {
            const int n = bn + (tx << 2) + j;
            float v = acc[i][j];
            if (bias) v += bias[n];
            if (act == 1) {          // softplus, numerically safe
                v = (v > 20.f) ? v : log1pf(expf(v));
            }
            C[(size_t)m * ldc + n] = v;
        }
    }
}

// ---------------------------------------------------------------------------
// Patchify: x (B,3,224,224) -> tp (B, 196, 768), pd = c*256 + p1*16 + p2
// ---------------------------------------------------------------------------
__global__ __launch_bounds__(256) void patchify_kernel(
    const float* __restrict__ x, float* __restrict__ tp)
{
    int idx = blockIdx.x * 256 + threadIdx.x;   // B*L*PD = 4,816,896
    int pd = idx % PDIM;
    int bl = idx / PDIM;
    int l = bl % LSEQ, b = bl / LSEQ;
    int c = pd >> 8, rem = pd & 255, p1 = rem >> 4, p2 = rem & 15;
    int gh = l / 14, gw = l % 14;
    int hh = gh * 16 + p1, ww = gw * 16 + p2;
    tp[idx] = x[(((size_t)b * 3 + c) * 224 + hh) * 224 + ww];
}

// ---------------------------------------------------------------------------
// LayerNorm over last dim W (512 or 768). Optional residual (out = LN(in+res)).
// One block (256 threads) per row; in-place safe.
// ---------------------------------------------------------------------------
__global__ __launch_bounds__(256) void ln_kernel(
    const float* __restrict__ in, const float* __restrict__ res,
    const float* __restrict__ g, const float* __restrict__ bt,
    float* __restrict__ out, int W)
{
    __shared__ float red[4];
    const int row = blockIdx.x;
    const size_t base = (size_t)row * W;
    const int nper = W >> 8;      // 2 or 3
    float vals[3];
    float s = 0.f;
    for (int j = 0; j < nper; ++j) {
        int c = (j << 8) + threadIdx.x;
        float v = in[base + c];
        if (res) v += res[base + c];
        vals[j] = v;
        s += v;
    }
    int lane = threadIdx.x & 63, wid = threadIdx.x >> 6;
    #pragma unroll
    for (int o = 32; o > 0; o >>= 1) s += __shfl_down(s, o);
    if (lane == 0) red[wid] = s;
    __syncthreads();
    float mu = (red[0] + red[1] + red[2] + red[3]) / (float)W;
    __syncthreads();
    float vs = 0.f;
    for (int j = 0; j < nper; ++j) { float d = vals[j] - mu; vs += d * d; }
    #pragma unroll
    for (int o = 32; o > 0; o >>= 1) vs += __shfl_down(vs, o);
    if (lane == 0) red[wid] = vs;
    __syncthreads();
    float var = (red[0] + red[1] + red[2] + red[3]) / (float)W;
    float rstd = rsqrtf(var + 1e-5f);
    for (int j = 0; j < nper; ++j) {
        int c = (j << 8) + threadIdx.x;
        out[base + c] = (vals[j] - mu) * rstd * g[c] + bt[c];
    }
}

// ---------------------------------------------------------------------------
// Causal depthwise conv (K=4) + SiLU.  xs = first half of xz (stride 2048).
// xc[b,l,d] = silu( sum_k cw[d,k]*xs[b, l-3+k, d] + cb[d] )
// ---------------------------------------------------------------------------
__global__ __launch_bounds__(256) void conv_silu_kernel(
    const float* __restrict__ xz, const float* __restrict__ cw,
    const float* __restrict__ cb, float* __restrict__ xc)
{
    int idx = blockIdx.x * 256 + threadIdx.x;  // B*L*DI = 6,422,528
    int d = idx & (DINNER - 1);
    int bl = idx >> 10;
    int l = bl % LSEQ, b = bl / LSEQ;
    float acc = cb[d];
    #pragma unroll
    for (int k = 0; k < 4; ++k) {
        int ls = l + k - 3;
        if (ls >= 0)
            acc += cw[(d << 2) + k] * xz[((size_t)(b * LSEQ + ls) << 11) + d];
    }
    // silu via fast exp + hw rcp (error ~1ulp; fp32 margin is 160x)
    xc[idx] = acc * __builtin_amdgcn_rcpf(1.f + __expf(-acc));
}

// ---------------------------------------------------------------------------
// Selective scan, state-parallel version.
// 4 lanes per (b,d) channel, 4 states per lane. Cross-state reduction via
// quad shuffles (DPP, free). Block = 256 threads = 64 channels.
// Grid = (DINNER/64, BATCH) = (16, 32) -> 2048 waves (8 waves/CU).
// Fuses: y = (scan + xc*D) * silu(z).
// ---------------------------------------------------------------------------
__global__ __launch_bounds__(256) void scan_kernel(
    const float* __restrict__ xc, const float* __restrict__ dt,
    const float* __restrict__ xdbl, const float* __restrict__ A_log,
    const float* __restrict__ Dv, const float* __restrict__ xz,
    float* __restrict__ y)
{
    const int b   = blockIdx.y;
    const int q   = threadIdx.x >> 2;       // 0..63 channel within block
    const int sub = threadIdx.x & 3;        // state group: states [4*sub, 4*sub+4)
    const int d   = blockIdx.x * 64 + q;

    float A[4], h[4];
    #pragma unroll
    for (int n = 0; n < 4; ++n) {
        A[n] = -__expf(A_log[d * NSTATE + sub * 4 + n]);
        h[n] = 0.f;
    }
    const float Dval = Dv[d];
    const size_t bL = (size_t)b * LSEQ;
    const float* xrow = xdbl + bL * 64;

    // software-pipelined prefetch of step 0
    float  dtv = dt[bL * DINNER + d];
    float  xv  = xc[bL * DINNER + d];
    float  zv  = xz[(bL << 11) + DINNER + d];
    float4 Bv  = *(const float4*)(xrow + 32 + 4 * sub);
    float4 Cv  = *(const float4*)(xrow + 48 + 4 * sub);

    for (int l = 0; l < LSEQ; ++l) {
        // prefetch step l+1 while computing step l
        const int lp = (l + 1 < LSEQ) ? l + 1 : l;
        const size_t basep = (bL + lp) * DINNER + d;
        float  dtv_n = dt[basep];
        float  xv_n  = xc[basep];
        float  zv_n  = xz[((bL + lp) << 11) + DINNER + d];
        float4 Bv_n  = *(const float4*)(xrow + lp * 64 + 32 + 4 * sub);
        float4 Cv_n  = *(const float4*)(xrow + lp * 64 + 48 + 4 * sub);

        const float dtx = dtv * xv;
        float dA0 = __expf(dtv * A[0]);
        float dA1 = __expf(dtv * A[1]);
        float dA2 = __expf(dtv * A[2]);
        float dA3 = __expf(dtv * A[3]);
        h[0] = dA0 * h[0] + dtx * Bv.x;
        h[1] = dA1 * h[1] + dtx * Bv.y;
        h[2] = dA2 * h[2] + dtx * Bv.z;
        h[3] = dA3 * h[3] + dtx * Bv.w;
        float acc = h[0] * Cv.x + h[1] * Cv.y + h[2] * Cv.z + h[3] * Cv.w;

        // reduce across the 4 state-groups (xor 1,2 stay in-quad -> DPP)
        acc += __shfl_xor(acc, 1);
        acc += __shfl_xor(acc, 2);

        if (sub == 0) {
            float yv = acc + xv * Dval;
            float sz = zv * __builtin_amdgcn_rcpf(1.f + __expf(-zv));
            y[(bL + l) * DINNER + d] = yv * sz;
        }
        dtv = dtv_n; xv = xv_n; zv = zv_n; Bv = Bv_n; Cv = Cv_n;
    }
}

// ---------------------------------------------------------------------------
// Mean pool over L, then (tiny) classifier head.
// ---------------------------------------------------------------------------
__global__ __launch_bounds__(256) void pool_kernel(
    const float* __restrict__ t, float* __restrict__ pooled)
{
    int idx = blockIdx.x * 256 + threadIdx.x;   // 32*512 = 16384
    int dm = idx & (DMODEL - 1);
    int b = idx >> 9;
    float s = 0.f;
    for (int l = 0; l < LSEQ; ++l)
        s += t[((size_t)(b * LSEQ + l) << 9) + dm];
    pooled[idx] = s * (1.f / (float)LSEQ);
}

__global__ __launch_bounds__(320) void head_kernel(
    const float* __restrict__ pooled, const float* __restrict__ Wh,
    const float* __restrict__ bh, float* __restrict__ out)
{
    int tid = threadIdx.x;
    if (tid >= 320) return;
    int b = tid / 10, o = tid % 10;
    float s = bh[o];
    for (int k = 0; k < DMODEL; ++k)
        s += pooled[b * DMODEL + k] * Wh[o * DMODEL + k];
    out[b * 10 + o] = s;
}

// ---------------------------------------------------------------------------
extern "C" void kernel_launch(void* const* d_in, const int* in_sizes, int n_in,
                              void* d_out, int out_size, void* d_ws, size_t ws_size,
                              hipStream_t stream)
{
    const float* x         = (const float*)d_in[0];
    const float* ln0_g     = (const float*)d_in[1];
    const float* ln0_b     = (const float*)d_in[2];
    const float* W_emb     = (const float*)d_in[3];
    const float* b_emb     = (const float*)d_in[4];
    const float* ln1_g     = (const float*)d_in[5];
    const float* ln1_b     = (const float*)d_in[6];
    const float* in_proj_w = (const float*)d_in[7];
    const float* conv_w    = (const float*)d_in[8];
    const float* conv_b    = (const float*)d_in[9];
    const float* x_proj_w  = (const float*)d_in[10];
    const float* dt_proj_w = (const float*)d_in[11];
    const float* dt_proj_b = (const float*)d_in[12];
    const float* A_log     = (const float*)d_in[13];
    const float* D_p       = (const float*)d_in[14];
    const float* out_proj_w= (const float*)d_in[15];
    const float* blk_ln_g  = (const float*)d_in[16];
    const float* blk_ln_b  = (const float*)d_in[17];
    const float* W_head    = (const float*)d_in[18];
    const float* b_head    = (const float*)d_in[19];

    const int M = BATCHN * LSEQ;   // 6272 rows

    char* ws = (char*)d_ws;
    size_t off = 0;
    auto alloc = [&](size_t bytes) -> float* {
        float* p = (float*)(ws + off);
        off += (bytes + 255) & ~(size_t)255;
        return p;
    };
    float* tp     = alloc((size_t)M * PDIM  * 4);   // patch tokens
    float* t      = alloc((size_t)M * DMODEL * 4);  // residual stream
    float* xz     = alloc((size_t)M * 2 * DINNER * 4);
    float* xc     = alloc((size_t)M * DINNER * 4);
    float* xdbl   = alloc((size_t)M * 64 * 4);
    float* dtbuf  = alloc((size_t)M * DINNER * 4);
    float* ybuf   = alloc((size_t)M * DINNER * 4);
    float* yout   = alloc((size_t)M * DMODEL * 4);
    float* pooled = alloc((size_t)BATCHN * DMODEL * 4);
    (void)ws_size; (void)in_sizes; (void)n_in; (void)out_size;

    // --- stem ---
    patchify_kernel<<<(M * PDIM) / 256, 256, 0, stream>>>(x, tp);
    ln_kernel<<<M, 256, 0, stream>>>(tp, nullptr, ln0_g, ln0_b, tp, PDIM);
    gemm_nt<<<dim3(DMODEL / 64, M / 64), 256, 0, stream>>>(
        tp, PDIM, W_emb, t, DMODEL, b_emb, M, DMODEL, PDIM, 0);
    ln_kernel<<<M, 256, 0, stream>>>(t, nullptr, ln1_g, ln1_b, t, DMODEL);

    // --- mamba layers ---
    for (int i = 0; i < NLAYER; ++i) {
        const float* inW  = in_proj_w + (size_t)i * 2 * DINNER * DMODEL;
        const float* cw   = conv_w    + (size_t)i * DINNER * 4;
        const float* cb   = conv_b    + (size_t)i * DINNER;
        const float* xpW  = x_proj_w  + (size_t)i * 64 * DINNER;
        const float* dtW  = dt_proj_w + (size_t)i * DINNER * RRANK;
        const float* dtB  = dt_proj_b + (size_t)i * DINNER;
        const float* Ali  = A_log     + (size_t)i * DINNER * NSTATE;
        const float* Di   = D_p       + (size_t)i * DINNER;
        const float* outW = out_proj_w+ (size_t)i * DMODEL * DINNER;
        const float* bg   = blk_ln_g  + (size_t)i * DMODEL;
        const float* bb   = blk_ln_b  + (size_t)i * DMODEL;

        // xz = t @ inW^T                       (6272 x 2048, K=512)
        gemm_nt<<<dim3((2 * DINNER) / 64, M / 64), 256, 0, stream>>>(
            t, DMODEL, inW, xz, 2 * DINNER, nullptr, M, 2 * DINNER, DMODEL, 0);
        // xc = silu(causal depthwise conv(xs))
        conv_silu_kernel<<<(M * DINNER) / 256, 256, 0, stream>>>(xz, cw, cb, xc);
        // x_dbl = xc @ xpW^T                   (6272 x 64, K=1024)
        gemm_nt<<<dim3(64 / 64, M / 64), 256, 0, stream>>>(
            xc, DINNER, xpW, xdbl, 64, nullptr, M, 64, DINNER, 0);
        // dt = softplus(x_dbl[:, :32] @ dtW^T + dtB)   (6272 x 1024, K=32)
        gemm_nt<<<dim3(DINNER / 64, M / 64), 256, 0, stream>>>(
            xdbl, 64, dtW, dtbuf, DINNER, dtB, M, DINNER, RRANK, 1);
        // selective scan + D skip + silu(z) gating (state-parallel)
        scan_kernel<<<dim3(DINNER / 64, BATCHN), 256, 0, stream>>>(
            xc, dtbuf, xdbl, Ali, Di, xz, ybuf);
        // yout = y @ outW^T                    (6272 x 512, K=1024)
        gemm_nt<<<dim3(DMODEL / 64, M / 64), 256, 0, stream>>>(
            ybuf, DINNER, outW, yout, DMODEL, nullptr, M, DMODEL, DINNER, 0);
        // t = LN(yout + t)
        ln_kernel<<<M, 256, 0, stream>>>(yout, t, bg, bb, t, DMODEL);
    }

    // --- pool + head ---
    pool_kernel<<<(BATCHN * DMODEL) / 256, 256, 0, stream>>>(t, pooled);
    head_kernel<<<1, 320, 0, stream>>>(pooled, W_head, b_head, (float*)d_out);
}

// Round 3
// 2268.501 us; speedup vs baseline: 2.0186x; 1.5612x over previous
//
#include <hip/hip_runtime.h>
#include <cstdint>
#include <cstddef>

// Problem constants
#define BATCHN 32
#define LSEQ   196     // (224/16)^2
#define DMODEL 512
#define DINNER 1024    // 2*DM
#define PDIM   768     // 3*16*16
#define NSTATE 16
#define RRANK  32
#define NLAYER 6

typedef __bf16 bf16_t;
typedef __bf16 bf16x8 __attribute__((ext_vector_type(8)));
typedef float  f32x4  __attribute__((ext_vector_type(4)));

// ---------------------------------------------------------------------------
// Split fp32 -> (hi, lo) bf16 pair.  x ~= hi + lo to ~2^-16 relative.
// ---------------------------------------------------------------------------
__global__ __launch_bounds__(256) void split_kernel(
    const float* __restrict__ src, bf16_t* __restrict__ hi,
    bf16_t* __restrict__ lo, int n)
{
    int i = blockIdx.x * 256 + threadIdx.x;
    if (i < n) {
        float x = src[i];
        bf16_t h = (bf16_t)x;
        hi[i] = h;
        lo[i] = (bf16_t)(x - (float)h);
    }
}

// ---------------------------------------------------------------------------
// bf16x3 split-precision MFMA GEMM:  C[M,N] = A[M,K] @ W[N,K]^T (+bias)
// A,W given as (hi,lo) bf16 pairs; computes Ah*Wh + Ah*Wl + Al*Wh with fp32
// accumulation (error ~2^-16 rel, fp32-grade).
// Block 256 thr = 4 waves; tile 128x128, BK=32; wave = 64x64 = 4x4 MFMA tiles.
// LDS rows padded 32->40 bf16 so ds_read_b128 fragments are ~conflict-free.
// Requires M%128==0, N%128==0, K%32==0.
// ---------------------------------------------------------------------------
__global__ __launch_bounds__(256) void gemm_mfma3(
    const bf16_t* __restrict__ Ah, const bf16_t* __restrict__ Al,
    const bf16_t* __restrict__ Wh, const bf16_t* __restrict__ Wl,
    float* __restrict__ C, const float* __restrict__ bias,
    int M, int N, int K)
{
    __shared__ bf16_t sAh[128][40];
    __shared__ bf16_t sAl[128][40];
    __shared__ bf16_t sBh[128][40];
    __shared__ bf16_t sBl[128][40];

    const int bm = blockIdx.y * 128;
    const int bn = blockIdx.x * 128;
    const int tid  = threadIdx.x;
    const int lane = tid & 63;
    const int w    = tid >> 6;
    const int wm   = (w & 1) * 64;
    const int wn   = (w >> 1) * 64;

    // staging: 512 16B-chunks per 128x32 tile; thread t covers chunk t and t+256
    const int srow = tid >> 2;          // 0..63
    const int scol = (tid & 3) * 8;     // 0,8,16,24 (bf16 elements)

    const size_t a0 = (size_t)(bm + srow)      * K + scol;
    const size_t a1 = (size_t)(bm + srow + 64) * K + scol;
    const size_t b0 = (size_t)(bn + srow)      * K + scol;
    const size_t b1 = (size_t)(bn + srow + 64) * K + scol;

    f32x4 acc[4][4] = {};

    for (int k0 = 0; k0 < K; k0 += 32) {
        float4 vah0 = *(const float4*)(Ah + a0 + k0);
        float4 vah1 = *(const float4*)(Ah + a1 + k0);
        float4 val0 = *(const float4*)(Al + a0 + k0);
        float4 val1 = *(const float4*)(Al + a1 + k0);
        float4 vbh0 = *(const float4*)(Wh + b0 + k0);
        float4 vbh1 = *(const float4*)(Wh + b1 + k0);
        float4 vbl0 = *(const float4*)(Wl + b0 + k0);
        float4 vbl1 = *(const float4*)(Wl + b1 + k0);
        __syncthreads();                  // previous iter's frag reads done
        *(float4*)&sAh[srow     ][scol] = vah0;
        *(float4*)&sAh[srow + 64][scol] = vah1;
        *(float4*)&sAl[srow     ][scol] = val0;
        *(float4*)&sAl[srow + 64][scol] = val1;
        *(float4*)&sBh[srow     ][scol] = vbh0;
        *(float4*)&sBh[srow + 64][scol] = vbh1;
        *(float4*)&sBl[srow     ][scol] = vbl0;
        *(float4*)&sBl[srow + 64][scol] = vbl1;
        __syncthreads();

        const int fr = lane & 15;         // row within 16-tile (m or n)
        const int fc = (lane >> 4) * 8;   // k offset of the 8-elem fragment

        bf16x8 afh[4], afl[4];
        #pragma unroll
        for (int mt = 0; mt < 4; ++mt) {
            afh[mt] = *(const bf16x8*)&sAh[wm + mt * 16 + fr][fc];
            afl[mt] = *(const bf16x8*)&sAl[wm + mt * 16 + fr][fc];
        }
        #pragma unroll
        for (int nt = 0; nt < 4; ++nt) {
            bf16x8 bfh = *(const bf16x8*)&sBh[wn + nt * 16 + fr][fc];
            bf16x8 bfl = *(const bf16x8*)&sBl[wn + nt * 16 + fr][fc];
            #pragma unroll
            for (int mt = 0; mt < 4; ++mt) {
                acc[mt][nt] = __builtin_amdgcn_mfma_f32_16x16x32_bf16(
                    afh[mt], bfh, acc[mt][nt], 0, 0, 0);
                acc[mt][nt] = __builtin_amdgcn_mfma_f32_16x16x32_bf16(
                    afh[mt], bfl, acc[mt][nt], 0, 0, 0);
                acc[mt][nt] = __builtin_amdgcn_mfma_f32_16x16x32_bf16(
                    afl[mt], bfh, acc[mt][nt], 0, 0, 0);
            }
        }
    }

    // epilogue: C/D layout col=lane&15, row=(lane>>4)*4+reg  [m89-verified]
    const int cr = (lane >> 4) * 4;
    const int cc = lane & 15;
    #pragma unroll
    for (int nt = 0; nt < 4; ++nt) {
        const int n = bn + wn + nt * 16 + cc;
        const float bv = bias ? bias[n] : 0.f;
        #pragma unroll
        for (int mt = 0; mt < 4; ++mt) {
            const int m0 = bm + wm + mt * 16 + cr;
            #pragma unroll
            for (int r = 0; r < 4; ++r)
                C[(size_t)(m0 + r) * N + n] = acc[mt][nt][r] + bv;
        }
    }
}

// ---------------------------------------------------------------------------
// Generic NT GEMM (fp32 vector) for the small shapes: x_proj (N=64) and
// dt_proj (K=32).  C[M,N] = A[M,K] @ W[N,K]^T (+bias) (+softplus)
// ---------------------------------------------------------------------------
__global__ __launch_bounds__(256) void gemm_nt(
    const float* __restrict__ A, int lda,
    const float* __restrict__ W,
    float* __restrict__ C, int ldc,
    const float* __restrict__ bias,
    int M, int N, int K, int act)
{
    __shared__ float As[16][64];
    __shared__ float Ws[16][64];
    const int bm = blockIdx.y * 64;
    const int bn = blockIdx.x * 64;
    const int tid = threadIdx.x;
    const int tx = tid & 15;
    const int ty = tid >> 4;
    const int r   = tid >> 2;
    const int kk4 = (tid & 3) << 2;

    float acc[4][4];
    #pragma unroll
    for (int i = 0; i < 4; ++i)
        #pragma unroll
        for (int j = 0; j < 4; ++j) acc[i][j] = 0.f;

    for (int k0 = 0; k0 < K; k0 += 16) {
        float4 va = *(const float4*)(A + (size_t)(bm + r) * lda + k0 + kk4);
        float4 vw = *(const float4*)(W + (size_t)(bn + r) * K   + k0 + kk4);
        __syncthreads();
        As[kk4 + 0][r] = va.x; As[kk4 + 1][r] = va.y;
        As[kk4 + 2][r] = va.z; As[kk4 + 3][r] = va.w;
        Ws[kk4 + 0][r] = vw.x; Ws[kk4 + 1][r] = vw.y;
        Ws[kk4 + 2][r] = vw.z; Ws[kk4 + 3][r] = vw.w;
        __syncthreads();
        #pragma unroll
        for (int kk = 0; kk < 16; ++kk) {
            float4 a = *(const float4*)&As[kk][ty << 2];
            float4 b = *(const float4*)&Ws[kk][tx << 2];
            acc[0][0] += a.x * b.x; acc[0][1] += a.x * b.y;
            acc[0][2] += a.x * b.z; acc[0][3] += a.x * b.w;
            acc[1][0] += a.y * b.x; acc[1][1] += a.y * b.y;
            acc[1][2] += a.y * b.z; acc[1][3] += a.y * b.w;
            acc[2][0] += a.z * b.x; acc[2][1] += a.z * b.y;
            acc[2][2] += a.z * b.z; acc[2][3] += a.z * b.w;
            acc[3][0] += a.w * b.x; acc[3][1] += a.w * b.y;
            acc[3][2] += a.w * b.z; acc[3][3] += a.w * b.w;
        }
    }

    #pragma unroll
    for (int i = 0; i < 4; ++i) {
        const int m = bm + (ty << 2) + i;
        #pragma unroll
        for (int j = 0; j < 4; ++j) {
            const int n = bn + (tx << 2) + j;
            float v = acc[i][j];
            if (bias) v += bias[n];
            if (act == 1) {
                v = (v > 20.f) ? v : log1pf(expf(v));
            }
            C[(size_t)m * ldc + n] = v;
        }
    }
}

// ---------------------------------------------------------------------------
// Patchify: x (B,3,224,224) -> tp (B, 196, 768), pd = c*256 + p1*16 + p2
// ---------------------------------------------------------------------------
__global__ __launch_bounds__(256) void patchify_kernel(
    const float* __restrict__ x, float* __restrict__ tp)
{
    int idx = blockIdx.x * 256 + threadIdx.x;   // B*L*PD = 4,816,896
    int pd = idx % PDIM;
    int bl = idx / PDIM;
    int l = bl % LSEQ, b = bl / LSEQ;
    int c = pd >> 8, rem = pd & 255, p1 = rem >> 4, p2 = rem & 15;
    int gh = l / 14, gw = l % 14;
    int hh = gh * 16 + p1, ww = gw * 16 + p2;
    tp[idx] = x[(((size_t)b * 3 + c) * 224 + hh) * 224 + ww];
}

// ---------------------------------------------------------------------------
// LayerNorm over last dim W (512 or 768). Optional residual; optional fp32
// output; optional (hi,lo) bf16-split output for the following MFMA GEMM.
// ---------------------------------------------------------------------------
__global__ __launch_bounds__(256) void ln_kernel(
    const float* __restrict__ in, const float* __restrict__ res,
    const float* __restrict__ g, const float* __restrict__ bt,
    float* __restrict__ out, bf16_t* __restrict__ hi,
    bf16_t* __restrict__ lo, int W)
{
    __shared__ float red[4];
    const int row = blockIdx.x;
    const size_t base = (size_t)row * W;
    const int nper = W >> 8;      // 2 or 3
    float vals[3];
    float s = 0.f;
    for (int j = 0; j < nper; ++j) {
        int c = (j << 8) + threadIdx.x;
        float v = in[base + c];
        if (res) v += res[base + c];
        vals[j] = v;
        s += v;
    }
    int lane = threadIdx.x & 63, wid = threadIdx.x >> 6;
    #pragma unroll
    for (int o = 32; o > 0; o >>= 1) s += __shfl_down(s, o);
    if (lane == 0) red[wid] = s;
    __syncthreads();
    float mu = (red[0] + red[1] + red[2] + red[3]) / (float)W;
    __syncthreads();
    float vs = 0.f;
    for (int j = 0; j < nper; ++j) { float d = vals[j] - mu; vs += d * d; }
    #pragma unroll
    for (int o = 32; o > 0; o >>= 1) vs += __shfl_down(vs, o);
    if (lane == 0) red[wid] = vs;
    __syncthreads();
    float var = (red[0] + red[1] + red[2] + red[3]) / (float)W;
    float rstd = rsqrtf(var + 1e-5f);
    for (int j = 0; j < nper; ++j) {
        int c = (j << 8) + threadIdx.x;
        float v = (vals[j] - mu) * rstd * g[c] + bt[c];
        if (out) out[base + c] = v;
        if (hi) {
            bf16_t h = (bf16_t)v;
            hi[base + c] = h;
            lo[base + c] = (bf16_t)(v - (float)h);
        }
    }
}

// ---------------------------------------------------------------------------
// Causal depthwise conv (K=4) + SiLU.  xs = first half of xz (stride 2048).
// ---------------------------------------------------------------------------
__global__ __launch_bounds__(256) void conv_silu_kernel(
    const float* __restrict__ xz, const float* __restrict__ cw,
    const float* __restrict__ cb, float* __restrict__ xc)
{
    int idx = blockIdx.x * 256 + threadIdx.x;  // B*L*DI = 6,422,528
    int d = idx & (DINNER - 1);
    int bl = idx >> 10;
    int l = bl % LSEQ, b = bl / LSEQ;
    float acc = cb[d];
    #pragma unroll
    for (int k = 0; k < 4; ++k) {
        int ls = l + k - 3;
        if (ls >= 0)
            acc += cw[(d << 2) + k] * xz[((size_t)(b * LSEQ + ls) << 11) + d];
    }
    xc[idx] = acc * __builtin_amdgcn_rcpf(1.f + __expf(-acc));
}

// ---------------------------------------------------------------------------
// Selective scan, state-parallel. 4 lanes per (b,d), 4 states/lane, quad-DPP
// reduction. Emits y directly as (hi,lo) bf16 split for the out_proj MFMA.
// ---------------------------------------------------------------------------
__global__ __launch_bounds__(256) void scan_kernel(
    const float* __restrict__ xc, const float* __restrict__ dt,
    const float* __restrict__ xdbl, const float* __restrict__ A_log,
    const float* __restrict__ Dv, const float* __restrict__ xz,
    bf16_t* __restrict__ yh, bf16_t* __restrict__ yl)
{
    const int b   = blockIdx.y;
    const int q   = threadIdx.x >> 2;
    const int sub = threadIdx.x & 3;
    const int d   = blockIdx.x * 64 + q;

    float A[4], h[4];
    #pragma unroll
    for (int n = 0; n < 4; ++n) {
        A[n] = -__expf(A_log[d * NSTATE + sub * 4 + n]);
        h[n] = 0.f;
    }
    const float Dval = Dv[d];
    const size_t bL = (size_t)b * LSEQ;
    const float* xrow = xdbl + bL * 64;

    float  dtv = dt[bL * DINNER + d];
    float  xv  = xc[bL * DINNER + d];
    float  zv  = xz[(bL << 11) + DINNER + d];
    float4 Bv  = *(const float4*)(xrow + 32 + 4 * sub);
    float4 Cv  = *(const float4*)(xrow + 48 + 4 * sub);

    for (int l = 0; l < LSEQ; ++l) {
        const int lp = (l + 1 < LSEQ) ? l + 1 : l;
        const size_t basep = (bL + lp) * DINNER + d;
        float  dtv_n = dt[basep];
        float  xv_n  = xc[basep];
        float  zv_n  = xz[((bL + lp) << 11) + DINNER + d];
        float4 Bv_n  = *(const float4*)(xrow + lp * 64 + 32 + 4 * sub);
        float4 Cv_n  = *(const float4*)(xrow + lp * 64 + 48 + 4 * sub);

        const float dtx = dtv * xv;
        float dA0 = __expf(dtv * A[0]);
        float dA1 = __expf(dtv * A[1]);
        float dA2 = __expf(dtv * A[2]);
        float dA3 = __expf(dtv * A[3]);
        h[0] = dA0 * h[0] + dtx * Bv.x;
        h[1] = dA1 * h[1] + dtx * Bv.y;
        h[2] = dA2 * h[2] + dtx * Bv.z;
        h[3] = dA3 * h[3] + dtx * Bv.w;
        float acc = h[0] * Cv.x + h[1] * Cv.y + h[2] * Cv.z + h[3] * Cv.w;

        acc += __shfl_xor(acc, 1);
        acc += __shfl_xor(acc, 2);

        if (sub == 0) {
            float yv = acc + xv * Dval;
            float sz = zv * __builtin_amdgcn_rcpf(1.f + __expf(-zv));
            float o = yv * sz;
            bf16_t ho = (bf16_t)o;
            const size_t oi = (bL + l) * DINNER + d;
            yh[oi] = ho;
            yl[oi] = (bf16_t)(o - (float)ho);
        }
        dtv = dtv_n; xv = xv_n; zv = zv_n; Bv = Bv_n; Cv = Cv_n;
    }
}

// ---------------------------------------------------------------------------
// Mean pool over L, then (tiny) classifier head.
// ---------------------------------------------------------------------------
__global__ __launch_bounds__(256) void pool_kernel(
    const float* __restrict__ t, float* __restrict__ pooled)
{
    int idx = blockIdx.x * 256 + threadIdx.x;   // 32*512 = 16384
    int dm = idx & (DMODEL - 1);
    int b = idx >> 9;
    float s = 0.f;
    for (int l = 0; l < LSEQ; ++l)
        s += t[((size_t)(b * LSEQ + l) << 9) + dm];
    pooled[idx] = s * (1.f / (float)LSEQ);
}

__global__ __launch_bounds__(320) void head_kernel(
    const float* __restrict__ pooled, const float* __restrict__ Wh,
    const float* __restrict__ bh, float* __restrict__ out)
{
    int tid = threadIdx.x;
    if (tid >= 320) return;
    int b = tid / 10, o = tid % 10;
    float s = bh[o];
    for (int k = 0; k < DMODEL; ++k)
        s += pooled[b * DMODEL + k] * Wh[o * DMODEL + k];
    out[b * 10 + o] = s;
}

// ---------------------------------------------------------------------------
extern "C" void kernel_launch(void* const* d_in, const int* in_sizes, int n_in,
                              void* d_out, int out_size, void* d_ws, size_t ws_size,
                              hipStream_t stream)
{
    const float* x         = (const float*)d_in[0];
    const float* ln0_g     = (const float*)d_in[1];
    const float* ln0_b     = (const float*)d_in[2];
    const float* W_emb     = (const float*)d_in[3];
    const float* b_emb     = (const float*)d_in[4];
    const float* ln1_g     = (const float*)d_in[5];
    const float* ln1_b     = (const float*)d_in[6];
    const float* in_proj_w = (const float*)d_in[7];
    const float* conv_w    = (const float*)d_in[8];
    const float* conv_b    = (const float*)d_in[9];
    const float* x_proj_w  = (const float*)d_in[10];
    const float* dt_proj_w = (const float*)d_in[11];
    const float* dt_proj_b = (const float*)d_in[12];
    const float* A_log     = (const float*)d_in[13];
    const float* D_p       = (const float*)d_in[14];
    const float* out_proj_w= (const float*)d_in[15];
    const float* blk_ln_g  = (const float*)d_in[16];
    const float* blk_ln_b  = (const float*)d_in[17];
    const float* W_head    = (const float*)d_in[18];
    const float* b_head    = (const float*)d_in[19];

    const int M = BATCHN * LSEQ;   // 6272 rows

    char* ws = (char*)d_ws;
    size_t off = 0;
    auto alloc = [&](size_t bytes) -> void* {
        void* p = (void*)(ws + off);
        off += (bytes + 255) & ~(size_t)255;
        return p;
    };
    float*  tp     = (float*)alloc((size_t)M * PDIM * 4);
    bf16_t* tp_h   = (bf16_t*)alloc((size_t)M * PDIM * 2);
    bf16_t* tp_l   = (bf16_t*)alloc((size_t)M * PDIM * 2);
    float*  t      = (float*)alloc((size_t)M * DMODEL * 4);
    bf16_t* t_h    = (bf16_t*)alloc((size_t)M * DMODEL * 2);
    bf16_t* t_l    = (bf16_t*)alloc((size_t)M * DMODEL * 2);
    float*  xz     = (float*)alloc((size_t)M * 2 * DINNER * 4);
    float*  xc     = (float*)alloc((size_t)M * DINNER * 4);
    float*  xdbl   = (float*)alloc((size_t)M * 64 * 4);
    float*  dtbuf  = (float*)alloc((size_t)M * DINNER * 4);
    bf16_t* y_h    = (bf16_t*)alloc((size_t)M * DINNER * 2);
    bf16_t* y_l    = (bf16_t*)alloc((size_t)M * DINNER * 2);
    float*  yout   = (float*)alloc((size_t)M * DMODEL * 4);
    float*  pooled = (float*)alloc((size_t)BATCHN * DMODEL * 4);
    const int n_inW  = NLAYER * 2 * DINNER * DMODEL;   // 6,291,456
    const int n_outW = NLAYER * DMODEL * DINNER;       // 3,145,728
    const int n_embW = DMODEL * PDIM;                  // 393,216
    bf16_t* winh  = (bf16_t*)alloc((size_t)n_inW * 2);
    bf16_t* winl  = (bf16_t*)alloc((size_t)n_inW * 2);
    bf16_t* wouth = (bf16_t*)alloc((size_t)n_outW * 2);
    bf16_t* woutl = (bf16_t*)alloc((size_t)n_outW * 2);
    bf16_t* wembh = (bf16_t*)alloc((size_t)n_embW * 2);
    bf16_t* wembl = (bf16_t*)alloc((size_t)n_embW * 2);
    (void)ws_size; (void)in_sizes; (void)n_in; (void)out_size;

    // --- weight splits (hi/lo bf16) ---
    split_kernel<<<(n_inW  + 255) / 256, 256, 0, stream>>>(in_proj_w,  winh,  winl,  n_inW);
    split_kernel<<<(n_outW + 255) / 256, 256, 0, stream>>>(out_proj_w, wouth, woutl, n_outW);
    split_kernel<<<(n_embW + 255) / 256, 256, 0, stream>>>(W_emb,      wembh, wembl, n_embW);

    // --- stem ---
    patchify_kernel<<<(M * PDIM) / 256, 256, 0, stream>>>(x, tp);
    ln_kernel<<<M, 256, 0, stream>>>(tp, nullptr, ln0_g, ln0_b, nullptr, tp_h, tp_l, PDIM);
    gemm_mfma3<<<dim3(DMODEL / 128, M / 128), 256, 0, stream>>>(
        tp_h, tp_l, wembh, wembl, t, b_emb, M, DMODEL, PDIM);
    ln_kernel<<<M, 256, 0, stream>>>(t, nullptr, ln1_g, ln1_b, t, t_h, t_l, DMODEL);

    // --- mamba layers ---
    for (int i = 0; i < NLAYER; ++i) {
        const bf16_t* winh_i  = winh  + (size_t)i * 2 * DINNER * DMODEL;
        const bf16_t* winl_i  = winl  + (size_t)i * 2 * DINNER * DMODEL;
        const bf16_t* wouth_i = wouth + (size_t)i * DMODEL * DINNER;
        const bf16_t* woutl_i = woutl + (size_t)i * DMODEL * DINNER;
        const float* cw   = conv_w    + (size_t)i * DINNER * 4;
        const float* cb   = conv_b    + (size_t)i * DINNER;
        const float* xpW  = x_proj_w  + (size_t)i * 64 * DINNER;
        const float* dtW  = dt_proj_w + (size_t)i * DINNER * RRANK;
        const float* dtB  = dt_proj_b + (size_t)i * DINNER;
        const float* Ali  = A_log     + (size_t)i * DINNER * NSTATE;
        const float* Di   = D_p       + (size_t)i * DINNER;
        const float* bg   = blk_ln_g  + (size_t)i * DMODEL;
        const float* bb   = blk_ln_b  + (size_t)i * DMODEL;

        // xz = t @ inW^T   (6272 x 2048, K=512)  [bf16x3 MFMA]
        gemm_mfma3<<<dim3((2 * DINNER) / 128, M / 128), 256, 0, stream>>>(
            t_h, t_l, winh_i, winl_i, xz, nullptr, M, 2 * DINNER, DMODEL);
        // xc = silu(causal depthwise conv(xs))
        conv_silu_kernel<<<(M * DINNER) / 256, 256, 0, stream>>>(xz, cw, cb, xc);
        // x_dbl = xc @ xpW^T   (6272 x 64, K=1024)  [fp32 vector]
        gemm_nt<<<dim3(64 / 64, M / 64), 256, 0, stream>>>(
            xc, DINNER, xpW, xdbl, 64, nullptr, M, 64, DINNER, 0);
        // dt = softplus(x_dbl[:, :32] @ dtW^T + dtB)   (K=32)  [fp32 vector]
        gemm_nt<<<dim3(DINNER / 64, M / 64), 256, 0, stream>>>(
            xdbl, 64, dtW, dtbuf, DINNER, dtB, M, DINNER, RRANK, 1);
        // selective scan + D skip + silu(z); emits y as bf16 hi/lo
        scan_kernel<<<dim3(DINNER / 64, BATCHN), 256, 0, stream>>>(
            xc, dtbuf, xdbl, Ali, Di, xz, y_h, y_l);
        // yout = y @ outW^T   (6272 x 512, K=1024)  [bf16x3 MFMA]
        gemm_mfma3<<<dim3(DMODEL / 128, M / 128), 256, 0, stream>>>(
            y_h, y_l, wouth_i, woutl_i, yout, nullptr, M, DMODEL, DINNER);
        // t = LN(yout + t), plus hi/lo split for next layer's in_proj
        ln_kernel<<<M, 256, 0, stream>>>(yout, t, bg, bb, t, t_h, t_l, DMODEL);
    }

    // --- pool + head ---
    pool_kernel<<<(BATCHN * DMODEL) / 256, 256, 0, stream>>>(t, pooled);
    head_kernel<<<1, 320, 0, stream>>>(pooled, W_head, b_head, (float*)d_out);
}

// Round 4
// 1959.900 us; speedup vs baseline: 2.3364x; 1.1575x over previous
//
#include <hip/hip_runtime.h>
#include <cstdint>
#include <cstddef>

// Problem constants
#define BATCHN 32
#define LSEQ   196     // (224/16)^2
#define DMODEL 512
#define DINNER 1024    // 2*DM
#define PDIM   768     // 3*16*16
#define NSTATE 16
#define RRANK  32
#define NLAYER 6

typedef __bf16 bf16_t;
typedef __bf16 bf16x8 __attribute__((ext_vector_type(8)));
typedef float  f32x4  __attribute__((ext_vector_type(4)));

// ---------------------------------------------------------------------------
// Split fp32 -> (hi, lo) bf16 pair.  x ~= hi + lo to ~2^-16 relative.
// ---------------------------------------------------------------------------
__global__ __launch_bounds__(256) void split_kernel(
    const float* __restrict__ src, bf16_t* __restrict__ hi,
    bf16_t* __restrict__ lo, int n)
{
    int i = blockIdx.x * 256 + threadIdx.x;
    if (i < n) {
        float x = src[i];
        bf16_t h = (bf16_t)x;
        hi[i] = h;
        lo[i] = (bf16_t)(x - (float)h);
    }
}

// ---------------------------------------------------------------------------
// bf16x3 split-precision MFMA GEMM:  C[M,N] = A[M,K] @ W[N,K]^T (+bias)
// ---------------------------------------------------------------------------
__global__ __launch_bounds__(256) void gemm_mfma3(
    const bf16_t* __restrict__ Ah, const bf16_t* __restrict__ Al,
    const bf16_t* __restrict__ Wh, const bf16_t* __restrict__ Wl,
    float* __restrict__ C, const float* __restrict__ bias,
    int M, int N, int K)
{
    __shared__ bf16_t sAh[128][40];
    __shared__ bf16_t sAl[128][40];
    __shared__ bf16_t sBh[128][40];
    __shared__ bf16_t sBl[128][40];

    const int bm = blockIdx.y * 128;
    const int bn = blockIdx.x * 128;
    const int tid  = threadIdx.x;
    const int lane = tid & 63;
    const int w    = tid >> 6;
    const int wm   = (w & 1) * 64;
    const int wn   = (w >> 1) * 64;

    const int srow = tid >> 2;          // 0..63
    const int scol = (tid & 3) * 8;     // 0,8,16,24 (bf16 elements)

    const size_t a0 = (size_t)(bm + srow)      * K + scol;
    const size_t a1 = (size_t)(bm + srow + 64) * K + scol;
    const size_t b0 = (size_t)(bn + srow)      * K + scol;
    const size_t b1 = (size_t)(bn + srow + 64) * K + scol;

    f32x4 acc[4][4] = {};

    for (int k0 = 0; k0 < K; k0 += 32) {
        float4 vah0 = *(const float4*)(Ah + a0 + k0);
        float4 vah1 = *(const float4*)(Ah + a1 + k0);
        float4 val0 = *(const float4*)(Al + a0 + k0);
        float4 val1 = *(const float4*)(Al + a1 + k0);
        float4 vbh0 = *(const float4*)(Wh + b0 + k0);
        float4 vbh1 = *(const float4*)(Wh + b1 + k0);
        float4 vbl0 = *(const float4*)(Wl + b0 + k0);
        float4 vbl1 = *(const float4*)(Wl + b1 + k0);
        __syncthreads();                  // previous iter's frag reads done
        *(float4*)&sAh[srow     ][scol] = vah0;
        *(float4*)&sAh[srow + 64][scol] = vah1;
        *(float4*)&sAl[srow     ][scol] = val0;
        *(float4*)&sAl[srow + 64][scol] = val1;
        *(float4*)&sBh[srow     ][scol] = vbh0;
        *(float4*)&sBh[srow + 64][scol] = vbh1;
        *(float4*)&sBl[srow     ][scol] = vbl0;
        *(float4*)&sBl[srow + 64][scol] = vbl1;
        __syncthreads();

        const int fr = lane & 15;         // row within 16-tile (m or n)
        const int fc = (lane >> 4) * 8;   // k offset of the 8-elem fragment

        bf16x8 afh[4], afl[4];
        #pragma unroll
        for (int mt = 0; mt < 4; ++mt) {
            afh[mt] = *(const bf16x8*)&sAh[wm + mt * 16 + fr][fc];
            afl[mt] = *(const bf16x8*)&sAl[wm + mt * 16 + fr][fc];
        }
        #pragma unroll
        for (int nt = 0; nt < 4; ++nt) {
            bf16x8 bfh = *(const bf16x8*)&sBh[wn + nt * 16 + fr][fc];
            bf16x8 bfl = *(const bf16x8*)&sBl[wn + nt * 16 + fr][fc];
            #pragma unroll
            for (int mt = 0; mt < 4; ++mt) {
                acc[mt][nt] = __builtin_amdgcn_mfma_f32_16x16x32_bf16(
                    afh[mt], bfh, acc[mt][nt], 0, 0, 0);
                acc[mt][nt] = __builtin_amdgcn_mfma_f32_16x16x32_bf16(
                    afh[mt], bfl, acc[mt][nt], 0, 0, 0);
                acc[mt][nt] = __builtin_amdgcn_mfma_f32_16x16x32_bf16(
                    afl[mt], bfh, acc[mt][nt], 0, 0, 0);
            }
        }
    }

    // epilogue: C/D layout col=lane&15, row=(lane>>4)*4+reg  [m89-verified]
    const int cr = (lane >> 4) * 4;
    const int cc = lane & 15;
    #pragma unroll
    for (int nt = 0; nt < 4; ++nt) {
        const int n = bn + wn + nt * 16 + cc;
        const float bv = bias ? bias[n] : 0.f;
        #pragma unroll
        for (int mt = 0; mt < 4; ++mt) {
            const int m0 = bm + wm + mt * 16 + cr;
            #pragma unroll
            for (int r = 0; r < 4; ++r)
                C[(size_t)(m0 + r) * N + n] = acc[mt][nt][r] + bv;
        }
    }
}

// ---------------------------------------------------------------------------
// fp32 vector NT GEMM (used for dt_proj: K=32).  C = A@W^T (+bias)(+softplus)
// ---------------------------------------------------------------------------
__global__ __launch_bounds__(256) void gemm_nt(
    const float* __restrict__ A, int lda,
    const float* __restrict__ W,
    float* __restrict__ C, int ldc,
    const float* __restrict__ bias,
    int M, int N, int K, int act)
{
    __shared__ float As[16][64];
    __shared__ float Ws[16][64];
    const int bm = blockIdx.y * 64;
    const int bn = blockIdx.x * 64;
    const int tid = threadIdx.x;
    const int tx = tid & 15;
    const int ty = tid >> 4;
    const int r   = tid >> 2;
    const int kk4 = (tid & 3) << 2;

    float acc[4][4];
    #pragma unroll
    for (int i = 0; i < 4; ++i)
        #pragma unroll
        for (int j = 0; j < 4; ++j) acc[i][j] = 0.f;

    for (int k0 = 0; k0 < K; k0 += 16) {
        float4 va = *(const float4*)(A + (size_t)(bm + r) * lda + k0 + kk4);
        float4 vw = *(const float4*)(W + (size_t)(bn + r) * K   + k0 + kk4);
        __syncthreads();
        As[kk4 + 0][r] = va.x; As[kk4 + 1][r] = va.y;
        As[kk4 + 2][r] = va.z; As[kk4 + 3][r] = va.w;
        Ws[kk4 + 0][r] = vw.x; Ws[kk4 + 1][r] = vw.y;
        Ws[kk4 + 2][r] = vw.z; Ws[kk4 + 3][r] = vw.w;
        __syncthreads();
        #pragma unroll
        for (int kk = 0; kk < 16; ++kk) {
            float4 a = *(const float4*)&As[kk][ty << 2];
            float4 b = *(const float4*)&Ws[kk][tx << 2];
            acc[0][0] += a.x * b.x; acc[0][1] += a.x * b.y;
            acc[0][2] += a.x * b.z; acc[0][3] += a.x * b.w;
            acc[1][0] += a.y * b.x; acc[1][1] += a.y * b.y;
            acc[1][2] += a.y * b.z; acc[1][3] += a.y * b.w;
            acc[2][0] += a.z * b.x; acc[2][1] += a.z * b.y;
            acc[2][2] += a.z * b.z; acc[2][3] += a.z * b.w;
            acc[3][0] += a.w * b.x; acc[3][1] += a.w * b.y;
            acc[3][2] += a.w * b.z; acc[3][3] += a.w * b.w;
        }
    }

    #pragma unroll
    for (int i = 0; i < 4; ++i) {
        const int m = bm + (ty << 2) + i;
        #pragma unroll
        for (int j = 0; j < 4; ++j) {
            const int n = bn + (tx << 2) + j;
            float v = acc[i][j];
            if (bias) v += bias[n];
            if (act == 1) {
                v = (v > 20.f) ? v : log1pf(expf(v));
            }
            C[(size_t)m * ldc + n] = v;
        }
    }
}

// ---------------------------------------------------------------------------
// Split-K variant for the narrow x_proj GEMM (N=64): grid.z = K-split index.
// Each split writes its partial 64x64 tiles to Cpart + z*M*ldc.
// ---------------------------------------------------------------------------
__global__ __launch_bounds__(256) void gemm_nt_splitk(
    const float* __restrict__ A, int lda,
    const float* __restrict__ W, int ldw,
    float* __restrict__ Cpart, int ldc,
    int M, int N, int kchunk)
{
    __shared__ float As[16][64];
    __shared__ float Ws[16][64];
    const int bm = blockIdx.y * 64;
    const int bn = blockIdx.x * 64;
    const int kb = blockIdx.z * kchunk;
    Cpart += (size_t)blockIdx.z * M * ldc;

    const int tid = threadIdx.x;
    const int tx = tid & 15;
    const int ty = tid >> 4;
    const int r   = tid >> 2;
    const int kk4 = (tid & 3) << 2;

    float acc[4][4];
    #pragma unroll
    for (int i = 0; i < 4; ++i)
        #pragma unroll
        for (int j = 0; j < 4; ++j) acc[i][j] = 0.f;

    for (int k0 = kb; k0 < kb + kchunk; k0 += 16) {
        float4 va = *(const float4*)(A + (size_t)(bm + r) * lda + k0 + kk4);
        float4 vw = *(const float4*)(W + (size_t)(bn + r) * ldw + k0 + kk4);
        __syncthreads();
        As[kk4 + 0][r] = va.x; As[kk4 + 1][r] = va.y;
        As[kk4 + 2][r] = va.z; As[kk4 + 3][r] = va.w;
        Ws[kk4 + 0][r] = vw.x; Ws[kk4 + 1][r] = vw.y;
        Ws[kk4 + 2][r] = vw.z; Ws[kk4 + 3][r] = vw.w;
        __syncthreads();
        #pragma unroll
        for (int kk = 0; kk < 16; ++kk) {
            float4 a = *(const float4*)&As[kk][ty << 2];
            float4 b = *(const float4*)&Ws[kk][tx << 2];
            acc[0][0] += a.x * b.x; acc[0][1] += a.x * b.y;
            acc[0][2] += a.x * b.z; acc[0][3] += a.x * b.w;
            acc[1][0] += a.y * b.x; acc[1][1] += a.y * b.y;
            acc[1][2] += a.y * b.z; acc[1][3] += a.y * b.w;
            acc[2][0] += a.z * b.x; acc[2][1] += a.z * b.y;
            acc[2][2] += a.z * b.z; acc[2][3] += a.z * b.w;
            acc[3][0] += a.w * b.x; acc[3][1] += a.w * b.y;
            acc[3][2] += a.w * b.z; acc[3][3] += a.w * b.w;
        }
    }

    #pragma unroll
    for (int i = 0; i < 4; ++i) {
        const int m = bm + (ty << 2) + i;
        #pragma unroll
        for (int j = 0; j < 4; ++j) {
            const int n = bn + (tx << 2) + j;
            Cpart[(size_t)m * ldc + n] = acc[i][j];
        }
    }
}

__global__ __launch_bounds__(256) void reduce_splitk(
    const float* __restrict__ part, float* __restrict__ out, int n, int nsplit)
{
    int i = blockIdx.x * 256 + threadIdx.x;
    if (i < n) {
        float s = 0.f;
        for (int j = 0; j < nsplit; ++j) s += part[(size_t)j * n + i];
        out[i] = s;
    }
}

// ---------------------------------------------------------------------------
// Patchify: x (B,3,224,224) -> tp (B, 196, 768), pd = c*256 + p1*16 + p2
// ---------------------------------------------------------------------------
__global__ __launch_bounds__(256) void patchify_kernel(
    const float* __restrict__ x, float* __restrict__ tp)
{
    int idx = blockIdx.x * 256 + threadIdx.x;   // B*L*PD = 4,816,896
    int pd = idx % PDIM;
    int bl = idx / PDIM;
    int l = bl % LSEQ, b = bl / LSEQ;
    int c = pd >> 8, rem = pd & 255, p1 = rem >> 4, p2 = rem & 15;
    int gh = l / 14, gw = l % 14;
    int hh = gh * 16 + p1, ww = gw * 16 + p2;
    tp[idx] = x[(((size_t)b * 3 + c) * 224 + hh) * 224 + ww];
}

// ---------------------------------------------------------------------------
// LayerNorm over last dim W (512 or 768). Optional residual; optional fp32
// output; optional (hi,lo) bf16-split output for the following MFMA GEMM.
// ---------------------------------------------------------------------------
__global__ __launch_bounds__(256) void ln_kernel(
    const float* __restrict__ in, const float* __restrict__ res,
    const float* __restrict__ g, const float* __restrict__ bt,
    float* __restrict__ out, bf16_t* __restrict__ hi,
    bf16_t* __restrict__ lo, int W)
{
    __shared__ float red[4];
    const int row = blockIdx.x;
    const size_t base = (size_t)row * W;
    const int nper = W >> 8;      // 2 or 3
    float vals[3];
    float s = 0.f;
    for (int j = 0; j < nper; ++j) {
        int c = (j << 8) + threadIdx.x;
        float v = in[base + c];
        if (res) v += res[base + c];
        vals[j] = v;
        s += v;
    }
    int lane = threadIdx.x & 63, wid = threadIdx.x >> 6;
    #pragma unroll
    for (int o = 32; o > 0; o >>= 1) s += __shfl_down(s, o);
    if (lane == 0) red[wid] = s;
    __syncthreads();
    float mu = (red[0] + red[1] + red[2] + red[3]) / (float)W;
    __syncthreads();
    float vs = 0.f;
    for (int j = 0; j < nper; ++j) { float d = vals[j] - mu; vs += d * d; }
    #pragma unroll
    for (int o = 32; o > 0; o >>= 1) vs += __shfl_down(vs, o);
    if (lane == 0) red[wid] = vs;
    __syncthreads();
    float var = (red[0] + red[1] + red[2] + red[3]) / (float)W;
    float rstd = rsqrtf(var + 1e-5f);
    for (int j = 0; j < nper; ++j) {
        int c = (j << 8) + threadIdx.x;
        float v = (vals[j] - mu) * rstd * g[c] + bt[c];
        if (out) out[base + c] = v;
        if (hi) {
            bf16_t h = (bf16_t)v;
            hi[base + c] = h;
            lo[base + c] = (bf16_t)(v - (float)h);
        }
    }
}

// ---------------------------------------------------------------------------
// Causal depthwise conv (K=4) + SiLU.  xs = first half of xz (stride 2048).
// ---------------------------------------------------------------------------
__global__ __launch_bounds__(256) void conv_silu_kernel(
    const float* __restrict__ xz, const float* __restrict__ cw,
    const float* __restrict__ cb, float* __restrict__ xc)
{
    int idx = blockIdx.x * 256 + threadIdx.x;  // B*L*DI = 6,422,528
    int d = idx & (DINNER - 1);
    int bl = idx >> 10;
    int l = bl % LSEQ, b = bl / LSEQ;
    float acc = cb[d];
    #pragma unroll
    for (int k = 0; k < 4; ++k) {
        int ls = l + k - 3;
        if (ls >= 0)
            acc += cw[(d << 2) + k] * xz[((size_t)(b * LSEQ + ls) << 11) + d];
    }
    xc[idx] = acc * __builtin_amdgcn_rcpf(1.f + __expf(-acc));
}

// ---------------------------------------------------------------------------
// quad broadcast: all 4 lanes of a quad get lane J's value (DPP quad_perm).
// MUST be executed with all quad lanes active (convergent).
// ---------------------------------------------------------------------------
template<int J>
__device__ __forceinline__ float qbcast(float v) {
    constexpr int ctrl = J | (J << 2) | (J << 4) | (J << 6);
    return __int_as_float(__builtin_amdgcn_mov_dpp(
        __float_as_int(v), ctrl, 0xF, 0xF, true));
}

// ---------------------------------------------------------------------------
// Selective scan v3, state-parallel + group-4 software pipeline.
// 4 lanes per (b,d): lane sub owns states [4sub,4sub+4).
// Steps processed in groups of 4 (LSEQ = 196 = 49*4):
//  - scalars dt/xc/z: lane sub loads step 4g+sub only; per-step value obtained
//    via quad_perm DPP broadcast (kills the 4x redundant loads).
//  - B/C quarters for all 4 steps batch-prefetched one full group ahead
//    (~300-cycle window covers L1/L2 latency at 2 waves/SIMD occupancy).
// Emits y as (hi,lo) bf16 split for the out_proj MFMA.
// ---------------------------------------------------------------------------
__global__ __launch_bounds__(256) void scan_kernel(
    const float* __restrict__ xc, const float* __restrict__ dt,
    const float* __restrict__ xdbl, const float* __restrict__ A_log,
    const float* __restrict__ Dv, const float* __restrict__ xz,
    bf16_t* __restrict__ yh, bf16_t* __restrict__ yl)
{
    const int b   = blockIdx.y;
    const int q   = threadIdx.x >> 2;
    const int sub = threadIdx.x & 3;
    const int d   = blockIdx.x * 64 + q;

    float A2[4], h[4];
    #pragma unroll
    for (int n = 0; n < 4; ++n) {
        // fold log2(e) so dA = exp2(dtv*A2[n]) is a bare v_exp_f32
        A2[n] = -__expf(A_log[d * NSTATE + sub * 4 + n]) * 1.44269504f;
        h[n] = 0.f;
    }
    const float Dval = Dv[d];
    const size_t bL = (size_t)b * LSEQ;
    const float* xrow = xdbl + bL * 64;

    // per-lane scalar streams: step 4g+sub
    const float* pdt = dt + (bL + sub) * DINNER + d;
    const float* pxc = xc + (bL + sub) * DINNER + d;
    const float* pz  = xz + ((bL + sub) << 11) + DINNER + d;
    // B/C quarter pointers (step s of group at +s*64; +256 per group)
    const float* pB  = xrow + 32 + 4 * sub;

    float dtc, xcc, zc;
    float4 Bc[4], Cc[4];
    dtc = pdt[0]; xcc = pxc[0]; zc = pz[0];
    #pragma unroll
    for (int s = 0; s < 4; ++s) {
        Bc[s] = *(const float4*)(pB + s * 64);
        Cc[s] = *(const float4*)(pB + s * 64 + 16);
    }

    for (int g = 0; g < 49; ++g) {
        // prefetch next group (clamped at the end; never dereferenced OOB)
        const int adv = (g < 48) ? 1 : 0;
        float dtn = *(pdt + (size_t)adv * 4 * DINNER);
        float xcn = *(pxc + (size_t)adv * 4 * DINNER);
        float zn  = *(pz  + ((size_t)adv * 4 << 11));
        float4 Bn[4], Cn[4];
        const float* pBn = pB + adv * 256;
        #pragma unroll
        for (int s = 0; s < 4; ++s) {
            Bn[s] = *(const float4*)(pBn + s * 64);
            Cn[s] = *(const float4*)(pBn + s * 64 + 16);
        }

        bf16_t* py_h = yh + (bL + 4 * (size_t)g) * DINNER + d;
        bf16_t* py_l = yl + (bL + 4 * (size_t)g) * DINNER + d;

#define SCAN_STEP(J) do {                                                     \
        float dtv = qbcast<J>(dtc);                                           \
        float xv  = qbcast<J>(xcc);                                           \
        float zq  = qbcast<J>(zc);                                            \
        float dtx = dtv * xv;                                                 \
        h[0] = exp2f(dtv * A2[0]) * h[0] + dtx * Bc[J].x;                     \
        h[1] = exp2f(dtv * A2[1]) * h[1] + dtx * Bc[J].y;                     \
        h[2] = exp2f(dtv * A2[2]) * h[2] + dtx * Bc[J].z;                     \
        h[3] = exp2f(dtv * A2[3]) * h[3] + dtx * Bc[J].w;                     \
        float acc = h[0] * Cc[J].x + h[1] * Cc[J].y                           \
                  + h[2] * Cc[J].z + h[3] * Cc[J].w;                          \
        acc += __shfl_xor(acc, 1);                                            \
        acc += __shfl_xor(acc, 2);                                            \
        if (sub == 0) {                                                       \
            float yv = acc + xv * Dval;                                       \
            float sz = zq * __builtin_amdgcn_rcpf(1.f + __expf(-zq));         \
            float o  = yv * sz;                                               \
            bf16_t ho = (bf16_t)o;                                            \
            py_h[(size_t)(J) * DINNER] = ho;                                  \
            py_l[(size_t)(J) * DINNER] = (bf16_t)(o - (float)ho);             \
        }                                                                     \
    } while (0)

        SCAN_STEP(0);
        SCAN_STEP(1);
        SCAN_STEP(2);
        SCAN_STEP(3);
#undef SCAN_STEP

        pdt += 4 * DINNER; pxc += 4 * DINNER;
        pz  += (size_t)4 << 11; pB += 256;
        dtc = dtn; xcc = xcn; zc = zn;
        #pragma unroll
        for (int s = 0; s < 4; ++s) { Bc[s] = Bn[s]; Cc[s] = Cn[s]; }
    }
}

// ---------------------------------------------------------------------------
// Mean pool over L, then (tiny) classifier head.
// ---------------------------------------------------------------------------
__global__ __launch_bounds__(256) void pool_kernel(
    const float* __restrict__ t, float* __restrict__ pooled)
{
    int idx = blockIdx.x * 256 + threadIdx.x;   // 32*512 = 16384
    int dm = idx & (DMODEL - 1);
    int b = idx >> 9;
    float s = 0.f;
    for (int l = 0; l < LSEQ; ++l)
        s += t[((size_t)(b * LSEQ + l) << 9) + dm];
    pooled[idx] = s * (1.f / (float)LSEQ);
}

__global__ __launch_bounds__(320) void head_kernel(
    const float* __restrict__ pooled, const float* __restrict__ Wh,
    const float* __restrict__ bh, float* __restrict__ out)
{
    int tid = threadIdx.x;
    if (tid >= 320) return;
    int b = tid / 10, o = tid % 10;
    float s = bh[o];
    for (int k = 0; k < DMODEL; ++k)
        s += pooled[b * DMODEL + k] * Wh[o * DMODEL + k];
    out[b * 10 + o] = s;
}

// ---------------------------------------------------------------------------
extern "C" void kernel_launch(void* const* d_in, const int* in_sizes, int n_in,
                              void* d_out, int out_size, void* d_ws, size_t ws_size,
                              hipStream_t stream)
{
    const float* x         = (const float*)d_in[0];
    const float* ln0_g     = (const float*)d_in[1];
    const float* ln0_b     = (const float*)d_in[2];
    const float* W_emb     = (const float*)d_in[3];
    const float* b_emb     = (const float*)d_in[4];
    const float* ln1_g     = (const float*)d_in[5];
    const float* ln1_b     = (const float*)d_in[6];
    const float* in_proj_w = (const float*)d_in[7];
    const float* conv_w    = (const float*)d_in[8];
    const float* conv_b    = (const float*)d_in[9];
    const float* x_proj_w  = (const float*)d_in[10];
    const float* dt_proj_w = (const float*)d_in[11];
    const float* dt_proj_b = (const float*)d_in[12];
    const float* A_log     = (const float*)d_in[13];
    const float* D_p       = (const float*)d_in[14];
    const float* out_proj_w= (const float*)d_in[15];
    const float* blk_ln_g  = (const float*)d_in[16];
    const float* blk_ln_b  = (const float*)d_in[17];
    const float* W_head    = (const float*)d_in[18];
    const float* b_head    = (const float*)d_in[19];

    const int M = BATCHN * LSEQ;   // 6272 rows
    const int NSPLIT = 8;          // x_proj split-K factor (K=1024 -> 128)

    char* ws = (char*)d_ws;
    size_t off = 0;
    auto alloc = [&](size_t bytes) -> void* {
        void* p = (void*)(ws + off);
        off += (bytes + 255) & ~(size_t)255;
        return p;
    };
    float*  tp     = (float*)alloc((size_t)M * PDIM * 4);
    bf16_t* tp_h   = (bf16_t*)alloc((size_t)M * PDIM * 2);
    bf16_t* tp_l   = (bf16_t*)alloc((size_t)M * PDIM * 2);
    float*  t      = (float*)alloc((size_t)M * DMODEL * 4);
    bf16_t* t_h    = (bf16_t*)alloc((size_t)M * DMODEL * 2);
    bf16_t* t_l    = (bf16_t*)alloc((size_t)M * DMODEL * 2);
    float*  xz     = (float*)alloc((size_t)M * 2 * DINNER * 4);
    float*  xc     = (float*)alloc((size_t)M * DINNER * 4);
    float*  xdbl   = (float*)alloc((size_t)M * 64 * 4);
    float*  xdbl_p = (float*)alloc((size_t)NSPLIT * M * 64 * 4);
    float*  dtbuf  = (float*)alloc((size_t)M * DINNER * 4);
    bf16_t* y_h    = (bf16_t*)alloc((size_t)M * DINNER * 2);
    bf16_t* y_l    = (bf16_t*)alloc((size_t)M * DINNER * 2);
    float*  yout   = (float*)alloc((size_t)M * DMODEL * 4);
    float*  pooled = (float*)alloc((size_t)BATCHN * DMODEL * 4);
    const int n_inW  = NLAYER * 2 * DINNER * DMODEL;   // 6,291,456
    const int n_outW = NLAYER * DMODEL * DINNER;       // 3,145,728
    const int n_embW = DMODEL * PDIM;                  // 393,216
    bf16_t* winh  = (bf16_t*)alloc((size_t)n_inW * 2);
    bf16_t* winl  = (bf16_t*)alloc((size_t)n_inW * 2);
    bf16_t* wouth = (bf16_t*)alloc((size_t)n_outW * 2);
    bf16_t* woutl = (bf16_t*)alloc((size_t)n_outW * 2);
    bf16_t* wembh = (bf16_t*)alloc((size_t)n_embW * 2);
    bf16_t* wembl = (bf16_t*)alloc((size_t)n_embW * 2);
    (void)ws_size; (void)in_sizes; (void)n_in; (void)out_size;

    // --- weight splits (hi/lo bf16) ---
    split_kernel<<<(n_inW  + 255) / 256, 256, 0, stream>>>(in_proj_w,  winh,  winl,  n_inW);
    split_kernel<<<(n_outW + 255) / 256, 256, 0, stream>>>(out_proj_w, wouth, woutl, n_outW);
    split_kernel<<<(n_embW + 255) / 256, 256, 0, stream>>>(W_emb,      wembh, wembl, n_embW);

    // --- stem ---
    patchify_kernel<<<(M * PDIM) / 256, 256, 0, stream>>>(x, tp);
    ln_kernel<<<M, 256, 0, stream>>>(tp, nullptr, ln0_g, ln0_b, nullptr, tp_h, tp_l, PDIM);
    gemm_mfma3<<<dim3(DMODEL / 128, M / 128), 256, 0, stream>>>(
        tp_h, tp_l, wembh, wembl, t, b_emb, M, DMODEL, PDIM);
    ln_kernel<<<M, 256, 0, stream>>>(t, nullptr, ln1_g, ln1_b, t, t_h, t_l, DMODEL);

    // --- mamba layers ---
    for (int i = 0; i < NLAYER; ++i) {
        const bf16_t* winh_i  = winh  + (size_t)i * 2 * DINNER * DMODEL;
        const bf16_t* winl_i  = winl  + (size_t)i * 2 * DINNER * DMODEL;
        const bf16_t* wouth_i = wouth + (size_t)i * DMODEL * DINNER;
        const bf16_t* woutl_i = woutl + (size_t)i * DMODEL * DINNER;
        const float* cw   = conv_w    + (size_t)i * DINNER * 4;
        const float* cb   = conv_b    + (size_t)i * DINNER;
        const float* xpW  = x_proj_w  + (size_t)i * 64 * DINNER;
        const float* dtW  = dt_proj_w + (size_t)i * DINNER * RRANK;
        const float* dtB  = dt_proj_b + (size_t)i * DINNER;
        const float* Ali  = A_log     + (size_t)i * DINNER * NSTATE;
        const float* Di   = D_p       + (size_t)i * DINNER;
        const float* bg   = blk_ln_g  + (size_t)i * DMODEL;
        const float* bb   = blk_ln_b  + (size_t)i * DMODEL;

        // xz = t @ inW^T   (6272 x 2048, K=512)  [bf16x3 MFMA]
        gemm_mfma3<<<dim3((2 * DINNER) / 128, M / 128), 256, 0, stream>>>(
            t_h, t_l, winh_i, winl_i, xz, nullptr, M, 2 * DINNER, DMODEL);
        // xc = silu(causal depthwise conv(xs))
        conv_silu_kernel<<<(M * DINNER) / 256, 256, 0, stream>>>(xz, cw, cb, xc);
        // x_dbl = xc @ xpW^T   (6272 x 64, K=1024)  [fp32 vector, split-K=8]
        gemm_nt_splitk<<<dim3(1, M / 64, NSPLIT), 256, 0, stream>>>(
            xc, DINNER, xpW, DINNER, xdbl_p, 64, M, 64, DINNER / NSPLIT);
        reduce_splitk<<<(M * 64 + 255) / 256, 256, 0, stream>>>(
            xdbl_p, xdbl, M * 64, NSPLIT);
        // dt = softplus(x_dbl[:, :32] @ dtW^T + dtB)   (K=32)  [fp32 vector]
        gemm_nt<<<dim3(DINNER / 64, M / 64), 256, 0, stream>>>(
            xdbl, 64, dtW, dtbuf, DINNER, dtB, M, DINNER, RRANK, 1);
        // selective scan + D skip + silu(z); emits y as bf16 hi/lo
        scan_kernel<<<dim3(DINNER / 64, BATCHN), 256, 0, stream>>>(
            xc, dtbuf, xdbl, Ali, Di, xz, y_h, y_l);
        // yout = y @ outW^T   (6272 x 512, K=1024)  [bf16x3 MFMA]
        gemm_mfma3<<<dim3(DMODEL / 128, M / 128), 256, 0, stream>>>(
            y_h, y_l, wouth_i, woutl_i, yout, nullptr, M, DMODEL, DINNER);
        // t = LN(yout + t), plus hi/lo split for next layer's in_proj
        ln_kernel<<<M, 256, 0, stream>>>(yout, t, bg, bb, t, t_h, t_l, DMODEL);
    }

    // --- pool + head ---
    pool_kernel<<<(BATCHN * DMODEL) / 256, 256, 0, stream>>>(t, pooled);
    head_kernel<<<1, 320, 0, stream>>>(pooled, W_head, b_head, (float*)d_out);
}

// Round 5
// 1795.080 us; speedup vs baseline: 2.5509x; 1.0918x over previous
//
#include <hip/hip_runtime.h>
#include <cstdint>
#include <cstddef>

// Problem constants
#define BATCHN 32
#define LSEQ   196     // (224/16)^2
#define DMODEL 512
#define DINNER 1024    // 2*DM
#define PDIM   768     // 3*16*16
#define NSTATE 16
#define RRANK  32
#define NLAYER 6

typedef __bf16 bf16_t;
typedef __bf16 bf16x8 __attribute__((ext_vector_type(8)));
typedef float  f32x4  __attribute__((ext_vector_type(4)));

// async global->LDS, 16B per lane: lane i lands at lds + i*16 bytes.
__device__ __forceinline__ void gl_lds16(const bf16_t* g, bf16_t* l) {
    __builtin_amdgcn_global_load_lds(
        (const __attribute__((address_space(1))) void*)g,
        (__attribute__((address_space(3))) void*)l, 16, 0, 0);
}

// ---------------------------------------------------------------------------
// Split fp32 -> (hi, lo) bf16 pair.  x ~= hi + lo to ~2^-16 relative.
// ---------------------------------------------------------------------------
__global__ __launch_bounds__(256) void split_kernel(
    const float* __restrict__ src, bf16_t* __restrict__ hi,
    bf16_t* __restrict__ lo, int n)
{
    int i = blockIdx.x * 256 + threadIdx.x;
    if (i < n) {
        float x = src[i];
        bf16_t h = (bf16_t)x;
        hi[i] = h;
        lo[i] = (bf16_t)(x - (float)h);
    }
}

// ---------------------------------------------------------------------------
// bf16x3 split-precision MFMA GEMM:  C[M,N] = A[M,K] @ W[N,K]^T (+bias)
// Staging via global_load_lds (16B/lane). LDS is lane-linear (rows of 32
// bf16, no pad); the *source* chunk index is XOR-swizzled by (row>>1)&3 so
// fragment ds_read_b128 hits each bank-group exactly twice per 16 lanes
// (2-way aliasing is free on gfx950 — m136).
// Requires M%128==0, N%128==0, K%32==0.
// ---------------------------------------------------------------------------
__global__ __launch_bounds__(256) void gemm_mfma3(
    const bf16_t* __restrict__ Ah, const bf16_t* __restrict__ Al,
    const bf16_t* __restrict__ Wh, const bf16_t* __restrict__ Wl,
    float* __restrict__ C, const float* __restrict__ bias,
    int M, int N, int K)
{
    __shared__ bf16_t sAh[128 * 32];
    __shared__ bf16_t sAl[128 * 32];
    __shared__ bf16_t sBh[128 * 32];
    __shared__ bf16_t sBl[128 * 32];

    const int bm = blockIdx.y * 128;
    const int bn = blockIdx.x * 128;
    const int tid  = threadIdx.x;
    const int lane = tid & 63;
    const int w    = tid >> 6;
    const int wm   = (w & 1) * 64;
    const int wn   = (w >> 1) * 64;

    // staging geometry: wave w, sub-instr j (0..1) covers rows [w*32+j*16, +16)
    // lane covers row (base + lane>>2), source chunk (lane&3)^((lane>>3)&3).
    const int lrow = lane >> 2;
    const int cg8  = ((lane & 3) ^ ((lane >> 3) & 3)) * 8;   // element offset
    const size_t arow = (size_t)(bm + w * 32 + lrow) * K + cg8;
    const size_t brow = (size_t)(bn + w * 32 + lrow) * K + cg8;

    // fragment read: element offset of swizzled chunk (per-lane constant)
    const int fsw = ((lane >> 4) ^ ((lane >> 1) & 3)) * 8;
    const int fr  = lane & 15;

    f32x4 acc[4][4] = {};

    for (int k0 = 0; k0 < K; k0 += 32) {
        __syncthreads();   // all waves done reading previous tile
        #pragma unroll
        for (int j = 0; j < 2; ++j) {
            const size_t ga = arow + (size_t)j * 16 * K + k0;
            const size_t gb = brow + (size_t)j * 16 * K + k0;
            const int lo = w * 1024 + j * 512;   // element offset in LDS
            gl_lds16(Ah + ga, &sAh[lo]);
            gl_lds16(Al + ga, &sAl[lo]);
            gl_lds16(Wh + gb, &sBh[lo]);
            gl_lds16(Wl + gb, &sBl[lo]);
        }
        __syncthreads();   // vmcnt(0) drain: staged tile visible

        bf16x8 afh[4], afl[4];
        #pragma unroll
        for (int mt = 0; mt < 4; ++mt) {
            const int r = wm + mt * 16 + fr;
            afh[mt] = *(const bf16x8*)&sAh[r * 32 + fsw];
            afl[mt] = *(const bf16x8*)&sAl[r * 32 + fsw];
        }
        #pragma unroll
        for (int nt = 0; nt < 4; ++nt) {
            const int r = wn + nt * 16 + fr;
            bf16x8 bfh = *(const bf16x8*)&sBh[r * 32 + fsw];
            bf16x8 bfl = *(const bf16x8*)&sBl[r * 32 + fsw];
            #pragma unroll
            for (int mt = 0; mt < 4; ++mt) {
                acc[mt][nt] = __builtin_amdgcn_mfma_f32_16x16x32_bf16(
                    afh[mt], bfh, acc[mt][nt], 0, 0, 0);
                acc[mt][nt] = __builtin_amdgcn_mfma_f32_16x16x32_bf16(
                    afh[mt], bfl, acc[mt][nt], 0, 0, 0);
                acc[mt][nt] = __builtin_amdgcn_mfma_f32_16x16x32_bf16(
                    afl[mt], bfh, acc[mt][nt], 0, 0, 0);
            }
        }
    }

    // epilogue: C/D layout col=lane&15, row=(lane>>4)*4+reg  [m89-verified]
    const int cr = (lane >> 4) * 4;
    const int cc = lane & 15;
    #pragma unroll
    for (int nt = 0; nt < 4; ++nt) {
        const int n = bn + wn + nt * 16 + cc;
        const float bv = bias ? bias[n] : 0.f;
        #pragma unroll
        for (int mt = 0; mt < 4; ++mt) {
            const int m0 = bm + wm + mt * 16 + cr;
            #pragma unroll
            for (int r = 0; r < 4; ++r)
                C[(size_t)(m0 + r) * N + n] = acc[mt][nt][r] + bv;
        }
    }
}

// ---------------------------------------------------------------------------
// fp32 vector NT GEMM (used for dt_proj: K=32).  C = A@W^T (+bias)(+softplus)
// ---------------------------------------------------------------------------
__global__ __launch_bounds__(256) void gemm_nt(
    const float* __restrict__ A, int lda,
    const float* __restrict__ W,
    float* __restrict__ C, int ldc,
    const float* __restrict__ bias,
    int M, int N, int K, int act)
{
    __shared__ float As[16][64];
    __shared__ float Ws[16][64];
    const int bm = blockIdx.y * 64;
    const int bn = blockIdx.x * 64;
    const int tid = threadIdx.x;
    const int tx = tid & 15;
    const int ty = tid >> 4;
    const int r   = tid >> 2;
    const int kk4 = (tid & 3) << 2;

    float acc[4][4];
    #pragma unroll
    for (int i = 0; i < 4; ++i)
        #pragma unroll
        for (int j = 0; j < 4; ++j) acc[i][j] = 0.f;

    for (int k0 = 0; k0 < K; k0 += 16) {
        float4 va = *(const float4*)(A + (size_t)(bm + r) * lda + k0 + kk4);
        float4 vw = *(const float4*)(W + (size_t)(bn + r) * K   + k0 + kk4);
        __syncthreads();
        As[kk4 + 0][r] = va.x; As[kk4 + 1][r] = va.y;
        As[kk4 + 2][r] = va.z; As[kk4 + 3][r] = va.w;
        Ws[kk4 + 0][r] = vw.x; Ws[kk4 + 1][r] = vw.y;
        Ws[kk4 + 2][r] = vw.z; Ws[kk4 + 3][r] = vw.w;
        __syncthreads();
        #pragma unroll
        for (int kk = 0; kk < 16; ++kk) {
            float4 a = *(const float4*)&As[kk][ty << 2];
            float4 b = *(const float4*)&Ws[kk][tx << 2];
            acc[0][0] += a.x * b.x; acc[0][1] += a.x * b.y;
            acc[0][2] += a.x * b.z; acc[0][3] += a.x * b.w;
            acc[1][0] += a.y * b.x; acc[1][1] += a.y * b.y;
            acc[1][2] += a.y * b.z; acc[1][3] += a.y * b.w;
            acc[2][0] += a.z * b.x; acc[2][1] += a.z * b.y;
            acc[2][2] += a.z * b.z; acc[2][3] += a.z * b.w;
            acc[3][0] += a.w * b.x; acc[3][1] += a.w * b.y;
            acc[3][2] += a.w * b.z; acc[3][3] += a.w * b.w;
        }
    }

    #pragma unroll
    for (int i = 0; i < 4; ++i) {
        const int m = bm + (ty << 2) + i;
        #pragma unroll
        for (int j = 0; j < 4; ++j) {
            const int n = bn + (tx << 2) + j;
            float v = acc[i][j];
            if (bias) v += bias[n];
            if (act == 1) {
                v = (v > 20.f) ? v : log1pf(expf(v));
            }
            C[(size_t)m * ldc + n] = v;
        }
    }
}

// ---------------------------------------------------------------------------
// Split-K variant for the narrow x_proj GEMM (N=64): grid.z = K-split index.
// ---------------------------------------------------------------------------
__global__ __launch_bounds__(256) void gemm_nt_splitk(
    const float* __restrict__ A, int lda,
    const float* __restrict__ W, int ldw,
    float* __restrict__ Cpart, int ldc,
    int M, int N, int kchunk)
{
    __shared__ float As[16][64];
    __shared__ float Ws[16][64];
    const int bm = blockIdx.y * 64;
    const int bn = blockIdx.x * 64;
    const int kb = blockIdx.z * kchunk;
    Cpart += (size_t)blockIdx.z * M * ldc;

    const int tid = threadIdx.x;
    const int tx = tid & 15;
    const int ty = tid >> 4;
    const int r   = tid >> 2;
    const int kk4 = (tid & 3) << 2;

    float acc[4][4];
    #pragma unroll
    for (int i = 0; i < 4; ++i)
        #pragma unroll
        for (int j = 0; j < 4; ++j) acc[i][j] = 0.f;

    for (int k0 = kb; k0 < kb + kchunk; k0 += 16) {
        float4 va = *(const float4*)(A + (size_t)(bm + r) * lda + k0 + kk4);
        float4 vw = *(const float4*)(W + (size_t)(bn + r) * ldw + k0 + kk4);
        __syncthreads();
        As[kk4 + 0][r] = va.x; As[kk4 + 1][r] = va.y;
        As[kk4 + 2][r] = va.z; As[kk4 + 3][r] = va.w;
        Ws[kk4 + 0][r] = vw.x; Ws[kk4 + 1][r] = vw.y;
        Ws[kk4 + 2][r] = vw.z; Ws[kk4 + 3][r] = vw.w;
        __syncthreads();
        #pragma unroll
        for (int kk = 0; kk < 16; ++kk) {
            float4 a = *(const float4*)&As[kk][ty << 2];
            float4 b = *(const float4*)&Ws[kk][tx << 2];
            acc[0][0] += a.x * b.x; acc[0][1] += a.x * b.y;
            acc[0][2] += a.x * b.z; acc[0][3] += a.x * b.w;
            acc[1][0] += a.y * b.x; acc[1][1] += a.y * b.y;
            acc[1][2] += a.y * b.z; acc[1][3] += a.y * b.w;
            acc[2][0] += a.z * b.x; acc[2][1] += a.z * b.y;
            acc[2][2] += a.z * b.z; acc[2][3] += a.z * b.w;
            acc[3][0] += a.w * b.x; acc[3][1] += a.w * b.y;
            acc[3][2] += a.w * b.z; acc[3][3] += a.w * b.w;
        }
    }

    #pragma unroll
    for (int i = 0; i < 4; ++i) {
        const int m = bm + (ty << 2) + i;
        #pragma unroll
        for (int j = 0; j < 4; ++j) {
            const int n = bn + (tx << 2) + j;
            Cpart[(size_t)m * ldc + n] = acc[i][j];
        }
    }
}

__global__ __launch_bounds__(256) void reduce_splitk(
    const float* __restrict__ part, float* __restrict__ out, int n, int nsplit)
{
    int i = blockIdx.x * 256 + threadIdx.x;
    if (i < n) {
        float s = 0.f;
        for (int j = 0; j < nsplit; ++j) s += part[(size_t)j * n + i];
        out[i] = s;
    }
}

// ---------------------------------------------------------------------------
// Patchify: x (B,3,224,224) -> tp (B, 196, 768), pd = c*256 + p1*16 + p2
// ---------------------------------------------------------------------------
__global__ __launch_bounds__(256) void patchify_kernel(
    const float* __restrict__ x, float* __restrict__ tp)
{
    int idx = blockIdx.x * 256 + threadIdx.x;   // B*L*PD = 4,816,896
    int pd = idx % PDIM;
    int bl = idx / PDIM;
    int l = bl % LSEQ, b = bl / LSEQ;
    int c = pd >> 8, rem = pd & 255, p1 = rem >> 4, p2 = rem & 15;
    int gh = l / 14, gw = l % 14;
    int hh = gh * 16 + p1, ww = gw * 16 + p2;
    tp[idx] = x[(((size_t)b * 3 + c) * 224 + hh) * 224 + ww];
}

// ---------------------------------------------------------------------------
// LayerNorm over last dim W (512 or 768). Optional residual; optional fp32
// output; optional (hi,lo) bf16-split output for the following MFMA GEMM.
// ---------------------------------------------------------------------------
__global__ __launch_bounds__(256) void ln_kernel(
    const float* __restrict__ in, const float* __restrict__ res,
    const float* __restrict__ g, const float* __restrict__ bt,
    float* __restrict__ out, bf16_t* __restrict__ hi,
    bf16_t* __restrict__ lo, int W)
{
    __shared__ float red[4];
    const int row = blockIdx.x;
    const size_t base = (size_t)row * W;
    const int nper = W >> 8;      // 2 or 3
    float vals[3];
    float s = 0.f;
    for (int j = 0; j < nper; ++j) {
        int c = (j << 8) + threadIdx.x;
        float v = in[base + c];
        if (res) v += res[base + c];
        vals[j] = v;
        s += v;
    }
    int lane = threadIdx.x & 63, wid = threadIdx.x >> 6;
    #pragma unroll
    for (int o = 32; o > 0; o >>= 1) s += __shfl_down(s, o);
    if (lane == 0) red[wid] = s;
    __syncthreads();
    float mu = (red[0] + red[1] + red[2] + red[3]) / (float)W;
    __syncthreads();
    float vs = 0.f;
    for (int j = 0; j < nper; ++j) { float d = vals[j] - mu; vs += d * d; }
    #pragma unroll
    for (int o = 32; o > 0; o >>= 1) vs += __shfl_down(vs, o);
    if (lane == 0) red[wid] = vs;
    __syncthreads();
    float var = (red[0] + red[1] + red[2] + red[3]) / (float)W;
    float rstd = rsqrtf(var + 1e-5f);
    for (int j = 0; j < nper; ++j) {
        int c = (j << 8) + threadIdx.x;
        float v = (vals[j] - mu) * rstd * g[c] + bt[c];
        if (out) out[base + c] = v;
        if (hi) {
            bf16_t h = (bf16_t)v;
            hi[base + c] = h;
            lo[base + c] = (bf16_t)(v - (float)h);
        }
    }
}

// ---------------------------------------------------------------------------
// Causal depthwise conv (K=4) + SiLU.  xs = first half of xz (stride 2048).
// ---------------------------------------------------------------------------
__global__ __launch_bounds__(256) void conv_silu_kernel(
    const float* __restrict__ xz, const float* __restrict__ cw,
    const float* __restrict__ cb, float* __restrict__ xc)
{
    int idx = blockIdx.x * 256 + threadIdx.x;  // B*L*DI = 6,422,528
    int d = idx & (DINNER - 1);
    int bl = idx >> 10;
    int l = bl % LSEQ, b = bl / LSEQ;
    float acc = cb[d];
    #pragma unroll
    for (int k = 0; k < 4; ++k) {
        int ls = l + k - 3;
        if (ls >= 0)
            acc += cw[(d << 2) + k] * xz[((size_t)(b * LSEQ + ls) << 11) + d];
    }
    xc[idx] = acc * __builtin_amdgcn_rcpf(1.f + __expf(-acc));
}

// ---------------------------------------------------------------------------
// quad broadcast: all 4 lanes of a quad get lane J's value (DPP quad_perm).
// ---------------------------------------------------------------------------
template<int J>
__device__ __forceinline__ float qbcast(float v) {
    constexpr int ctrl = J | (J << 2) | (J << 4) | (J << 6);
    return __int_as_float(__builtin_amdgcn_mov_dpp(
        __float_as_int(v), ctrl, 0xF, 0xF, true));
}

// ---------------------------------------------------------------------------
// Selective scan v5: state-parallel (4 lanes/channel), group-4 steps,
// DEPTH-2 software pipeline (loads issued 2 groups = 8 steps ahead, ~550+
// cycle cover for L3/HBM latency), and group-batched stores: after the
// xor-reduce every lane holds the step sum; lane sub keeps step 4g+sub and
// all 64 lanes store once per group (2 dense store instrs vs 8 divergent).
// ---------------------------------------------------------------------------
__global__ __launch_bounds__(256) void scan_kernel(
    const float* __restrict__ xc, const float* __restrict__ dt,
    const float* __restrict__ xdbl, const float* __restrict__ A_log,
    const float* __restrict__ Dv, const float* __restrict__ xz,
    bf16_t* __restrict__ yh, bf16_t* __restrict__ yl)
{
    const int b   = blockIdx.y;
    const int q   = threadIdx.x >> 2;
    const int sub = threadIdx.x & 3;
    const int d   = blockIdx.x * 64 + q;

    float A2[4], h[4];
    #pragma unroll
    for (int n = 0; n < 4; ++n) {
        // fold log2(e) so dA = exp2(dtv*A2[n]) is a bare v_exp_f32
        A2[n] = -__expf(A_log[d * NSTATE + sub * 4 + n]) * 1.44269504f;
        h[n] = 0.f;
    }
    const float Dval = Dv[d];
    const size_t bL = (size_t)b * LSEQ;

    // per-lane streams: lane sub owns step 4g+sub's scalars
    const float* pdt = dt + (bL + sub) * DINNER + d;
    const float* pxc = xc + (bL + sub) * DINNER + d;
    const float* pz  = xz + ((bL + sub) << 11) + DINNER + d;
    const float* pB  = xdbl + bL * 64 + 32 + 4 * sub;

    float  dt_c, xc_c, z_c, dt_1, xc_1, z_1;
    float4 B_c[4], C_c[4], B_1[4], C_1[4];

    // preload groups 0 and 1
    dt_c = pdt[0];          xc_c = pxc[0];          z_c = pz[0];
    dt_1 = pdt[4 * DINNER]; xc_1 = pxc[4 * DINNER]; z_1 = pz[4 * 2048];
    #pragma unroll
    for (int s = 0; s < 4; ++s) {
        B_c[s] = *(const float4*)(pB + s * 64);
        C_c[s] = *(const float4*)(pB + s * 64 + 16);
        B_1[s] = *(const float4*)(pB + 256 + s * 64);
        C_1[s] = *(const float4*)(pB + 256 + s * 64 + 16);
    }

    for (int g = 0; g < 49; ++g) {
        // issue loads for group g+2 (clamped; last iters re-load in-bounds)
        const int adv = (g < 47) ? 2 : (48 - g);
        float dt_2 = pdt[(size_t)adv * 4 * DINNER];
        float xc_2 = pxc[(size_t)adv * 4 * DINNER];
        float z_2  = pz[(size_t)adv * 4 * 2048];
        float4 B_2[4], C_2[4];
        const float* pB2 = pB + adv * 256;
        #pragma unroll
        for (int s = 0; s < 4; ++s) {
            B_2[s] = *(const float4*)(pB2 + s * 64);
            C_2[s] = *(const float4*)(pB2 + s * 64 + 16);
        }

        float acc_keep = 0.f;

#define SCAN_STEP(J) do {                                                     \
        float dtv = qbcast<J>(dt_c);                                          \
        float xv  = qbcast<J>(xc_c);                                          \
        float dtx = dtv * xv;                                                 \
        h[0] = exp2f(dtv * A2[0]) * h[0] + dtx * B_c[J].x;                    \
        h[1] = exp2f(dtv * A2[1]) * h[1] + dtx * B_c[J].y;                    \
        h[2] = exp2f(dtv * A2[2]) * h[2] + dtx * B_c[J].z;                    \
        h[3] = exp2f(dtv * A2[3]) * h[3] + dtx * B_c[J].w;                    \
        float acc = h[0] * C_c[J].x + h[1] * C_c[J].y                         \
                  + h[2] * C_c[J].z + h[3] * C_c[J].w;                        \
        acc += __shfl_xor(acc, 1);                                            \
        acc += __shfl_xor(acc, 2);                                            \
        acc_keep = (sub == (J)) ? acc : acc_keep;                             \
    } while (0)

        SCAN_STEP(0);
        SCAN_STEP(1);
        SCAN_STEP(2);
        SCAN_STEP(3);
#undef SCAN_STEP

        // batched store: lane sub writes step 4g+sub (64 dense lanes)
        {
            float yv = acc_keep + xc_c * Dval;
            float sz = z_c * __builtin_amdgcn_rcpf(1.f + __expf(-z_c));
            float o  = yv * sz;
            bf16_t ho = (bf16_t)o;
            const size_t oi = (bL + 4 * (size_t)g + sub) * DINNER + d;
            yh[oi] = ho;
            yl[oi] = (bf16_t)(o - (float)ho);
        }

        pdt += 4 * DINNER; pxc += 4 * DINNER; pz += 4 * 2048; pB += 256;
        dt_c = dt_1; xc_c = xc_1; z_c = z_1;
        dt_1 = dt_2; xc_1 = xc_2; z_1 = z_2;
        #pragma unroll
        for (int s = 0; s < 4; ++s) {
            B_c[s] = B_1[s]; C_c[s] = C_1[s];
            B_1[s] = B_2[s]; C_1[s] = C_2[s];
        }
    }
}

// ---------------------------------------------------------------------------
// Mean pool over L, then (tiny) classifier head.
// ---------------------------------------------------------------------------
__global__ __launch_bounds__(256) void pool_kernel(
    const float* __restrict__ t, float* __restrict__ pooled)
{
    int idx = blockIdx.x * 256 + threadIdx.x;   // 32*512 = 16384
    int dm = idx & (DMODEL - 1);
    int b = idx >> 9;
    float s = 0.f;
    for (int l = 0; l < LSEQ; ++l)
        s += t[((size_t)(b * LSEQ + l) << 9) + dm];
    pooled[idx] = s * (1.f / (float)LSEQ);
}

__global__ __launch_bounds__(320) void head_kernel(
    const float* __restrict__ pooled, const float* __restrict__ Wh,
    const float* __restrict__ bh, float* __restrict__ out)
{
    int tid = threadIdx.x;
    if (tid >= 320) return;
    int b = tid / 10, o = tid % 10;
    float s = bh[o];
    for (int k = 0; k < DMODEL; ++k)
        s += pooled[b * DMODEL + k] * Wh[o * DMODEL + k];
    out[b * 10 + o] = s;
}

// ---------------------------------------------------------------------------
extern "C" void kernel_launch(void* const* d_in, const int* in_sizes, int n_in,
                              void* d_out, int out_size, void* d_ws, size_t ws_size,
                              hipStream_t stream)
{
    const float* x         = (const float*)d_in[0];
    const float* ln0_g     = (const float*)d_in[1];
    const float* ln0_b     = (const float*)d_in[2];
    const float* W_emb     = (const float*)d_in[3];
    const float* b_emb     = (const float*)d_in[4];
    const float* ln1_g     = (const float*)d_in[5];
    const float* ln1_b     = (const float*)d_in[6];
    const float* in_proj_w = (const float*)d_in[7];
    const float* conv_w    = (const float*)d_in[8];
    const float* conv_b    = (const float*)d_in[9];
    const float* x_proj_w  = (const float*)d_in[10];
    const float* dt_proj_w = (const float*)d_in[11];
    const float* dt_proj_b = (const float*)d_in[12];
    const float* A_log     = (const float*)d_in[13];
    const float* D_p       = (const float*)d_in[14];
    const float* out_proj_w= (const float*)d_in[15];
    const float* blk_ln_g  = (const float*)d_in[16];
    const float* blk_ln_b  = (const float*)d_in[17];
    const float* W_head    = (const float*)d_in[18];
    const float* b_head    = (const float*)d_in[19];

    const int M = BATCHN * LSEQ;   // 6272 rows
    const int NSPLIT = 8;          // x_proj split-K factor (K=1024 -> 128)

    char* ws = (char*)d_ws;
    size_t off = 0;
    auto alloc = [&](size_t bytes) -> void* {
        void* p = (void*)(ws + off);
        off += (bytes + 255) & ~(size_t)255;
        return p;
    };
    float*  tp     = (float*)alloc((size_t)M * PDIM * 4);
    bf16_t* tp_h   = (bf16_t*)alloc((size_t)M * PDIM * 2);
    bf16_t* tp_l   = (bf16_t*)alloc((size_t)M * PDIM * 2);
    float*  t      = (float*)alloc((size_t)M * DMODEL * 4);
    bf16_t* t_h    = (bf16_t*)alloc((size_t)M * DMODEL * 2);
    bf16_t* t_l    = (bf16_t*)alloc((size_t)M * DMODEL * 2);
    float*  xz     = (float*)alloc((size_t)M * 2 * DINNER * 4);
    float*  xc     = (float*)alloc((size_t)M * DINNER * 4);
    float*  xdbl   = (float*)alloc((size_t)M * 64 * 4);
    float*  xdbl_p = (float*)alloc((size_t)NSPLIT * M * 64 * 4);
    float*  dtbuf  = (float*)alloc((size_t)M * DINNER * 4);
    bf16_t* y_h    = (bf16_t*)alloc((size_t)M * DINNER * 2);
    bf16_t* y_l    = (bf16_t*)alloc((size_t)M * DINNER * 2);
    float*  yout   = (float*)alloc((size_t)M * DMODEL * 4);
    float*  pooled = (float*)alloc((size_t)BATCHN * DMODEL * 4);
    const int n_inW  = NLAYER * 2 * DINNER * DMODEL;   // 6,291,456
    const int n_outW = NLAYER * DMODEL * DINNER;       // 3,145,728
    const int n_embW = DMODEL * PDIM;                  // 393,216
    bf16_t* winh  = (bf16_t*)alloc((size_t)n_inW * 2);
    bf16_t* winl  = (bf16_t*)alloc((size_t)n_inW * 2);
    bf16_t* wouth = (bf16_t*)alloc((size_t)n_outW * 2);
    bf16_t* woutl = (bf16_t*)alloc((size_t)n_outW * 2);
    bf16_t* wembh = (bf16_t*)alloc((size_t)n_embW * 2);
    bf16_t* wembl = (bf16_t*)alloc((size_t)n_embW * 2);
    (void)ws_size; (void)in_sizes; (void)n_in; (void)out_size;

    // --- weight splits (hi/lo bf16) ---
    split_kernel<<<(n_inW  + 255) / 256, 256, 0, stream>>>(in_proj_w,  winh,  winl,  n_inW);
    split_kernel<<<(n_outW + 255) / 256, 256, 0, stream>>>(out_proj_w, wouth, woutl, n_outW);
    split_kernel<<<(n_embW + 255) / 256, 256, 0, stream>>>(W_emb,      wembh, wembl, n_embW);

    // --- stem ---
    patchify_kernel<<<(M * PDIM) / 256, 256, 0, stream>>>(x, tp);
    ln_kernel<<<M, 256, 0, stream>>>(tp, nullptr, ln0_g, ln0_b, nullptr, tp_h, tp_l, PDIM);
    gemm_mfma3<<<dim3(DMODEL / 128, M / 128), 256, 0, stream>>>(
        tp_h, tp_l, wembh, wembl, t, b_emb, M, DMODEL, PDIM);
    ln_kernel<<<M, 256, 0, stream>>>(t, nullptr, ln1_g, ln1_b, t, t_h, t_l, DMODEL);

    // --- mamba layers ---
    for (int i = 0; i < NLAYER; ++i) {
        const bf16_t* winh_i  = winh  + (size_t)i * 2 * DINNER * DMODEL;
        const bf16_t* winl_i  = winl  + (size_t)i * 2 * DINNER * DMODEL;
        const bf16_t* wouth_i = wouth + (size_t)i * DMODEL * DINNER;
        const bf16_t* woutl_i = woutl + (size_t)i * DMODEL * DINNER;
        const float* cw   = conv_w    + (size_t)i * DINNER * 4;
        const float* cb   = conv_b    + (size_t)i * DINNER;
        const float* xpW  = x_proj_w  + (size_t)i * 64 * DINNER;
        const float* dtW  = dt_proj_w + (size_t)i * DINNER * RRANK;
        const float* dtB  = dt_proj_b + (size_t)i * DINNER;
        const float* Ali  = A_log     + (size_t)i * DINNER * NSTATE;
        const float* Di   = D_p       + (size_t)i * DINNER;
        const float* bg   = blk_ln_g  + (size_t)i * DMODEL;
        const float* bb   = blk_ln_b  + (size_t)i * DMODEL;

        // xz = t @ inW^T   (6272 x 2048, K=512)  [bf16x3 MFMA]
        gemm_mfma3<<<dim3((2 * DINNER) / 128, M / 128), 256, 0, stream>>>(
            t_h, t_l, winh_i, winl_i, xz, nullptr, M, 2 * DINNER, DMODEL);
        // xc = silu(causal depthwise conv(xs))
        conv_silu_kernel<<<(M * DINNER) / 256, 256, 0, stream>>>(xz, cw, cb, xc);
        // x_dbl = xc @ xpW^T   (6272 x 64, K=1024)  [fp32 vector, split-K=8]
        gemm_nt_splitk<<<dim3(1, M / 64, NSPLIT), 256, 0, stream>>>(
            xc, DINNER, xpW, DINNER, xdbl_p, 64, M, 64, DINNER / NSPLIT);
        reduce_splitk<<<(M * 64 + 255) / 256, 256, 0, stream>>>(
            xdbl_p, xdbl, M * 64, NSPLIT);
        // dt = softplus(x_dbl[:, :32] @ dtW^T + dtB)   (K=32)  [fp32 vector]
        gemm_nt<<<dim3(DINNER / 64, M / 64), 256, 0, stream>>>(
            xdbl, 64, dtW, dtbuf, DINNER, dtB, M, DINNER, RRANK, 1);
        // selective scan + D skip + silu(z); emits y as bf16 hi/lo
        scan_kernel<<<dim3(DINNER / 64, BATCHN), 256, 0, stream>>>(
            xc, dtbuf, xdbl, Ali, Di, xz, y_h, y_l);
        // yout = y @ outW^T   (6272 x 512, K=1024)  [bf16x3 MFMA]
        gemm_mfma3<<<dim3(DMODEL / 128, M / 128), 256, 0, stream>>>(
            y_h, y_l, wouth_i, woutl_i, yout, nullptr, M, DMODEL, DINNER);
        // t = LN(yout + t), plus hi/lo split for next layer's in_proj
        ln_kernel<<<M, 256, 0, stream>>>(yout, t, bg, bb, t, t_h, t_l, DMODEL);
    }

    // --- pool + head ---
    pool_kernel<<<(BATCHN * DMODEL) / 256, 256, 0, stream>>>(t, pooled);
    head_kernel<<<1, 320, 0, stream>>>(pooled, W_head, b_head, (float*)d_out);
}

// Round 6
// 1696.772 us; speedup vs baseline: 2.6987x; 1.0579x over previous
//
#include <hip/hip_runtime.h>
#include <cstdint>
#include <cstddef>

// Problem constants
#define BATCHN 32
#define LSEQ   196     // (224/16)^2
#define DMODEL 512
#define DINNER 1024    // 2*DM
#define PDIM   768     // 3*16*16
#define NSTATE 16
#define RRANK  32
#define NLAYER 6

typedef __bf16 bf16_t;
typedef __bf16 bf16x8 __attribute__((ext_vector_type(8)));
typedef float  f32x4  __attribute__((ext_vector_type(4)));

// async global->LDS, 16B per lane: lane i lands at lds + i*16 bytes.
__device__ __forceinline__ void gl_lds16(const bf16_t* g, bf16_t* l) {
    __builtin_amdgcn_global_load_lds(
        (const __attribute__((address_space(1))) void*)g,
        (__attribute__((address_space(3))) void*)l, 16, 0, 0);
}

// ---------------------------------------------------------------------------
// Split fp32 -> (hi, lo) bf16 pair.  x ~= hi + lo to ~2^-16 relative.
// ---------------------------------------------------------------------------
__global__ __launch_bounds__(256) void split_kernel(
    const float* __restrict__ src, bf16_t* __restrict__ hi,
    bf16_t* __restrict__ lo, int n)
{
    int i = blockIdx.x * 256 + threadIdx.x;
    if (i < n) {
        float x = src[i];
        bf16_t h = (bf16_t)x;
        hi[i] = h;
        lo[i] = (bf16_t)(x - (float)h);
    }
}

// ---------------------------------------------------------------------------
// bf16x3 split-precision MFMA GEMM:  C[M,N] = A[M,K] @ W[N,K]^T (+bias)
// Staging via global_load_lds (16B/lane), XOR-swizzled source chunks.
// Requires M%128==0, N%128==0, K%32==0.
// ---------------------------------------------------------------------------
__global__ __launch_bounds__(256) void gemm_mfma3(
    const bf16_t* __restrict__ Ah, const bf16_t* __restrict__ Al,
    const bf16_t* __restrict__ Wh, const bf16_t* __restrict__ Wl,
    float* __restrict__ C, const float* __restrict__ bias,
    int M, int N, int K)
{
    __shared__ bf16_t sAh[128 * 32];
    __shared__ bf16_t sAl[128 * 32];
    __shared__ bf16_t sBh[128 * 32];
    __shared__ bf16_t sBl[128 * 32];

    const int bm = blockIdx.y * 128;
    const int bn = blockIdx.x * 128;
    const int tid  = threadIdx.x;
    const int lane = tid & 63;
    const int w    = tid >> 6;
    const int wm   = (w & 1) * 64;
    const int wn   = (w >> 1) * 64;

    const int lrow = lane >> 2;
    const int cg8  = ((lane & 3) ^ ((lane >> 3) & 3)) * 8;   // element offset
    const size_t arow = (size_t)(bm + w * 32 + lrow) * K + cg8;
    const size_t brow = (size_t)(bn + w * 32 + lrow) * K + cg8;

    const int fsw = ((lane >> 4) ^ ((lane >> 1) & 3)) * 8;
    const int fr  = lane & 15;

    f32x4 acc[4][4] = {};

    for (int k0 = 0; k0 < K; k0 += 32) {
        __syncthreads();   // all waves done reading previous tile
        #pragma unroll
        for (int j = 0; j < 2; ++j) {
            const size_t ga = arow + (size_t)j * 16 * K + k0;
            const size_t gb = brow + (size_t)j * 16 * K + k0;
            const int lo = w * 1024 + j * 512;   // element offset in LDS
            gl_lds16(Ah + ga, &sAh[lo]);
            gl_lds16(Al + ga, &sAl[lo]);
            gl_lds16(Wh + gb, &sBh[lo]);
            gl_lds16(Wl + gb, &sBl[lo]);
        }
        __syncthreads();   // vmcnt(0) drain: staged tile visible

        bf16x8 afh[4], afl[4];
        #pragma unroll
        for (int mt = 0; mt < 4; ++mt) {
            const int r = wm + mt * 16 + fr;
            afh[mt] = *(const bf16x8*)&sAh[r * 32 + fsw];
            afl[mt] = *(const bf16x8*)&sAl[r * 32 + fsw];
        }
        #pragma unroll
        for (int nt = 0; nt < 4; ++nt) {
            const int r = wn + nt * 16 + fr;
            bf16x8 bfh = *(const bf16x8*)&sBh[r * 32 + fsw];
            bf16x8 bfl = *(const bf16x8*)&sBl[r * 32 + fsw];
            #pragma unroll
            for (int mt = 0; mt < 4; ++mt) {
                acc[mt][nt] = __builtin_amdgcn_mfma_f32_16x16x32_bf16(
                    afh[mt], bfh, acc[mt][nt], 0, 0, 0);
                acc[mt][nt] = __builtin_amdgcn_mfma_f32_16x16x32_bf16(
                    afh[mt], bfl, acc[mt][nt], 0, 0, 0);
                acc[mt][nt] = __builtin_amdgcn_mfma_f32_16x16x32_bf16(
                    afl[mt], bfh, acc[mt][nt], 0, 0, 0);
            }
        }
    }

    // epilogue: C/D layout col=lane&15, row=(lane>>4)*4+reg  [m89-verified]
    const int cr = (lane >> 4) * 4;
    const int cc = lane & 15;
    #pragma unroll
    for (int nt = 0; nt < 4; ++nt) {
        const int n = bn + wn + nt * 16 + cc;
        const float bv = bias ? bias[n] : 0.f;
        #pragma unroll
        for (int mt = 0; mt < 4; ++mt) {
            const int m0 = bm + wm + mt * 16 + cr;
            #pragma unroll
            for (int r = 0; r < 4; ++r)
                C[(size_t)(m0 + r) * N + n] = acc[mt][nt][r] + bv;
        }
    }
}

// ---------------------------------------------------------------------------
// fp32 vector NT GEMM (used for dt_proj: K=32).  C = A@W^T (+bias)(+softplus)
// ---------------------------------------------------------------------------
__global__ __launch_bounds__(256) void gemm_nt(
    const float* __restrict__ A, int lda,
    const float* __restrict__ W,
    float* __restrict__ C, int ldc,
    const float* __restrict__ bias,
    int M, int N, int K, int act)
{
    __shared__ float As[16][64];
    __shared__ float Ws[16][64];
    const int bm = blockIdx.y * 64;
    const int bn = blockIdx.x * 64;
    const int tid = threadIdx.x;
    const int tx = tid & 15;
    const int ty = tid >> 4;
    const int r   = tid >> 2;
    const int kk4 = (tid & 3) << 2;

    float acc[4][4];
    #pragma unroll
    for (int i = 0; i < 4; ++i)
        #pragma unroll
        for (int j = 0; j < 4; ++j) acc[i][j] = 0.f;

    for (int k0 = 0; k0 < K; k0 += 16) {
        float4 va = *(const float4*)(A + (size_t)(bm + r) * lda + k0 + kk4);
        float4 vw = *(const float4*)(W + (size_t)(bn + r) * K   + k0 + kk4);
        __syncthreads();
        As[kk4 + 0][r] = va.x; As[kk4 + 1][r] = va.y;
        As[kk4 + 2][r] = va.z; As[kk4 + 3][r] = va.w;
        Ws[kk4 + 0][r] = vw.x; Ws[kk4 + 1][r] = vw.y;
        Ws[kk4 + 2][r] = vw.z; Ws[kk4 + 3][r] = vw.w;
        __syncthreads();
        #pragma unroll
        for (int kk = 0; kk < 16; ++kk) {
            float4 a = *(const float4*)&As[kk][ty << 2];
            float4 b = *(const float4*)&Ws[kk][tx << 2];
            acc[0][0] += a.x * b.x; acc[0][1] += a.x * b.y;
            acc[0][2] += a.x * b.z; acc[0][3] += a.x * b.w;
            acc[1][0] += a.y * b.x; acc[1][1] += a.y * b.y;
            acc[1][2] += a.y * b.z; acc[1][3] += a.y * b.w;
            acc[2][0] += a.z * b.x; acc[2][1] += a.z * b.y;
            acc[2][2] += a.z * b.z; acc[2][3] += a.z * b.w;
            acc[3][0] += a.w * b.x; acc[3][1] += a.w * b.y;
            acc[3][2] += a.w * b.z; acc[3][3] += a.w * b.w;
        }
    }

    #pragma unroll
    for (int i = 0; i < 4; ++i) {
        const int m = bm + (ty << 2) + i;
        #pragma unroll
        for (int j = 0; j < 4; ++j) {
            const int n = bn + (tx << 2) + j;
            float v = acc[i][j];
            if (bias) v += bias[n];
            if (act == 1) {
                v = (v > 20.f) ? v : log1pf(expf(v));
            }
            C[(size_t)m * ldc + n] = v;
        }
    }
}

// ---------------------------------------------------------------------------
// Split-K variant for the narrow x_proj GEMM (N=64): grid.z = K-split index.
// ---------------------------------------------------------------------------
__global__ __launch_bounds__(256) void gemm_nt_splitk(
    const float* __restrict__ A, int lda,
    const float* __restrict__ W, int ldw,
    float* __restrict__ Cpart, int ldc,
    int M, int N, int kchunk)
{
    __shared__ float As[16][64];
    __shared__ float Ws[16][64];
    const int bm = blockIdx.y * 64;
    const int bn = blockIdx.x * 64;
    const int kb = blockIdx.z * kchunk;
    Cpart += (size_t)blockIdx.z * M * ldc;

    const int tid = threadIdx.x;
    const int tx = tid & 15;
    const int ty = tid >> 4;
    const int r   = tid >> 2;
    const int kk4 = (tid & 3) << 2;

    float acc[4][4];
    #pragma unroll
    for (int i = 0; i < 4; ++i)
        #pragma unroll
        for (int j = 0; j < 4; ++j) acc[i][j] = 0.f;

    for (int k0 = kb; k0 < kb + kchunk; k0 += 16) {
        float4 va = *(const float4*)(A + (size_t)(bm + r) * lda + k0 + kk4);
        float4 vw = *(const float4*)(W + (size_t)(bn + r) * ldw + k0 + kk4);
        __syncthreads();
        As[kk4 + 0][r] = va.x; As[kk4 + 1][r] = va.y;
        As[kk4 + 2][r] = va.z; As[kk4 + 3][r] = va.w;
        Ws[kk4 + 0][r] = vw.x; Ws[kk4 + 1][r] = vw.y;
        Ws[kk4 + 2][r] = vw.z; Ws[kk4 + 3][r] = vw.w;
        __syncthreads();
        #pragma unroll
        for (int kk = 0; kk < 16; ++kk) {
            float4 a = *(const float4*)&As[kk][ty << 2];
            float4 b = *(const float4*)&Ws[kk][tx << 2];
            acc[0][0] += a.x * b.x; acc[0][1] += a.x * b.y;
            acc[0][2] += a.x * b.z; acc[0][3] += a.x * b.w;
            acc[1][0] += a.y * b.x; acc[1][1] += a.y * b.y;
            acc[1][2] += a.y * b.z; acc[1][3] += a.y * b.w;
            acc[2][0] += a.z * b.x; acc[2][1] += a.z * b.y;
            acc[2][2] += a.z * b.z; acc[2][3] += a.z * b.w;
            acc[3][0] += a.w * b.x; acc[3][1] += a.w * b.y;
            acc[3][2] += a.w * b.z; acc[3][3] += a.w * b.w;
        }
    }

    #pragma unroll
    for (int i = 0; i < 4; ++i) {
        const int m = bm + (ty << 2) + i;
        #pragma unroll
        for (int j = 0; j < 4; ++j) {
            const int n = bn + (tx << 2) + j;
            Cpart[(size_t)m * ldc + n] = acc[i][j];
        }
    }
}

__global__ __launch_bounds__(256) void reduce_splitk(
    const float* __restrict__ part, float* __restrict__ out, int n, int nsplit)
{
    int i = blockIdx.x * 256 + threadIdx.x;
    if (i < n) {
        float s = 0.f;
        for (int j = 0; j < nsplit; ++j) s += part[(size_t)j * n + i];
        out[i] = s;
    }
}

// ---------------------------------------------------------------------------
// Patchify: x (B,3,224,224) -> tp (B, 196, 768), pd = c*256 + p1*16 + p2
// ---------------------------------------------------------------------------
__global__ __launch_bounds__(256) void patchify_kernel(
    const float* __restrict__ x, float* __restrict__ tp)
{
    int idx = blockIdx.x * 256 + threadIdx.x;   // B*L*PD = 4,816,896
    int pd = idx % PDIM;
    int bl = idx / PDIM;
    int l = bl % LSEQ, b = bl / LSEQ;
    int c = pd >> 8, rem = pd & 255, p1 = rem >> 4, p2 = rem & 15;
    int gh = l / 14, gw = l % 14;
    int hh = gh * 16 + p1, ww = gw * 16 + p2;
    tp[idx] = x[(((size_t)b * 3 + c) * 224 + hh) * 224 + ww];
}

// ---------------------------------------------------------------------------
// LayerNorm over last dim W (512 or 768). Optional residual; optional fp32
// output; optional (hi,lo) bf16-split output for the following MFMA GEMM.
// ---------------------------------------------------------------------------
__global__ __launch_bounds__(256) void ln_kernel(
    const float* __restrict__ in, const float* __restrict__ res,
    const float* __restrict__ g, const float* __restrict__ bt,
    float* __restrict__ out, bf16_t* __restrict__ hi,
    bf16_t* __restrict__ lo, int W)
{
    __shared__ float red[4];
    const int row = blockIdx.x;
    const size_t base = (size_t)row * W;
    const int nper = W >> 8;      // 2 or 3
    float vals[3];
    float s = 0.f;
    for (int j = 0; j < nper; ++j) {
        int c = (j << 8) + threadIdx.x;
        float v = in[base + c];
        if (res) v += res[base + c];
        vals[j] = v;
        s += v;
    }
    int lane = threadIdx.x & 63, wid = threadIdx.x >> 6;
    #pragma unroll
    for (int o = 32; o > 0; o >>= 1) s += __shfl_down(s, o);
    if (lane == 0) red[wid] = s;
    __syncthreads();
    float mu = (red[0] + red[1] + red[2] + red[3]) / (float)W;
    __syncthreads();
    float vs = 0.f;
    for (int j = 0; j < nper; ++j) { float d = vals[j] - mu; vs += d * d; }
    #pragma unroll
    for (int o = 32; o > 0; o >>= 1) vs += __shfl_down(vs, o);
    if (lane == 0) red[wid] = vs;
    __syncthreads();
    float var = (red[0] + red[1] + red[2] + red[3]) / (float)W;
    float rstd = rsqrtf(var + 1e-5f);
    for (int j = 0; j < nper; ++j) {
        int c = (j << 8) + threadIdx.x;
        float v = (vals[j] - mu) * rstd * g[c] + bt[c];
        if (out) out[base + c] = v;
        if (hi) {
            bf16_t h = (bf16_t)v;
            hi[base + c] = h;
            lo[base + c] = (bf16_t)(v - (float)h);
        }
    }
}

// ---------------------------------------------------------------------------
// Causal depthwise conv (K=4) + SiLU, float4-vectorized over channels.
// xs = first half of xz (row stride 2048).
// ---------------------------------------------------------------------------
__global__ __launch_bounds__(256) void conv_silu_kernel(
    const float* __restrict__ xz, const float* __restrict__ cw,
    const float* __restrict__ cb, float* __restrict__ xc)
{
    int idx = blockIdx.x * 256 + threadIdx.x;  // B*L*(DINNER/4) = 1,605,632
    int d4 = idx & 255;
    int bl = idx >> 8;
    int l = bl % LSEQ, b = bl / LSEQ;
    int d = d4 << 2;

    float4 w0 = *(const float4*)(cw + (size_t)(d + 0) * 4);
    float4 w1 = *(const float4*)(cw + (size_t)(d + 1) * 4);
    float4 w2 = *(const float4*)(cw + (size_t)(d + 2) * 4);
    float4 w3 = *(const float4*)(cw + (size_t)(d + 3) * 4);
    float4 acc = *(const float4*)(cb + d);

    const float* base = xz + ((size_t)(b * LSEQ) << 11) + d;
    #pragma unroll
    for (int k = 0; k < 4; ++k) {
        int ls = l + k - 3;
        if (ls >= 0) {
            float4 xv = *(const float4*)(base + ((size_t)ls << 11));
            const float wk0 = (&w0.x)[k], wk1 = (&w1.x)[k];
            const float wk2 = (&w2.x)[k], wk3 = (&w3.x)[k];
            acc.x += wk0 * xv.x; acc.y += wk1 * xv.y;
            acc.z += wk2 * xv.z; acc.w += wk3 * xv.w;
        }
    }
    acc.x = acc.x * __builtin_amdgcn_rcpf(1.f + __expf(-acc.x));
    acc.y = acc.y * __builtin_amdgcn_rcpf(1.f + __expf(-acc.y));
    acc.z = acc.z * __builtin_amdgcn_rcpf(1.f + __expf(-acc.z));
    acc.w = acc.w * __builtin_amdgcn_rcpf(1.f + __expf(-acc.w));
    *(float4*)(xc + ((size_t)bl << 10) + d) = acc;
}

// ---------------------------------------------------------------------------
// quad broadcast: all 4 lanes of a quad get lane J's value (DPP quad_perm).
// ---------------------------------------------------------------------------
template<int J>
__device__ __forceinline__ float qbcast(float v) {
    constexpr int ctrl = J | (J << 2) | (J << 4) | (J << 6);
    return __int_as_float(__builtin_amdgcn_mov_dpp(
        __float_as_int(v), ctrl, 0xF, 0xF, true));
}

// ---------------------------------------------------------------------------
// Selective scan v6: state-parallel (4 lanes/channel), group-4 steps.
// B/C rows depend only on (b,l) — shared by all 64 channels of the block.
// Each wave stages a whole group's B/C (4 rows x 256B = 1KB) with ONE float4
// global load per lane into a wave-PRIVATE LDS region (no __syncthreads —
// DS ops are wave-ordered, so no vmcnt(0) barrier drain). Per-step B/C are
// ds_read_b128 broadcasts (same addr across the 16 channel-quads, conflict-
// free). Scalars dt/xc/z: depth-2 register pipeline, quad-DPP broadcast.
// Row staging runs depth-2 (load g+3, write g+2, compute g).
// ---------------------------------------------------------------------------
__global__ __launch_bounds__(256, 1) void scan_kernel(
    const float* __restrict__ xc, const float* __restrict__ dt,
    const float* __restrict__ xdbl, const float* __restrict__ A_log,
    const float* __restrict__ Dv, const float* __restrict__ xz,
    bf16_t* __restrict__ yh, bf16_t* __restrict__ yl)
{
    __shared__ float sBC[4][2][256];   // [wave][buf][4 steps x 64 floats]

    const int b    = blockIdx.y;
    const int tid  = threadIdx.x;
    const int lane = tid & 63;
    const int w    = tid >> 6;
    const int q    = tid >> 2;        // channel within block (0..63)
    const int sub  = tid & 3;         // state group: states [4*sub, 4*sub+4)
    const int d    = blockIdx.x * 64 + q;

    float A2[4], h[4];
    #pragma unroll
    for (int n = 0; n < 4; ++n) {
        // fold log2(e) so dA = exp2(dtv*A2[n]) is a bare v_exp_f32
        A2[n] = -__expf(A_log[d * NSTATE + sub * 4 + n]) * 1.44269504f;
        h[n] = 0.f;
    }
    const float Dval = Dv[d];
    const size_t bL = (size_t)b * LSEQ;

    // per-lane scalar streams: lane sub owns step 4g+sub's scalars
    const float* pdt = dt + (bL + sub) * DINNER + d;
    const float* pxc = xc + (bL + sub) * DINNER + d;
    const float* pz  = xz + ((bL + sub) << 11) + DINNER + d;

    // B/C row staging: lane covers step (lane>>4), floats [(lane&15)*4, +4)
    const float* xrow = xdbl + bL * 64;
    const int roff = (lane >> 4) * 64 + (lane & 15) * 4;
    float* lds0 = &sBC[w][0][0];
    float* lds1 = &sBC[w][1][0];

    // preload: groups 0,1 -> LDS; group 2 row -> reg; scalars depth-2
    float4 r0 = *(const float4*)(xrow + roff);
    float4 r1 = *(const float4*)(xrow + 256 + roff);
    float4 rowreg = *(const float4*)(xrow + 512 + roff);
    *(float4*)(lds0 + roff) = r0;
    *(float4*)(lds1 + roff) = r1;

    float dt_c = pdt[0];          float xc_c = pxc[0];          float z_c = pz[0];
    float dt_1 = pdt[4 * DINNER]; float xc_1 = pxc[4 * DINNER]; float z_1 = pz[4 * 2048];

    for (int g = 0; g < 49; ++g) {
        // issue row load for group g+3 and scalar loads for group g+2
        const int gl  = (g + 3 <= 48) ? g + 3 : 48;
        float4 rownext = *(const float4*)(xrow + gl * 256 + roff);
        const int adv = (g < 47) ? 2 : (48 - g);
        float dt_2 = pdt[(size_t)adv * 4 * DINNER];
        float xc_2 = pxc[(size_t)adv * 4 * DINNER];
        float z_2  = pz[(size_t)adv * 4 * 2048];

        const float* Bbuf = (g & 1) ? lds1 : lds0;
        float acc_keep = 0.f;

#define SCAN_STEP(J) do {                                                     \
        float4 Bv = *(const float4*)&Bbuf[(J) * 64 + 32 + 4 * sub];           \
        float4 Cv = *(const float4*)&Bbuf[(J) * 64 + 48 + 4 * sub];           \
        float dtv = qbcast<J>(dt_c);                                          \
        float xv  = qbcast<J>(xc_c);                                          \
        float dtx = dtv * xv;                                                 \
        h[0] = exp2f(dtv * A2[0]) * h[0] + dtx * Bv.x;                        \
        h[1] = exp2f(dtv * A2[1]) * h[1] + dtx * Bv.y;                        \
        h[2] = exp2f(dtv * A2[2]) * h[2] + dtx * Bv.z;                        \
        h[3] = exp2f(dtv * A2[3]) * h[3] + dtx * Bv.w;                        \
        float acc = h[0] * Cv.x + h[1] * Cv.y + h[2] * Cv.z + h[3] * Cv.w;    \
        acc += __shfl_xor(acc, 1);                                            \
        acc += __shfl_xor(acc, 2);                                            \
        acc_keep = (sub == (J)) ? acc : acc_keep;                             \
    } while (0)

        SCAN_STEP(0);
        SCAN_STEP(1);
        SCAN_STEP(2);
        SCAN_STEP(3);
#undef SCAN_STEP

        // batched store: lane sub writes step 4g+sub (uses its OWN xc/z)
        {
            float yv = acc_keep + xc_c * Dval;
            float sz = z_c * __builtin_amdgcn_rcpf(1.f + __expf(-z_c));
            float o  = yv * sz;
            bf16_t ho = (bf16_t)o;
            const size_t oi = (bL + 4 * (size_t)g + sub) * DINNER + d;
            yh[oi] = ho;
            yl[oi] = (bf16_t)(o - (float)ho);
        }

        // write group g+2's row into the buffer we just finished reading
        // (same-wave DS ordering guarantees reads-before-write)
        *(float4*)(((g & 1) ? lds1 : lds0) + roff) = rowreg;
        rowreg = rownext;

        pdt += 4 * DINNER; pxc += 4 * DINNER; pz += 4 * 2048;
        dt_c = dt_1; xc_c = xc_1; z_c = z_1;
        dt_1 = dt_2; xc_1 = xc_2; z_1 = z_2;
    }
}

// ---------------------------------------------------------------------------
// Mean pool over L, then (tiny) classifier head.
// ---------------------------------------------------------------------------
__global__ __launch_bounds__(256) void pool_kernel(
    const float* __restrict__ t, float* __restrict__ pooled)
{
    int idx = blockIdx.x * 256 + threadIdx.x;   // 32*512 = 16384
    int dm = idx & (DMODEL - 1);
    int b = idx >> 9;
    float s = 0.f;
    for (int l = 0; l < LSEQ; ++l)
        s += t[((size_t)(b * LSEQ + l) << 9) + dm];
    pooled[idx] = s * (1.f / (float)LSEQ);
}

__global__ __launch_bounds__(320) void head_kernel(
    const float* __restrict__ pooled, const float* __restrict__ Wh,
    const float* __restrict__ bh, float* __restrict__ out)
{
    int tid = threadIdx.x;
    if (tid >= 320) return;
    int b = tid / 10, o = tid % 10;
    float s = bh[o];
    for (int k = 0; k < DMODEL; ++k)
        s += pooled[b * DMODEL + k] * Wh[o * DMODEL + k];
    out[b * 10 + o] = s;
}

// ---------------------------------------------------------------------------
extern "C" void kernel_launch(void* const* d_in, const int* in_sizes, int n_in,
                              void* d_out, int out_size, void* d_ws, size_t ws_size,
                              hipStream_t stream)
{
    const float* x         = (const float*)d_in[0];
    const float* ln0_g     = (const float*)d_in[1];
    const float* ln0_b     = (const float*)d_in[2];
    const float* W_emb     = (const float*)d_in[3];
    const float* b_emb     = (const float*)d_in[4];
    const float* ln1_g     = (const float*)d_in[5];
    const float* ln1_b     = (const float*)d_in[6];
    const float* in_proj_w = (const float*)d_in[7];
    const float* conv_w    = (const float*)d_in[8];
    const float* conv_b    = (const float*)d_in[9];
    const float* x_proj_w  = (const float*)d_in[10];
    const float* dt_proj_w = (const float*)d_in[11];
    const float* dt_proj_b = (const float*)d_in[12];
    const float* A_log     = (const float*)d_in[13];
    const float* D_p       = (const float*)d_in[14];
    const float* out_proj_w= (const float*)d_in[15];
    const float* blk_ln_g  = (const float*)d_in[16];
    const float* blk_ln_b  = (const float*)d_in[17];
    const float* W_head    = (const float*)d_in[18];
    const float* b_head    = (const float*)d_in[19];

    const int M = BATCHN * LSEQ;   // 6272 rows
    const int NSPLIT = 8;          // x_proj split-K factor (K=1024 -> 128)

    char* ws = (char*)d_ws;
    size_t off = 0;
    auto alloc = [&](size_t bytes) -> void* {
        void* p = (void*)(ws + off);
        off += (bytes + 255) & ~(size_t)255;
        return p;
    };
    float*  tp     = (float*)alloc((size_t)M * PDIM * 4);
    bf16_t* tp_h   = (bf16_t*)alloc((size_t)M * PDIM * 2);
    bf16_t* tp_l   = (bf16_t*)alloc((size_t)M * PDIM * 2);
    float*  t      = (float*)alloc((size_t)M * DMODEL * 4);
    bf16_t* t_h    = (bf16_t*)alloc((size_t)M * DMODEL * 2);
    bf16_t* t_l    = (bf16_t*)alloc((size_t)M * DMODEL * 2);
    float*  xz     = (float*)alloc((size_t)M * 2 * DINNER * 4);
    float*  xc     = (float*)alloc((size_t)M * DINNER * 4);
    float*  xdbl   = (float*)alloc((size_t)M * 64 * 4);
    float*  xdbl_p = (float*)alloc((size_t)NSPLIT * M * 64 * 4);
    float*  dtbuf  = (float*)alloc((size_t)M * DINNER * 4);
    bf16_t* y_h    = (bf16_t*)alloc((size_t)M * DINNER * 2);
    bf16_t* y_l    = (bf16_t*)alloc((size_t)M * DINNER * 2);
    float*  yout   = (float*)alloc((size_t)M * DMODEL * 4);
    float*  pooled = (float*)alloc((size_t)BATCHN * DMODEL * 4);
    const int n_inW  = NLAYER * 2 * DINNER * DMODEL;   // 6,291,456
    const int n_outW = NLAYER * DMODEL * DINNER;       // 3,145,728
    const int n_embW = DMODEL * PDIM;                  // 393,216
    bf16_t* winh  = (bf16_t*)alloc((size_t)n_inW * 2);
    bf16_t* winl  = (bf16_t*)alloc((size_t)n_inW * 2);
    bf16_t* wouth = (bf16_t*)alloc((size_t)n_outW * 2);
    bf16_t* woutl = (bf16_t*)alloc((size_t)n_outW * 2);
    bf16_t* wembh = (bf16_t*)alloc((size_t)n_embW * 2);
    bf16_t* wembl = (bf16_t*)alloc((size_t)n_embW * 2);
    (void)ws_size; (void)in_sizes; (void)n_in; (void)out_size;

    // --- weight splits (hi/lo bf16) ---
    split_kernel<<<(n_inW  + 255) / 256, 256, 0, stream>>>(in_proj_w,  winh,  winl,  n_inW);
    split_kernel<<<(n_outW + 255) / 256, 256, 0, stream>>>(out_proj_w, wouth, woutl, n_outW);
    split_kernel<<<(n_embW + 255) / 256, 256, 0, stream>>>(W_emb,      wembh, wembl, n_embW);

    // --- stem ---
    patchify_kernel<<<(M * PDIM) / 256, 256, 0, stream>>>(x, tp);
    ln_kernel<<<M, 256, 0, stream>>>(tp, nullptr, ln0_g, ln0_b, nullptr, tp_h, tp_l, PDIM);
    gemm_mfma3<<<dim3(DMODEL / 128, M / 128), 256, 0, stream>>>(
        tp_h, tp_l, wembh, wembl, t, b_emb, M, DMODEL, PDIM);
    ln_kernel<<<M, 256, 0, stream>>>(t, nullptr, ln1_g, ln1_b, t, t_h, t_l, DMODEL);

    // --- mamba layers ---
    for (int i = 0; i < NLAYER; ++i) {
        const bf16_t* winh_i  = winh  + (size_t)i * 2 * DINNER * DMODEL;
        const bf16_t* winl_i  = winl  + (size_t)i * 2 * DINNER * DMODEL;
        const bf16_t* wouth_i = wouth + (size_t)i * DMODEL * DINNER;
        const bf16_t* woutl_i = woutl + (size_t)i * DMODEL * DINNER;
        const float* cw   = conv_w    + (size_t)i * DINNER * 4;
        const float* cb   = conv_b    + (size_t)i * DINNER;
        const float* xpW  = x_proj_w  + (size_t)i * 64 * DINNER;
        const float* dtW  = dt_proj_w + (size_t)i * DINNER * RRANK;
        const float* dtB  = dt_proj_b + (size_t)i * DINNER;
        const float* Ali  = A_log     + (size_t)i * DINNER * NSTATE;
        const float* Di   = D_p       + (size_t)i * DINNER;
        const float* bg   = blk_ln_g  + (size_t)i * DMODEL;
        const float* bb   = blk_ln_b  + (size_t)i * DMODEL;

        // xz = t @ inW^T   (6272 x 2048, K=512)  [bf16x3 MFMA]
        gemm_mfma3<<<dim3((2 * DINNER) / 128, M / 128), 256, 0, stream>>>(
            t_h, t_l, winh_i, winl_i, xz, nullptr, M, 2 * DINNER, DMODEL);
        // xc = silu(causal depthwise conv(xs))  [float4 over channels]
        conv_silu_kernel<<<(M * DINNER / 4) / 256, 256, 0, stream>>>(xz, cw, cb, xc);
        // x_dbl = xc @ xpW^T   (6272 x 64, K=1024)  [fp32 vector, split-K=8]
        gemm_nt_splitk<<<dim3(1, M / 64, NSPLIT), 256, 0, stream>>>(
            xc, DINNER, xpW, DINNER, xdbl_p, 64, M, 64, DINNER / NSPLIT);
        reduce_splitk<<<(M * 64 + 255) / 256, 256, 0, stream>>>(
            xdbl_p, xdbl, M * 64, NSPLIT);
        // dt = softplus(x_dbl[:, :32] @ dtW^T + dtB)   (K=32)  [fp32 vector]
        gemm_nt<<<dim3(DINNER / 64, M / 64), 256, 0, stream>>>(
            xdbl, 64, dtW, dtbuf, DINNER, dtB, M, DINNER, RRANK, 1);
        // selective scan + D skip + silu(z); emits y as bf16 hi/lo
        scan_kernel<<<dim3(DINNER / 64, BATCHN), 256, 0, stream>>>(
            xc, dtbuf, xdbl, Ali, Di, xz, y_h, y_l);
        // yout = y @ outW^T   (6272 x 512, K=1024)  [bf16x3 MFMA]
        gemm_mfma3<<<dim3(DMODEL / 128, M / 128), 256, 0, stream>>>(
            y_h, y_l, wouth_i, woutl_i, yout, nullptr, M, DMODEL, DINNER);
        // t = LN(yout + t), plus hi/lo split for next layer's in_proj
        ln_kernel<<<M, 256, 0, stream>>>(yout, t, bg, bb, t, t_h, t_l, DMODEL);
    }

    // --- pool + head ---
    pool_kernel<<<(BATCHN * DMODEL) / 256, 256, 0, stream>>>(t, pooled);
    head_kernel<<<1, 320, 0, stream>>>(pooled, W_head, b_head, (float*)d_out);
}

// Round 8
// 1544.330 us; speedup vs baseline: 2.9651x; 1.0987x over previous
//
#include <hip/hip_runtime.h>
#include <cstdint>
#include <cstddef>

// Problem constants
#define BATCHN 32
#define LSEQ   196     // (224/16)^2
#define DMODEL 512
#define DINNER 1024    // 2*DM
#define PDIM   768     // 3*16*16
#define NSTATE 16
#define RRANK  32
#define NLAYER 6

typedef __bf16 bf16_t;
typedef __bf16 bf16x8 __attribute__((ext_vector_type(8)));
typedef float  f32x4  __attribute__((ext_vector_type(4)));

// async global->LDS, 16B per lane: lane i lands at lds + i*16 bytes.
__device__ __forceinline__ void gl_lds16(const bf16_t* g, bf16_t* l) {
    __builtin_amdgcn_global_load_lds(
        (const __attribute__((address_space(1))) void*)g,
        (__attribute__((address_space(3))) void*)l, 16, 0, 0);
}

// ---------------------------------------------------------------------------
// Split fp32 -> (hi, lo) bf16 pair.  x ~= hi + lo to ~2^-16 relative.
// ---------------------------------------------------------------------------
__global__ __launch_bounds__(256) void split_kernel(
    const float* __restrict__ src, bf16_t* __restrict__ hi,
    bf16_t* __restrict__ lo, int n)
{
    int i = blockIdx.x * 256 + threadIdx.x;
    if (i < n) {
        float x = src[i];
        bf16_t h = (bf16_t)x;
        hi[i] = h;
        lo[i] = (bf16_t)(x - (float)h);
    }
}

// ---------------------------------------------------------------------------
// bf16x3 split-precision MFMA GEMM:  C = A[M,K] @ W[N,K]^T (+bias)
// Pipelined: sA single-buffered (A-frags live in regs across the stage),
// sB double-buffered (read inline during MFMA). Per K-iter:
//   barrier(vmcnt drain, covered by prev iter's 48 MFMAs) -> ds_read A-frags
//   -> cheap barrier -> issue gl_lds(k+1) -> MFMA + inline B ds_reads.
// LDS 48KB -> 3 blocks/CU. Optional split-K via gridDim.z: each z computes
// K/gridDim.z and writes partials to C + z*M*N (summed by the next LN).
// Requires M%128==0, N%128==0, (K/gridDim.z)%32==0.
// ---------------------------------------------------------------------------
__global__ __launch_bounds__(256) void gemm_mfma3(
    const bf16_t* __restrict__ Ah, const bf16_t* __restrict__ Al,
    const bf16_t* __restrict__ Wh, const bf16_t* __restrict__ Wl,
    float* __restrict__ C, const float* __restrict__ bias,
    int M, int N, int K)
{
    __shared__ bf16_t sAh[128 * 32];
    __shared__ bf16_t sAl[128 * 32];
    __shared__ bf16_t sBh[2][128 * 32];
    __shared__ bf16_t sBl[2][128 * 32];

    const int bm = blockIdx.y * 128;
    const int bn = blockIdx.x * 128;
    const int kchunk = K / gridDim.z;
    const int kb = blockIdx.z * kchunk;
    C += (size_t)blockIdx.z * M * N;

    const int tid  = threadIdx.x;
    const int lane = tid & 63;
    const int w    = tid >> 6;
    const int wm   = (w & 1) * 64;
    const int wn   = (w >> 1) * 64;

    const int lrow = lane >> 2;
    const int cg8  = ((lane & 3) ^ ((lane >> 3) & 3)) * 8;   // element offset
    const size_t arow = (size_t)(bm + w * 32 + lrow) * K + cg8;
    const size_t brow = (size_t)(bn + w * 32 + lrow) * K + cg8;

    const int fsw = ((lane >> 4) ^ ((lane >> 1) & 3)) * 8;
    const int fr  = lane & 15;
    const int llo = w * 1024;          // this wave's LDS staging base

    f32x4 acc[4][4] = {};

    // prologue: stage tile 0
    #pragma unroll
    for (int j = 0; j < 2; ++j) {
        gl_lds16(Ah + arow + (size_t)j * 16 * K + kb, &sAh[llo + j * 512]);
        gl_lds16(Al + arow + (size_t)j * 16 * K + kb, &sAl[llo + j * 512]);
        gl_lds16(Wh + brow + (size_t)j * 16 * K + kb, &sBh[0][llo + j * 512]);
        gl_lds16(Wl + brow + (size_t)j * 16 * K + kb, &sBl[0][llo + j * 512]);
    }

    const int kiter = kchunk / 32;
    for (int ki = 0; ki < kiter; ++ki) {
        const int buf = ki & 1;
        __syncthreads();   // vmcnt(0) drain of stage(ki) — covered by MFMAs

        // A fragments -> registers (sA about to be overwritten)
        bf16x8 afh[4], afl[4];
        #pragma unroll
        for (int mt = 0; mt < 4; ++mt) {
            const int r = wm + mt * 16 + fr;
            afh[mt] = *(const bf16x8*)&sAh[r * 32 + fsw];
            afl[mt] = *(const bf16x8*)&sAl[r * 32 + fsw];
        }
        __syncthreads();   // all waves done with sA (cheap lgkm drain)

        if (ki + 1 < kiter) {
            const int k0 = kb + (ki + 1) * 32;
            #pragma unroll
            for (int j = 0; j < 2; ++j) {
                gl_lds16(Ah + arow + (size_t)j * 16 * K + k0, &sAh[llo + j * 512]);
                gl_lds16(Al + arow + (size_t)j * 16 * K + k0, &sAl[llo + j * 512]);
                gl_lds16(Wh + brow + (size_t)j * 16 * K + k0, &sBh[buf ^ 1][llo + j * 512]);
                gl_lds16(Wl + brow + (size_t)j * 16 * K + k0, &sBl[buf ^ 1][llo + j * 512]);
            }
        }

        // MFMA block with inline B reads from the stable sB[buf]
        #pragma unroll
        for (int nt = 0; nt < 4; ++nt) {
            const int r = wn + nt * 16 + fr;
            bf16x8 bfh = *(const bf16x8*)&sBh[buf][r * 32 + fsw];
            bf16x8 bfl = *(const bf16x8*)&sBl[buf][r * 32 + fsw];
            #pragma unroll
            for (int mt = 0; mt < 4; ++mt) {
                acc[mt][nt] = __builtin_amdgcn_mfma_f32_16x16x32_bf16(
                    afh[mt], bfh, acc[mt][nt], 0, 0, 0);
                acc[mt][nt] = __builtin_amdgcn_mfma_f32_16x16x32_bf16(
                    afh[mt], bfl, acc[mt][nt], 0, 0, 0);
                acc[mt][nt] = __builtin_amdgcn_mfma_f32_16x16x32_bf16(
                    afl[mt], bfh, acc[mt][nt], 0, 0, 0);
            }
        }
    }

    // epilogue: C/D layout col=lane&15, row=(lane>>4)*4+reg  [m89-verified]
    const int cr = (lane >> 4) * 4;
    const int cc = lane & 15;
    #pragma unroll
    for (int nt = 0; nt < 4; ++nt) {
        const int n = bn + wn + nt * 16 + cc;
        const float bv = bias ? bias[n] : 0.f;
        #pragma unroll
        for (int mt = 0; mt < 4; ++mt) {
            const int m0 = bm + wm + mt * 16 + cr;
            #pragma unroll
            for (int r = 0; r < 4; ++r)
                C[(size_t)(m0 + r) * N + n] = acc[mt][nt][r] + bv;
        }
    }
}

// ---------------------------------------------------------------------------
// fp32 vector NT GEMM (used for dt_proj: K=32).  C = A@W^T (+bias)(+softplus)
// ---------------------------------------------------------------------------
__global__ __launch_bounds__(256) void gemm_nt(
    const float* __restrict__ A, int lda,
    const float* __restrict__ W,
    float* __restrict__ C, int ldc,
    const float* __restrict__ bias,
    int M, int N, int K, int act)
{
    __shared__ float As[16][64];
    __shared__ float Ws[16][64];
    const int bm = blockIdx.y * 64;
    const int bn = blockIdx.x * 64;
    const int tid = threadIdx.x;
    const int tx = tid & 15;
    const int ty = tid >> 4;
    const int r   = tid >> 2;
    const int kk4 = (tid & 3) << 2;

    float acc[4][4];
    #pragma unroll
    for (int i = 0; i < 4; ++i)
        #pragma unroll
        for (int j = 0; j < 4; ++j) acc[i][j] = 0.f;

    for (int k0 = 0; k0 < K; k0 += 16) {
        float4 va = *(const float4*)(A + (size_t)(bm + r) * lda + k0 + kk4);
        float4 vw = *(const float4*)(W + (size_t)(bn + r) * K   + k0 + kk4);
        __syncthreads();
        As[kk4 + 0][r] = va.x; As[kk4 + 1][r] = va.y;
        As[kk4 + 2][r] = va.z; As[kk4 + 3][r] = va.w;
        Ws[kk4 + 0][r] = vw.x; Ws[kk4 + 1][r] = vw.y;
        Ws[kk4 + 2][r] = vw.z; Ws[kk4 + 3][r] = vw.w;
        __syncthreads();
        #pragma unroll
        for (int kk = 0; kk < 16; ++kk) {
            float4 a = *(const float4*)&As[kk][ty << 2];
            float4 b = *(const float4*)&Ws[kk][tx << 2];
            acc[0][0] += a.x * b.x; acc[0][1] += a.x * b.y;
            acc[0][2] += a.x * b.z; acc[0][3] += a.x * b.w;
            acc[1][0] += a.y * b.x; acc[1][1] += a.y * b.y;
            acc[1][2] += a.y * b.z; acc[1][3] += a.y * b.w;
            acc[2][0] += a.z * b.x; acc[2][1] += a.z * b.y;
            acc[2][2] += a.z * b.z; acc[2][3] += a.z * b.w;
            acc[3][0] += a.w * b.x; acc[3][1] += a.w * b.y;
            acc[3][2] += a.w * b.z; acc[3][3] += a.w * b.w;
        }
    }

    #pragma unroll
    for (int i = 0; i < 4; ++i) {
        const int m = bm + (ty << 2) + i;
        #pragma unroll
        for (int j = 0; j < 4; ++j) {
            const int n = bn + (tx << 2) + j;
            float v = acc[i][j];
            if (bias) v += bias[n];
            if (act == 1) {
                v = (v > 20.f) ? v : log1pf(expf(v));
            }
            C[(size_t)m * ldc + n] = v;
        }
    }
}

// ---------------------------------------------------------------------------
// FUSED conv+silu+x_proj split-K.  Computes xc = silu(causal depthwise
// conv(xs)) inline while staging the A-tile, writes xc once (for the scan),
// and accumulates the x_proj partial GEMM (N=64).  grid=(1, M/64, NSPLIT).
// Each split z covers channels [z*kchunk, (z+1)*kchunk) — every xc element
// is computed exactly once across the grid.
// ---------------------------------------------------------------------------
__global__ __launch_bounds__(256) void conv_xproj_kernel(
    const float* __restrict__ xz, const float* __restrict__ cw,
    const float* __restrict__ cb, const float* __restrict__ xpW,
    float* __restrict__ xc, float* __restrict__ Cpart,
    int kchunk)
{
    __shared__ float As[16][64];
    __shared__ float Ws[16][64];
    __shared__ float scw[128 * 4 + 128];   // conv w (128 ch x 4) + bias (128)

    const int bm = blockIdx.y * 64;
    const int kb = blockIdx.z * kchunk;
    Cpart += (size_t)blockIdx.z * (BATCHN * LSEQ) * 64;

    const int tid = threadIdx.x;
    if (tid < 128) {
        *(float4*)&scw[tid * 4] = *(const float4*)(cw + (size_t)(kb + tid) * 4);
        scw[512 + tid] = cb[kb + tid];
    }
    __syncthreads();

    const int tx = tid & 15;
    const int ty = tid >> 4;
    const int r   = tid >> 2;
    const int kk4 = (tid & 3) << 2;
    const int bl  = bm + r;          // global token row
    const int l   = bl % LSEQ;       // position within batch
    const float* xrow = xz + ((size_t)bl << 11);   // xs row (stride 2048)

    float acc[4][4];
    #pragma unroll
    for (int i = 0; i < 4; ++i)
        #pragma unroll
        for (int j = 0; j < 4; ++j) acc[i][j] = 0.f;

    for (int k0 = 0; k0 < kchunk; k0 += 16) {
        const int cl = k0 + kk4;       // channel offset within split
        const int c  = kb + cl;        // global channel
        // --- conv + silu for 4 channels at row bl ---
        float4 va = *(const float4*)&scw[512 + cl];
        #pragma unroll
        for (int kk = 0; kk < 4; ++kk) {
            int ls = l + kk - 3;
            if (ls >= 0) {
                float4 xv = *(const float4*)(xrow + ((ptrdiff_t)(kk - 3) << 11) + c);
                va.x += scw[(cl + 0) * 4 + kk] * xv.x;
                va.y += scw[(cl + 1) * 4 + kk] * xv.y;
                va.z += scw[(cl + 2) * 4 + kk] * xv.z;
                va.w += scw[(cl + 3) * 4 + kk] * xv.w;
            }
        }
        va.x = va.x * __builtin_amdgcn_rcpf(1.f + __expf(-va.x));
        va.y = va.y * __builtin_amdgcn_rcpf(1.f + __expf(-va.y));
        va.z = va.z * __builtin_amdgcn_rcpf(1.f + __expf(-va.z));
        va.w = va.w * __builtin_amdgcn_rcpf(1.f + __expf(-va.w));
        *(float4*)(xc + ((size_t)bl << 10) + c) = va;

        float4 vw = *(const float4*)(xpW + (size_t)r * DINNER + c);
        __syncthreads();
        As[kk4 + 0][r] = va.x; As[kk4 + 1][r] = va.y;
        As[kk4 + 2][r] = va.z; As[kk4 + 3][r] = va.w;
        Ws[kk4 + 0][r] = vw.x; Ws[kk4 + 1][r] = vw.y;
        Ws[kk4 + 2][r] = vw.z; Ws[kk4 + 3][r] = vw.w;
        __syncthreads();
        #pragma unroll
        for (int kk = 0; kk < 16; ++kk) {
            float4 a = *(const float4*)&As[kk][ty << 2];
            float4 b = *(const float4*)&Ws[kk][tx << 2];
            acc[0][0] += a.x * b.x; acc[0][1] += a.x * b.y;
            acc[0][2] += a.x * b.z; acc[0][3] += a.x * b.w;
            acc[1][0] += a.y * b.x; acc[1][1] += a.y * b.y;
            acc[1][2] += a.y * b.z; acc[1][3] += a.y * b.w;
            acc[2][0] += a.z * b.x; acc[2][1] += a.z * b.y;
            acc[2][2] += a.z * b.z; acc[2][3] += a.z * b.w;
            acc[3][0] += a.w * b.x; acc[3][1] += a.w * b.y;
            acc[3][2] += a.w * b.z; acc[3][3] += a.w * b.w;
        }
    }

    #pragma unroll
    for (int i = 0; i < 4; ++i) {
        const int m = bm + (ty << 2) + i;
        #pragma unroll
        for (int j = 0; j < 4; ++j) {
            const int n = (tx << 2) + j;
            Cpart[(size_t)m * 64 + n] = acc[i][j];
        }
    }
}

__global__ __launch_bounds__(256) void reduce_splitk(
    const float* __restrict__ part, float* __restrict__ out, int n, int nsplit)
{
    int i = blockIdx.x * 256 + threadIdx.x;
    if (i < n) {
        float s = 0.f;
        for (int j = 0; j < nsplit; ++j) s += part[(size_t)j * n + i];
        out[i] = s;
    }
}

// ---------------------------------------------------------------------------
// Patchify: x (B,3,224,224) -> tp (B, 196, 768), pd = c*256 + p1*16 + p2
// ---------------------------------------------------------------------------
__global__ __launch_bounds__(256) void patchify_kernel(
    const float* __restrict__ x, float* __restrict__ tp)
{
    int idx = blockIdx.x * 256 + threadIdx.x;   // B*L*PD = 4,816,896
    int pd = idx % PDIM;
    int bl = idx / PDIM;
    int l = bl % LSEQ, b = bl / LSEQ;
    int c = pd >> 8, rem = pd & 255, p1 = rem >> 4, p2 = rem & 15;
    int gh = l / 14, gw = l % 14;
    int hh = gh * 16 + p1, ww = gw * 16 + p2;
    tp[idx] = x[(((size_t)b * 3 + c) * 224 + hh) * 224 + ww];
}

// ---------------------------------------------------------------------------
// LayerNorm over last dim W (512 or 768). Optional second input (split-K
// partial sum), optional residual, optional fp32 out, optional bf16 hi/lo.
// ---------------------------------------------------------------------------
__global__ __launch_bounds__(256) void ln_kernel(
    const float* __restrict__ in, const float* __restrict__ in2,
    const float* __restrict__ res,
    const float* __restrict__ g, const float* __restrict__ bt,
    float* __restrict__ out, bf16_t* __restrict__ hi,
    bf16_t* __restrict__ lo, int W)
{
    __shared__ float red[4];
    const int row = blockIdx.x;
    const size_t base = (size_t)row * W;
    const int nper = W >> 8;      // 2 or 3
    float vals[3];
    float s = 0.f;
    for (int j = 0; j < nper; ++j) {
        int c = (j << 8) + threadIdx.x;
        float v = in[base + c];
        if (in2) v += in2[base + c];
        if (res) v += res[base + c];
        vals[j] = v;
        s += v;
    }
    int lane = threadIdx.x & 63, wid = threadIdx.x >> 6;
    #pragma unroll
    for (int o = 32; o > 0; o >>= 1) s += __shfl_down(s, o);
    if (lane == 0) red[wid] = s;
    __syncthreads();
    float mu = (red[0] + red[1] + red[2] + red[3]) / (float)W;
    __syncthreads();
    float vs = 0.f;
    for (int j = 0; j < nper; ++j) { float d = vals[j] - mu; vs += d * d; }
    #pragma unroll
    for (int o = 32; o > 0; o >>= 1) vs += __shfl_down(vs, o);
    if (lane == 0) red[wid] = vs;
    __syncthreads();
    float var = (red[0] + red[1] + red[2] + red[3]) / (float)W;
    float rstd = rsqrtf(var + 1e-5f);
    for (int j = 0; j < nper; ++j) {
        int c = (j << 8) + threadIdx.x;
        float v = (vals[j] - mu) * rstd * g[c] + bt[c];
        if (out) out[base + c] = v;
        if (hi) {
            bf16_t h = (bf16_t)v;
            hi[base + c] = h;
            lo[base + c] = (bf16_t)(v - (float)h);
        }
    }
}

// ---------------------------------------------------------------------------
// quad broadcast: all 4 lanes of a quad get lane J's value (DPP quad_perm).
// ---------------------------------------------------------------------------
template<int J>
__device__ __forceinline__ float qbcast(float v) {
    constexpr int ctrl = J | (J << 2) | (J << 4) | (J << 6);
    return __int_as_float(__builtin_amdgcn_mov_dpp(
        __float_as_int(v), ctrl, 0xF, 0xF, true));
}

// ---------------------------------------------------------------------------
// Selective scan v6: state-parallel, group-4 steps, wave-private LDS staging
// of shared B/C rows, depth-2 scalar pipeline, group-batched stores.
// ---------------------------------------------------------------------------
__global__ __launch_bounds__(256, 1) void scan_kernel(
    const float* __restrict__ xc, const float* __restrict__ dt,
    const float* __restrict__ xdbl, const float* __restrict__ A_log,
    const float* __restrict__ Dv, const float* __restrict__ xz,
    bf16_t* __restrict__ yh, bf16_t* __restrict__ yl)
{
    __shared__ float sBC[4][2][256];   // [wave][buf][4 steps x 64 floats]

    const int b    = blockIdx.y;
    const int tid  = threadIdx.x;
    const int lane = tid & 63;
    const int w    = tid >> 6;
    const int q    = tid >> 2;        // channel within block (0..63)
    const int sub  = tid & 3;         // state group: states [4*sub, 4*sub+4)
    const int d    = blockIdx.x * 64 + q;

    float A2[4], h[4];
    #pragma unroll
    for (int n = 0; n < 4; ++n) {
        A2[n] = -__expf(A_log[d * NSTATE + sub * 4 + n]) * 1.44269504f;
        h[n] = 0.f;
    }
    const float Dval = Dv[d];
    const size_t bL = (size_t)b * LSEQ;

    const float* pdt = dt + (bL + sub) * DINNER + d;
    const float* pxc = xc + (bL + sub) * DINNER + d;
    const float* pz  = xz + ((bL + sub) << 11) + DINNER + d;

    const float* xrow = xdbl + bL * 64;
    const int roff = (lane >> 4) * 64 + (lane & 15) * 4;
    float* lds0 = &sBC[w][0][0];
    float* lds1 = &sBC[w][1][0];

    float4 r0 = *(const float4*)(xrow + roff);
    float4 r1 = *(const float4*)(xrow + 256 + roff);
    float4 rowreg = *(const float4*)(xrow + 512 + roff);
    *(float4*)(lds0 + roff) = r0;
    *(float4*)(lds1 + roff) = r1;

    float dt_c = pdt[0];          float xc_c = pxc[0];          float z_c = pz[0];
    float dt_1 = pdt[4 * DINNER]; float xc_1 = pxc[4 * DINNER]; float z_1 = pz[4 * 2048];

    for (int g = 0; g < 49; ++g) {
        const int gl  = (g + 3 <= 48) ? g + 3 : 48;
        float4 rownext = *(const float4*)(xrow + gl * 256 + roff);
        const int adv = (g < 47) ? 2 : (48 - g);
        float dt_2 = pdt[(size_t)adv * 4 * DINNER];
        float xc_2 = pxc[(size_t)adv * 4 * DINNER];
        float z_2  = pz[(size_t)adv * 4 * 2048];

        const float* Bbuf = (g & 1) ? lds1 : lds0;
        float acc_keep = 0.f;

#define SCAN_STEP(J) do {                                                     \
        float4 Bv = *(const float4*)&Bbuf[(J) * 64 + 32 + 4 * sub];           \
        float4 Cv = *(const float4*)&Bbuf[(J) * 64 + 48 + 4 * sub];           \
        float dtv = qbcast<J>(dt_c);                                          \
        float xv  = qbcast<J>(xc_c);                                          \
        float dtx = dtv * xv;                                                 \
        h[0] = exp2f(dtv * A2[0]) * h[0] + dtx * Bv.x;                        \
        h[1] = exp2f(dtv * A2[1]) * h[1] + dtx * Bv.y;                        \
        h[2] = exp2f(dtv * A2[2]) * h[2] + dtx * Bv.z;                        \
        h[3] = exp2f(dtv * A2[3]) * h[3] + dtx * Bv.w;                        \
        float acc = h[0] * Cv.x + h[1] * Cv.y + h[2] * Cv.z + h[3] * Cv.w;    \
        acc += __shfl_xor(acc, 1);                                            \
        acc += __shfl_xor(acc, 2);                                            \
        acc_keep = (sub == (J)) ? acc : acc_keep;                             \
    } while (0)

        SCAN_STEP(0);
        SCAN_STEP(1);
        SCAN_STEP(2);
        SCAN_STEP(3);
#undef SCAN_STEP

        {
            float yv = acc_keep + xc_c * Dval;
            float sz = z_c * __builtin_amdgcn_rcpf(1.f + __expf(-z_c));
            float o  = yv * sz;
            bf16_t ho = (bf16_t)o;
            const size_t oi = (bL + 4 * (size_t)g + sub) * DINNER + d;
            yh[oi] = ho;
            yl[oi] = (bf16_t)(o - (float)ho);
        }

        *(float4*)(((g & 1) ? lds1 : lds0) + roff) = rowreg;
        rowreg = rownext;

        pdt += 4 * DINNER; pxc += 4 * DINNER; pz += 4 * 2048;
        dt_c = dt_1; xc_c = xc_1; z_c = z_1;
        dt_1 = dt_2; xc_1 = xc_2; z_1 = z_2;
    }
}

// ---------------------------------------------------------------------------
// Mean pool over L, then (tiny) classifier head.
// ---------------------------------------------------------------------------
__global__ __launch_bounds__(256) void pool_kernel(
    const float* __restrict__ t, float* __restrict__ pooled)
{
    int idx = blockIdx.x * 256 + threadIdx.x;   // 32*512 = 16384
    int dm = idx & (DMODEL - 1);
    int b = idx >> 9;
    float s = 0.f;
    for (int l = 0; l < LSEQ; ++l)
        s += t[((size_t)(b * LSEQ + l) << 9) + dm];
    pooled[idx] = s * (1.f / (float)LSEQ);
}

__global__ __launch_bounds__(320) void head_kernel(
    const float* __restrict__ pooled, const float* __restrict__ Wh,
    const float* __restrict__ bh, float* __restrict__ out)
{
    int tid = threadIdx.x;
    if (tid >= 320) return;
    int b = tid / 10, o = tid % 10;
    float s = bh[o];
    for (int k = 0; k < DMODEL; ++k)
        s += pooled[b * DMODEL + k] * Wh[o * DMODEL + k];
    out[b * 10 + o] = s;
}

// ---------------------------------------------------------------------------
extern "C" void kernel_launch(void* const* d_in, const int* in_sizes, int n_in,
                              void* d_out, int out_size, void* d_ws, size_t ws_size,
                              hipStream_t stream)
{
    const float* x         = (const float*)d_in[0];
    const float* ln0_g     = (const float*)d_in[1];
    const float* ln0_b     = (const float*)d_in[2];
    const float* W_emb     = (const float*)d_in[3];
    const float* b_emb     = (const float*)d_in[4];
    const float* ln1_g     = (const float*)d_in[5];
    const float* ln1_b     = (const float*)d_in[6];
    const float* in_proj_w = (const float*)d_in[7];
    const float* conv_w    = (const float*)d_in[8];
    const float* conv_b    = (const float*)d_in[9];
    const float* x_proj_w  = (const float*)d_in[10];
    const float* dt_proj_w = (const float*)d_in[11];
    const float* dt_proj_b = (const float*)d_in[12];
    const float* A_log     = (const float*)d_in[13];
    const float* D_p       = (const float*)d_in[14];
    const float* out_proj_w= (const float*)d_in[15];
    const float* blk_ln_g  = (const float*)d_in[16];
    const float* blk_ln_b  = (const float*)d_in[17];
    const float* W_head    = (const float*)d_in[18];
    const float* b_head    = (const float*)d_in[19];

    const int M = BATCHN * LSEQ;   // 6272 rows
    const int NSPLIT = 8;          // x_proj split-K factor (K=1024 -> 128)

    char* ws = (char*)d_ws;
    size_t off = 0;
    auto alloc = [&](size_t bytes) -> void* {
        void* p = (void*)(ws + off);
        off += (bytes + 255) & ~(size_t)255;
        return p;
    };
    // NOTE: workspace budget is tight (~256MB). Two aliases (stream-order
    // safe):  xdbl_p reuses tp (tp dead after the stem embedding GEMM);
    // yout reuses dtbuf (dt dead after scan; dtbuf rewritten only next layer
    // after the LN that consumes yout).
    float*  tp     = (float*)alloc((size_t)M * PDIM * 4);
    bf16_t* tp_h   = (bf16_t*)alloc((size_t)M * PDIM * 2);
    bf16_t* tp_l   = (bf16_t*)alloc((size_t)M * PDIM * 2);
    float*  t      = (float*)alloc((size_t)M * DMODEL * 4);
    bf16_t* t_h    = (bf16_t*)alloc((size_t)M * DMODEL * 2);
    bf16_t* t_l    = (bf16_t*)alloc((size_t)M * DMODEL * 2);
    float*  xz     = (float*)alloc((size_t)M * 2 * DINNER * 4);
    float*  xc     = (float*)alloc((size_t)M * DINNER * 4);
    float*  xdbl   = (float*)alloc((size_t)M * 64 * 4);
    float*  dtbuf  = (float*)alloc((size_t)M * DINNER * 4);
    bf16_t* y_h    = (bf16_t*)alloc((size_t)M * DINNER * 2);
    bf16_t* y_l    = (bf16_t*)alloc((size_t)M * DINNER * 2);
    float*  pooled = (float*)alloc((size_t)BATCHN * DMODEL * 4);
    float*  xdbl_p = tp;       // alias: NSPLIT*M*64*4 = 12.8MB <= 19.3MB
    float*  yout   = dtbuf;    // alias: 2*M*DMODEL*4 = 25.7MB == dtbuf size
    const int n_inW  = NLAYER * 2 * DINNER * DMODEL;   // 6,291,456
    const int n_outW = NLAYER * DMODEL * DINNER;       // 3,145,728
    const int n_embW = DMODEL * PDIM;                  // 393,216
    bf16_t* winh  = (bf16_t*)alloc((size_t)n_inW * 2);
    bf16_t* winl  = (bf16_t*)alloc((size_t)n_inW * 2);
    bf16_t* wouth = (bf16_t*)alloc((size_t)n_outW * 2);
    bf16_t* woutl = (bf16_t*)alloc((size_t)n_outW * 2);
    bf16_t* wembh = (bf16_t*)alloc((size_t)n_embW * 2);
    bf16_t* wembl = (bf16_t*)alloc((size_t)n_embW * 2);
    (void)ws_size; (void)in_sizes; (void)n_in; (void)out_size;

    // --- weight splits (hi/lo bf16) ---
    split_kernel<<<(n_inW  + 255) / 256, 256, 0, stream>>>(in_proj_w,  winh,  winl,  n_inW);
    split_kernel<<<(n_outW + 255) / 256, 256, 0, stream>>>(out_proj_w, wouth, woutl, n_outW);
    split_kernel<<<(n_embW + 255) / 256, 256, 0, stream>>>(W_emb,      wembh, wembl, n_embW);

    // --- stem ---
    patchify_kernel<<<(M * PDIM) / 256, 256, 0, stream>>>(x, tp);
    ln_kernel<<<M, 256, 0, stream>>>(tp, nullptr, nullptr, ln0_g, ln0_b,
                                     nullptr, tp_h, tp_l, PDIM);
    gemm_mfma3<<<dim3(DMODEL / 128, M / 128, 1), 256, 0, stream>>>(
        tp_h, tp_l, wembh, wembl, t, b_emb, M, DMODEL, PDIM);
    ln_kernel<<<M, 256, 0, stream>>>(t, nullptr, nullptr, ln1_g, ln1_b,
                                     t, t_h, t_l, DMODEL);

    // --- mamba layers ---
    for (int i = 0; i < NLAYER; ++i) {
        const bf16_t* winh_i  = winh  + (size_t)i * 2 * DINNER * DMODEL;
        const bf16_t* winl_i  = winl  + (size_t)i * 2 * DINNER * DMODEL;
        const bf16_t* wouth_i = wouth + (size_t)i * DMODEL * DINNER;
        const bf16_t* woutl_i = woutl + (size_t)i * DMODEL * DINNER;
        const float* cw   = conv_w    + (size_t)i * DINNER * 4;
        const float* cb   = conv_b    + (size_t)i * DINNER;
        const float* xpW  = x_proj_w  + (size_t)i * 64 * DINNER;
        const float* dtW  = dt_proj_w + (size_t)i * DINNER * RRANK;
        const float* dtB  = dt_proj_b + (size_t)i * DINNER;
        const float* Ali  = A_log     + (size_t)i * DINNER * NSTATE;
        const float* Di   = D_p       + (size_t)i * DINNER;
        const float* bg   = blk_ln_g  + (size_t)i * DMODEL;
        const float* bb   = blk_ln_b  + (size_t)i * DMODEL;

        // xz = t @ inW^T   (6272 x 2048, K=512)  [bf16x3 MFMA, pipelined]
        gemm_mfma3<<<dim3((2 * DINNER) / 128, M / 128, 1), 256, 0, stream>>>(
            t_h, t_l, winh_i, winl_i, xz, nullptr, M, 2 * DINNER, DMODEL);
        // xc = silu(conv(xs)) fused with x_proj split-K=8 partials
        conv_xproj_kernel<<<dim3(1, M / 64, NSPLIT), 256, 0, stream>>>(
            xz, cw, cb, xpW, xc, xdbl_p, DINNER / NSPLIT);
        reduce_splitk<<<(M * 64 + 255) / 256, 256, 0, stream>>>(
            xdbl_p, xdbl, M * 64, NSPLIT);
        // dt = softplus(x_dbl[:, :32] @ dtW^T + dtB)   (K=32)  [fp32 vector]
        gemm_nt<<<dim3(DINNER / 64, M / 64), 256, 0, stream>>>(
            xdbl, 64, dtW, dtbuf, DINNER, dtB, M, DINNER, RRANK, 1);
        // selective scan + D skip + silu(z); emits y as bf16 hi/lo
        scan_kernel<<<dim3(DINNER / 64, BATCHN), 256, 0, stream>>>(
            xc, dtbuf, xdbl, Ali, Di, xz, y_h, y_l);
        // yout = y @ outW^T   (6272 x 512, K=1024)  [MFMA, split-K=2]
        // (yout aliases dtbuf — dt is dead after scan_kernel)
        gemm_mfma3<<<dim3(DMODEL / 128, M / 128, 2), 256, 0, stream>>>(
            y_h, y_l, wouth_i, woutl_i, yout, nullptr, M, DMODEL, DINNER);
        // t = LN(yout0 + yout1 + t), plus hi/lo split for next in_proj
        ln_kernel<<<M, 256, 0, stream>>>(yout, yout + (size_t)M * DMODEL, t,
                                         bg, bb, t, t_h, t_l, DMODEL);
    }

    // --- pool + head ---
    pool_kernel<<<(BATCHN * DMODEL) / 256, 256, 0, stream>>>(t, pooled);
    head_kernel<<<1, 320, 0, stream>>>(pooled, W_head, b_head, (float*)d_out);
}

// Round 9
// 1530.153 us; speedup vs baseline: 2.9926x; 1.0093x over previous
//
#include <hip/hip_runtime.h>
#include <cstdint>
#include <cstddef>

// Problem constants
#define BATCHN 32
#define LSEQ   196     // (224/16)^2
#define DMODEL 512
#define DINNER 1024    // 2*DM
#define PDIM   768     // 3*16*16
#define NSTATE 16
#define RRANK  32
#define NLAYER 6

typedef __bf16 bf16_t;
typedef __bf16 bf16x8 __attribute__((ext_vector_type(8)));
typedef float  f32x4  __attribute__((ext_vector_type(4)));

// async global->LDS, 16B per lane: lane i lands at lds + i*16 bytes.
__device__ __forceinline__ void gl_lds16(const bf16_t* g, bf16_t* l) {
    __builtin_amdgcn_global_load_lds(
        (const __attribute__((address_space(1))) void*)g,
        (__attribute__((address_space(3))) void*)l, 16, 0, 0);
}

// ---------------------------------------------------------------------------
// Split fp32 -> (hi, lo) bf16 pair.  x ~= hi + lo to ~2^-16 relative.
// ---------------------------------------------------------------------------
__global__ __launch_bounds__(256) void split_kernel(
    const float* __restrict__ src, bf16_t* __restrict__ hi,
    bf16_t* __restrict__ lo, int n)
{
    int i = blockIdx.x * 256 + threadIdx.x;
    if (i < n) {
        float x = src[i];
        bf16_t h = (bf16_t)x;
        hi[i] = h;
        lo[i] = (bf16_t)(x - (float)h);
    }
}

// ---------------------------------------------------------------------------
// bf16x3 split-precision MFMA GEMM:  C = A[M,K] @ W[N,K]^T (+bias)
// Pipelined staging (sA single-buffered w/ reg-hoisted frags, sB double-
// buffered).  MFMA block is TERM-OUTERMOST: all 16 (mt,nt) tiles for term
// Ah*Wh, then Ah*Wl, then Al*Wh — accumulator reuse distance = 16 MFMAs,
// so the matrix pipe issues at full rate (the R8 version chained 3 MFMAs
// through the same acc back-to-back -> ~26% MfmaUtil, latency-capped).
// Split-K via gridDim.z: partials to C + z*M*N (summed by the next LN).
// Requires M%128==0, N%128==0, (K/gridDim.z)%32==0.
// ---------------------------------------------------------------------------
__global__ __launch_bounds__(256) void gemm_mfma3(
    const bf16_t* __restrict__ Ah, const bf16_t* __restrict__ Al,
    const bf16_t* __restrict__ Wh, const bf16_t* __restrict__ Wl,
    float* __restrict__ C, const float* __restrict__ bias,
    int M, int N, int K)
{
    __shared__ bf16_t sAh[128 * 32];
    __shared__ bf16_t sAl[128 * 32];
    __shared__ bf16_t sBh[2][128 * 32];
    __shared__ bf16_t sBl[2][128 * 32];

    const int bm = blockIdx.y * 128;
    const int bn = blockIdx.x * 128;
    const int kchunk = K / gridDim.z;
    const int kb = blockIdx.z * kchunk;
    C += (size_t)blockIdx.z * M * N;

    const int tid  = threadIdx.x;
    const int lane = tid & 63;
    const int w    = tid >> 6;
    const int wm   = (w & 1) * 64;
    const int wn   = (w >> 1) * 64;

    const int lrow = lane >> 2;
    const int cg8  = ((lane & 3) ^ ((lane >> 3) & 3)) * 8;   // element offset
    const size_t arow = (size_t)(bm + w * 32 + lrow) * K + cg8;
    const size_t brow = (size_t)(bn + w * 32 + lrow) * K + cg8;

    const int fsw = ((lane >> 4) ^ ((lane >> 1) & 3)) * 8;
    const int fr  = lane & 15;
    const int llo = w * 1024;          // this wave's LDS staging base

    f32x4 acc[4][4] = {};

    // prologue: stage tile 0
    #pragma unroll
    for (int j = 0; j < 2; ++j) {
        gl_lds16(Ah + arow + (size_t)j * 16 * K + kb, &sAh[llo + j * 512]);
        gl_lds16(Al + arow + (size_t)j * 16 * K + kb, &sAl[llo + j * 512]);
        gl_lds16(Wh + brow + (size_t)j * 16 * K + kb, &sBh[0][llo + j * 512]);
        gl_lds16(Wl + brow + (size_t)j * 16 * K + kb, &sBl[0][llo + j * 512]);
    }

    const int kiter = kchunk / 32;
    for (int ki = 0; ki < kiter; ++ki) {
        const int buf = ki & 1;
        __syncthreads();   // vmcnt(0) drain of stage(ki) — covered by MFMAs

        // A fragments -> registers (sA about to be overwritten)
        bf16x8 afh[4], afl[4];
        #pragma unroll
        for (int mt = 0; mt < 4; ++mt) {
            const int r = wm + mt * 16 + fr;
            afh[mt] = *(const bf16x8*)&sAh[r * 32 + fsw];
            afl[mt] = *(const bf16x8*)&sAl[r * 32 + fsw];
        }
        __syncthreads();   // all waves done with sA (cheap lgkm drain)

        if (ki + 1 < kiter) {
            const int k0 = kb + (ki + 1) * 32;
            #pragma unroll
            for (int j = 0; j < 2; ++j) {
                gl_lds16(Ah + arow + (size_t)j * 16 * K + k0, &sAh[llo + j * 512]);
                gl_lds16(Al + arow + (size_t)j * 16 * K + k0, &sAl[llo + j * 512]);
                gl_lds16(Wh + brow + (size_t)j * 16 * K + k0, &sBh[buf ^ 1][llo + j * 512]);
                gl_lds16(Wl + brow + (size_t)j * 16 * K + k0, &sBl[buf ^ 1][llo + j * 512]);
            }
        }

        // B fragments -> registers, then term-outermost MFMA sweep
        bf16x8 bfh[4], bfl[4];
        #pragma unroll
        for (int nt = 0; nt < 4; ++nt) {
            const int r = wn + nt * 16 + fr;
            bfh[nt] = *(const bf16x8*)&sBh[buf][r * 32 + fsw];
            bfl[nt] = *(const bf16x8*)&sBl[buf][r * 32 + fsw];
        }
        #pragma unroll
        for (int nt = 0; nt < 4; ++nt)
            #pragma unroll
            for (int mt = 0; mt < 4; ++mt)
                acc[mt][nt] = __builtin_amdgcn_mfma_f32_16x16x32_bf16(
                    afh[mt], bfh[nt], acc[mt][nt], 0, 0, 0);
        #pragma unroll
        for (int nt = 0; nt < 4; ++nt)
            #pragma unroll
            for (int mt = 0; mt < 4; ++mt)
                acc[mt][nt] = __builtin_amdgcn_mfma_f32_16x16x32_bf16(
                    afh[mt], bfl[nt], acc[mt][nt], 0, 0, 0);
        #pragma unroll
        for (int nt = 0; nt < 4; ++nt)
            #pragma unroll
            for (int mt = 0; mt < 4; ++mt)
                acc[mt][nt] = __builtin_amdgcn_mfma_f32_16x16x32_bf16(
                    afl[mt], bfh[nt], acc[mt][nt], 0, 0, 0);
    }

    // epilogue: C/D layout col=lane&15, row=(lane>>4)*4+reg  [m89-verified]
    const int cr = (lane >> 4) * 4;
    const int cc = lane & 15;
    #pragma unroll
    for (int nt = 0; nt < 4; ++nt) {
        const int n = bn + wn + nt * 16 + cc;
        const float bv = bias ? bias[n] : 0.f;
        #pragma unroll
        for (int mt = 0; mt < 4; ++mt) {
            const int m0 = bm + wm + mt * 16 + cr;
            #pragma unroll
            for (int r = 0; r < 4; ++r)
                C[(size_t)(m0 + r) * N + n] = acc[mt][nt][r] + bv;
        }
    }
}

// ---------------------------------------------------------------------------
// fp32 vector NT GEMM (used for dt_proj: K=32).  C = A@W^T (+bias)(+softplus)
// ---------------------------------------------------------------------------
__global__ __launch_bounds__(256) void gemm_nt(
    const float* __restrict__ A, int lda,
    const float* __restrict__ W,
    float* __restrict__ C, int ldc,
    const float* __restrict__ bias,
    int M, int N, int K, int act)
{
    __shared__ float As[16][64];
    __shared__ float Ws[16][64];
    const int bm = blockIdx.y * 64;
    const int bn = blockIdx.x * 64;
    const int tid = threadIdx.x;
    const int tx = tid & 15;
    const int ty = tid >> 4;
    const int r   = tid >> 2;
    const int kk4 = (tid & 3) << 2;

    float acc[4][4];
    #pragma unroll
    for (int i = 0; i < 4; ++i)
        #pragma unroll
        for (int j = 0; j < 4; ++j) acc[i][j] = 0.f;

    for (int k0 = 0; k0 < K; k0 += 16) {
        float4 va = *(const float4*)(A + (size_t)(bm + r) * lda + k0 + kk4);
        float4 vw = *(const float4*)(W + (size_t)(bn + r) * K   + k0 + kk4);
        __syncthreads();
        As[kk4 + 0][r] = va.x; As[kk4 + 1][r] = va.y;
        As[kk4 + 2][r] = va.z; As[kk4 + 3][r] = va.w;
        Ws[kk4 + 0][r] = vw.x; Ws[kk4 + 1][r] = vw.y;
        Ws[kk4 + 2][r] = vw.z; Ws[kk4 + 3][r] = vw.w;
        __syncthreads();
        #pragma unroll
        for (int kk = 0; kk < 16; ++kk) {
            float4 a = *(const float4*)&As[kk][ty << 2];
            float4 b = *(const float4*)&Ws[kk][tx << 2];
            acc[0][0] += a.x * b.x; acc[0][1] += a.x * b.y;
            acc[0][2] += a.x * b.z; acc[0][3] += a.x * b.w;
            acc[1][0] += a.y * b.x; acc[1][1] += a.y * b.y;
            acc[1][2] += a.y * b.z; acc[1][3] += a.y * b.w;
            acc[2][0] += a.z * b.x; acc[2][1] += a.z * b.y;
            acc[2][2] += a.z * b.z; acc[2][3] += a.z * b.w;
            acc[3][0] += a.w * b.x; acc[3][1] += a.w * b.y;
            acc[3][2] += a.w * b.z; acc[3][3] += a.w * b.w;
        }
    }

    #pragma unroll
    for (int i = 0; i < 4; ++i) {
        const int m = bm + (ty << 2) + i;
        #pragma unroll
        for (int j = 0; j < 4; ++j) {
            const int n = bn + (tx << 2) + j;
            float v = acc[i][j];
            if (bias) v += bias[n];
            if (act == 1) {
                v = (v > 20.f) ? v : log1pf(expf(v));
            }
            C[(size_t)m * ldc + n] = v;
        }
    }
}

// ---------------------------------------------------------------------------
// FUSED conv+silu+x_proj split-K.  Computes xc = silu(causal depthwise
// conv(xs)) inline while staging the A-tile, writes xc once (for the scan),
// and accumulates the x_proj partial GEMM (N=64).  grid=(1, M/64, NSPLIT).
// ---------------------------------------------------------------------------
__global__ __launch_bounds__(256) void conv_xproj_kernel(
    const float* __restrict__ xz, const float* __restrict__ cw,
    const float* __restrict__ cb, const float* __restrict__ xpW,
    float* __restrict__ xc, float* __restrict__ Cpart,
    int kchunk)
{
    __shared__ float As[16][64];
    __shared__ float Ws[16][64];
    __shared__ float scw[128 * 4 + 128];   // conv w (128 ch x 4) + bias (128)

    const int bm = blockIdx.y * 64;
    const int kb = blockIdx.z * kchunk;
    Cpart += (size_t)blockIdx.z * (BATCHN * LSEQ) * 64;

    const int tid = threadIdx.x;
    if (tid < 128) {
        *(float4*)&scw[tid * 4] = *(const float4*)(cw + (size_t)(kb + tid) * 4);
        scw[512 + tid] = cb[kb + tid];
    }
    __syncthreads();

    const int tx = tid & 15;
    const int ty = tid >> 4;
    const int r   = tid >> 2;
    const int kk4 = (tid & 3) << 2;
    const int bl  = bm + r;          // global token row
    const int l   = bl % LSEQ;       // position within batch
    const float* xrow = xz + ((size_t)bl << 11);   // xs row (stride 2048)

    float acc[4][4];
    #pragma unroll
    for (int i = 0; i < 4; ++i)
        #pragma unroll
        for (int j = 0; j < 4; ++j) acc[i][j] = 0.f;

    for (int k0 = 0; k0 < kchunk; k0 += 16) {
        const int cl = k0 + kk4;       // channel offset within split
        const int c  = kb + cl;        // global channel
        // --- conv + silu for 4 channels at row bl ---
        float4 va = *(const float4*)&scw[512 + cl];
        #pragma unroll
        for (int kk = 0; kk < 4; ++kk) {
            int ls = l + kk - 3;
            if (ls >= 0) {
                float4 xv = *(const float4*)(xrow + ((ptrdiff_t)(kk - 3) << 11) + c);
                va.x += scw[(cl + 0) * 4 + kk] * xv.x;
                va.y += scw[(cl + 1) * 4 + kk] * xv.y;
                va.z += scw[(cl + 2) * 4 + kk] * xv.z;
                va.w += scw[(cl + 3) * 4 + kk] * xv.w;
            }
        }
        va.x = va.x * __builtin_amdgcn_rcpf(1.f + __expf(-va.x));
        va.y = va.y * __builtin_amdgcn_rcpf(1.f + __expf(-va.y));
        va.z = va.z * __builtin_amdgcn_rcpf(1.f + __expf(-va.z));
        va.w = va.w * __builtin_amdgcn_rcpf(1.f + __expf(-va.w));
        *(float4*)(xc + ((size_t)bl << 10) + c) = va;

        float4 vw = *(const float4*)(xpW + (size_t)r * DINNER + c);
        __syncthreads();
        As[kk4 + 0][r] = va.x; As[kk4 + 1][r] = va.y;
        As[kk4 + 2][r] = va.z; As[kk4 + 3][r] = va.w;
        Ws[kk4 + 0][r] = vw.x; Ws[kk4 + 1][r] = vw.y;
        Ws[kk4 + 2][r] = vw.z; Ws[kk4 + 3][r] = vw.w;
        __syncthreads();
        #pragma unroll
        for (int kk = 0; kk < 16; ++kk) {
            float4 a = *(const float4*)&As[kk][ty << 2];
            float4 b = *(const float4*)&Ws[kk][tx << 2];
            acc[0][0] += a.x * b.x; acc[0][1] += a.x * b.y;
            acc[0][2] += a.x * b.z; acc[0][3] += a.x * b.w;
            acc[1][0] += a.y * b.x; acc[1][1] += a.y * b.y;
            acc[1][2] += a.y * b.z; acc[1][3] += a.y * b.w;
            acc[2][0] += a.z * b.x; acc[2][1] += a.z * b.y;
            acc[2][2] += a.z * b.z; acc[2][3] += a.z * b.w;
            acc[3][0] += a.w * b.x; acc[3][1] += a.w * b.y;
            acc[3][2] += a.w * b.z; acc[3][3] += a.w * b.w;
        }
    }

    #pragma unroll
    for (int i = 0; i < 4; ++i) {
        const int m = bm + (ty << 2) + i;
        #pragma unroll
        for (int j = 0; j < 4; ++j) {
            const int n = (tx << 2) + j;
            Cpart[(size_t)m * 64 + n] = acc[i][j];
        }
    }
}

__global__ __launch_bounds__(256) void reduce_splitk(
    const float* __restrict__ part, float* __restrict__ out, int n, int nsplit)
{
    int i = blockIdx.x * 256 + threadIdx.x;
    if (i < n) {
        float s = 0.f;
        for (int j = 0; j < nsplit; ++j) s += part[(size_t)j * n + i];
        out[i] = s;
    }
}

// ---------------------------------------------------------------------------
// Patchify: x (B,3,224,224) -> tp (B, 196, 768), pd = c*256 + p1*16 + p2
// ---------------------------------------------------------------------------
__global__ __launch_bounds__(256) void patchify_kernel(
    const float* __restrict__ x, float* __restrict__ tp)
{
    int idx = blockIdx.x * 256 + threadIdx.x;   // B*L*PD = 4,816,896
    int pd = idx % PDIM;
    int bl = idx / PDIM;
    int l = bl % LSEQ, b = bl / LSEQ;
    int c = pd >> 8, rem = pd & 255, p1 = rem >> 4, p2 = rem & 15;
    int gh = l / 14, gw = l % 14;
    int hh = gh * 16 + p1, ww = gw * 16 + p2;
    tp[idx] = x[(((size_t)b * 3 + c) * 224 + hh) * 224 + ww];
}

// ---------------------------------------------------------------------------
// LayerNorm over last dim W (512 or 768). Optional second input (split-K
// partial sum), optional residual, optional fp32 out, optional bf16 hi/lo.
// ---------------------------------------------------------------------------
__global__ __launch_bounds__(256) void ln_kernel(
    const float* __restrict__ in, const float* __restrict__ in2,
    const float* __restrict__ res,
    const float* __restrict__ g, const float* __restrict__ bt,
    float* __restrict__ out, bf16_t* __restrict__ hi,
    bf16_t* __restrict__ lo, int W)
{
    __shared__ float red[4];
    const int row = blockIdx.x;
    const size_t base = (size_t)row * W;
    const int nper = W >> 8;      // 2 or 3
    float vals[3];
    float s = 0.f;
    for (int j = 0; j < nper; ++j) {
        int c = (j << 8) + threadIdx.x;
        float v = in[base + c];
        if (in2) v += in2[base + c];
        if (res) v += res[base + c];
        vals[j] = v;
        s += v;
    }
    int lane = threadIdx.x & 63, wid = threadIdx.x >> 6;
    #pragma unroll
    for (int o = 32; o > 0; o >>= 1) s += __shfl_down(s, o);
    if (lane == 0) red[wid] = s;
    __syncthreads();
    float mu = (red[0] + red[1] + red[2] + red[3]) / (float)W;
    __syncthreads();
    float vs = 0.f;
    for (int j = 0; j < nper; ++j) { float d = vals[j] - mu; vs += d * d; }
    #pragma unroll
    for (int o = 32; o > 0; o >>= 1) vs += __shfl_down(vs, o);
    if (lane == 0) red[wid] = vs;
    __syncthreads();
    float var = (red[0] + red[1] + red[2] + red[3]) / (float)W;
    float rstd = rsqrtf(var + 1e-5f);
    for (int j = 0; j < nper; ++j) {
        int c = (j << 8) + threadIdx.x;
        float v = (vals[j] - mu) * rstd * g[c] + bt[c];
        if (out) out[base + c] = v;
        if (hi) {
            bf16_t h = (bf16_t)v;
            hi[base + c] = h;
            lo[base + c] = (bf16_t)(v - (float)h);
        }
    }
}

// ---------------------------------------------------------------------------
// quad broadcast: all 4 lanes of a quad get lane J's value (DPP quad_perm).
// ---------------------------------------------------------------------------
template<int J>
__device__ __forceinline__ float qbcast(float v) {
    constexpr int ctrl = J | (J << 2) | (J << 4) | (J << 6);
    return __int_as_float(__builtin_amdgcn_mov_dpp(
        __float_as_int(v), ctrl, 0xF, 0xF, true));
}

// ---------------------------------------------------------------------------
// Selective scan v6: state-parallel, group-4 steps, wave-private LDS staging
// of shared B/C rows, depth-2 scalar pipeline, group-batched stores.
// ---------------------------------------------------------------------------
__global__ __launch_bounds__(256, 1) void scan_kernel(
    const float* __restrict__ xc, const float* __restrict__ dt,
    const float* __restrict__ xdbl, const float* __restrict__ A_log,
    const float* __restrict__ Dv, const float* __restrict__ xz,
    bf16_t* __restrict__ yh, bf16_t* __restrict__ yl)
{
    __shared__ float sBC[4][2][256];   // [wave][buf][4 steps x 64 floats]

    const int b    = blockIdx.y;
    const int tid  = threadIdx.x;
    const int lane = tid & 63;
    const int w    = tid >> 6;
    const int q    = tid >> 2;        // channel within block (0..63)
    const int sub  = tid & 3;         // state group: states [4*sub, 4*sub+4)
    const int d    = blockIdx.x * 64 + q;

    float A2[4], h[4];
    #pragma unroll
    for (int n = 0; n < 4; ++n) {
        A2[n] = -__expf(A_log[d * NSTATE + sub * 4 + n]) * 1.44269504f;
        h[n] = 0.f;
    }
    const float Dval = Dv[d];
    const size_t bL = (size_t)b * LSEQ;

    const float* pdt = dt + (bL + sub) * DINNER + d;
    const float* pxc = xc + (bL + sub) * DINNER + d;
    const float* pz  = xz + ((bL + sub) << 11) + DINNER + d;

    const float* xrow = xdbl + bL * 64;
    const int roff = (lane >> 4) * 64 + (lane & 15) * 4;
    float* lds0 = &sBC[w][0][0];
    float* lds1 = &sBC[w][1][0];

    float4 r0 = *(const float4*)(xrow + roff);
    float4 r1 = *(const float4*)(xrow + 256 + roff);
    float4 rowreg = *(const float4*)(xrow + 512 + roff);
    *(float4*)(lds0 + roff) = r0;
    *(float4*)(lds1 + roff) = r1;

    float dt_c = pdt[0];          float xc_c = pxc[0];          float z_c = pz[0];
    float dt_1 = pdt[4 * DINNER]; float xc_1 = pxc[4 * DINNER]; float z_1 = pz[4 * 2048];

    for (int g = 0; g < 49; ++g) {
        const int gl  = (g + 3 <= 48) ? g + 3 : 48;
        float4 rownext = *(const float4*)(xrow + gl * 256 + roff);
        const int adv = (g < 47) ? 2 : (48 - g);
        float dt_2 = pdt[(size_t)adv * 4 * DINNER];
        float xc_2 = pxc[(size_t)adv * 4 * DINNER];
        float z_2  = pz[(size_t)adv * 4 * 2048];

        const float* Bbuf = (g & 1) ? lds1 : lds0;
        float acc_keep = 0.f;

#define SCAN_STEP(J) do {                                                     \
        float4 Bv = *(const float4*)&Bbuf[(J) * 64 + 32 + 4 * sub];           \
        float4 Cv = *(const float4*)&Bbuf[(J) * 64 + 48 + 4 * sub];           \
        float dtv = qbcast<J>(dt_c);                                          \
        float xv  = qbcast<J>(xc_c);                                          \
        float dtx = dtv * xv;                                                 \
        h[0] = exp2f(dtv * A2[0]) * h[0] + dtx * Bv.x;                        \
        h[1] = exp2f(dtv * A2[1]) * h[1] + dtx * Bv.y;                        \
        h[2] = exp2f(dtv * A2[2]) * h[2] + dtx * Bv.z;                        \
        h[3] = exp2f(dtv * A2[3]) * h[3] + dtx * Bv.w;                        \
        float acc = h[0] * Cv.x + h[1] * Cv.y + h[2] * Cv.z + h[3] * Cv.w;    \
        acc += __shfl_xor(acc, 1);                                            \
        acc += __shfl_xor(acc, 2);                                            \
        acc_keep = (sub == (J)) ? acc : acc_keep;                             \
    } while (0)

        SCAN_STEP(0);
        SCAN_STEP(1);
        SCAN_STEP(2);
        SCAN_STEP(3);
#undef SCAN_STEP

        {
            float yv = acc_keep + xc_c * Dval;
            float sz = z_c * __builtin_amdgcn_rcpf(1.f + __expf(-z_c));
            float o  = yv * sz;
            bf16_t ho = (bf16_t)o;
            const size_t oi = (bL + 4 * (size_t)g + sub) * DINNER + d;
            yh[oi] = ho;
            yl[oi] = (bf16_t)(o - (float)ho);
        }

        *(float4*)(((g & 1) ? lds1 : lds0) + roff) = rowreg;
        rowreg = rownext;

        pdt += 4 * DINNER; pxc += 4 * DINNER; pz += 4 * 2048;
        dt_c = dt_1; xc_c = xc_1; z_c = z_1;
        dt_1 = dt_2; xc_1 = xc_2; z_1 = z_2;
    }
}

// ---------------------------------------------------------------------------
// Mean pool over L, then (tiny) classifier head.
// ---------------------------------------------------------------------------
__global__ __launch_bounds__(256) void pool_kernel(
    const float* __restrict__ t, float* __restrict__ pooled)
{
    int idx = blockIdx.x * 256 + threadIdx.x;   // 32*512 = 16384
    int dm = idx & (DMODEL - 1);
    int b = idx >> 9;
    float s = 0.f;
    for (int l = 0; l < LSEQ; ++l)
        s += t[((size_t)(b * LSEQ + l) << 9) + dm];
    pooled[idx] = s * (1.f / (float)LSEQ);
}

__global__ __launch_bounds__(320) void head_kernel(
    const float* __restrict__ pooled, const float* __restrict__ Wh,
    const float* __restrict__ bh, float* __restrict__ out)
{
    int tid = threadIdx.x;
    if (tid >= 320) return;
    int b = tid / 10, o = tid % 10;
    float s = bh[o];
    for (int k = 0; k < DMODEL; ++k)
        s += pooled[b * DMODEL + k] * Wh[o * DMODEL + k];
    out[b * 10 + o] = s;
}

// ---------------------------------------------------------------------------
extern "C" void kernel_launch(void* const* d_in, const int* in_sizes, int n_in,
                              void* d_out, int out_size, void* d_ws, size_t ws_size,
                              hipStream_t stream)
{
    const float* x         = (const float*)d_in[0];
    const float* ln0_g     = (const float*)d_in[1];
    const float* ln0_b     = (const float*)d_in[2];
    const float* W_emb     = (const float*)d_in[3];
    const float* b_emb     = (const float*)d_in[4];
    const float* ln1_g     = (const float*)d_in[5];
    const float* ln1_b     = (const float*)d_in[6];
    const float* in_proj_w = (const float*)d_in[7];
    const float* conv_w    = (const float*)d_in[8];
    const float* conv_b    = (const float*)d_in[9];
    const float* x_proj_w  = (const float*)d_in[10];
    const float* dt_proj_w = (const float*)d_in[11];
    const float* dt_proj_b = (const float*)d_in[12];
    const float* A_log     = (const float*)d_in[13];
    const float* D_p       = (const float*)d_in[14];
    const float* out_proj_w= (const float*)d_in[15];
    const float* blk_ln_g  = (const float*)d_in[16];
    const float* blk_ln_b  = (const float*)d_in[17];
    const float* W_head    = (const float*)d_in[18];
    const float* b_head    = (const float*)d_in[19];

    const int M = BATCHN * LSEQ;   // 6272 rows
    const int NSPLIT = 8;          // x_proj split-K factor (K=1024 -> 128)

    char* ws = (char*)d_ws;
    size_t off = 0;
    auto alloc = [&](size_t bytes) -> void* {
        void* p = (void*)(ws + off);
        off += (bytes + 255) & ~(size_t)255;
        return p;
    };
    // NOTE: workspace budget is tight (~256MB). Two aliases (stream-order
    // safe):  xdbl_p reuses tp (tp dead after the stem embedding GEMM);
    // yout reuses dtbuf (dt dead after scan; dtbuf rewritten only next layer
    // after the LN that consumes yout).
    float*  tp     = (float*)alloc((size_t)M * PDIM * 4);
    bf16_t* tp_h   = (bf16_t*)alloc((size_t)M * PDIM * 2);
    bf16_t* tp_l   = (bf16_t*)alloc((size_t)M * PDIM * 2);
    float*  t      = (float*)alloc((size_t)M * DMODEL * 4);
    bf16_t* t_h    = (bf16_t*)alloc((size_t)M * DMODEL * 2);
    bf16_t* t_l    = (bf16_t*)alloc((size_t)M * DMODEL * 2);
    float*  xz     = (float*)alloc((size_t)M * 2 * DINNER * 4);
    float*  xc     = (float*)alloc((size_t)M * DINNER * 4);
    float*  xdbl   = (float*)alloc((size_t)M * 64 * 4);
    float*  dtbuf  = (float*)alloc((size_t)M * DINNER * 4);
    bf16_t* y_h    = (bf16_t*)alloc((size_t)M * DINNER * 2);
    bf16_t* y_l    = (bf16_t*)alloc((size_t)M * DINNER * 2);
    float*  pooled = (float*)alloc((size_t)BATCHN * DMODEL * 4);
    float*  xdbl_p = tp;       // alias: NSPLIT*M*64*4 = 12.8MB <= 19.3MB
    float*  yout   = dtbuf;    // alias: 2*M*DMODEL*4 = 25.7MB == dtbuf size
    const int n_inW  = NLAYER * 2 * DINNER * DMODEL;   // 6,291,456
    const int n_outW = NLAYER * DMODEL * DINNER;       // 3,145,728
    const int n_embW = DMODEL * PDIM;                  // 393,216
    bf16_t* winh  = (bf16_t*)alloc((size_t)n_inW * 2);
    bf16_t* winl  = (bf16_t*)alloc((size_t)n_inW * 2);
    bf16_t* wouth = (bf16_t*)alloc((size_t)n_outW * 2);
    bf16_t* woutl = (bf16_t*)alloc((size_t)n_outW * 2);
    bf16_t* wembh = (bf16_t*)alloc((size_t)n_embW * 2);
    bf16_t* wembl = (bf16_t*)alloc((size_t)n_embW * 2);
    (void)ws_size; (void)in_sizes; (void)n_in; (void)out_size;

    // --- weight splits (hi/lo bf16) ---
    split_kernel<<<(n_inW  + 255) / 256, 256, 0, stream>>>(in_proj_w,  winh,  winl,  n_inW);
    split_kernel<<<(n_outW + 255) / 256, 256, 0, stream>>>(out_proj_w, wouth, woutl, n_outW);
    split_kernel<<<(n_embW + 255) / 256, 256, 0, stream>>>(W_emb,      wembh, wembl, n_embW);

    // --- stem ---
    patchify_kernel<<<(M * PDIM) / 256, 256, 0, stream>>>(x, tp);
    ln_kernel<<<M, 256, 0, stream>>>(tp, nullptr, nullptr, ln0_g, ln0_b,
                                     nullptr, tp_h, tp_l, PDIM);
    gemm_mfma3<<<dim3(DMODEL / 128, M / 128, 1), 256, 0, stream>>>(
        tp_h, tp_l, wembh, wembl, t, b_emb, M, DMODEL, PDIM);
    ln_kernel<<<M, 256, 0, stream>>>(t, nullptr, nullptr, ln1_g, ln1_b,
                                     t, t_h, t_l, DMODEL);

    // --- mamba layers ---
    for (int i = 0; i < NLAYER; ++i) {
        const bf16_t* winh_i  = winh  + (size_t)i * 2 * DINNER * DMODEL;
        const bf16_t* winl_i  = winl  + (size_t)i * 2 * DINNER * DMODEL;
        const bf16_t* wouth_i = wouth + (size_t)i * DMODEL * DINNER;
        const bf16_t* woutl_i = woutl + (size_t)i * DMODEL * DINNER;
        const float* cw   = conv_w    + (size_t)i * DINNER * 4;
        const float* cb   = conv_b    + (size_t)i * DINNER;
        const float* xpW  = x_proj_w  + (size_t)i * 64 * DINNER;
        const float* dtW  = dt_proj_w + (size_t)i * DINNER * RRANK;
        const float* dtB  = dt_proj_b + (size_t)i * DINNER;
        const float* Ali  = A_log     + (size_t)i * DINNER * NSTATE;
        const float* Di   = D_p       + (size_t)i * DINNER;
        const float* bg   = blk_ln_g  + (size_t)i * DMODEL;
        const float* bb   = blk_ln_b  + (size_t)i * DMODEL;

        // xz = t @ inW^T   (6272 x 2048, K=512)  [bf16x3 MFMA, pipelined]
        gemm_mfma3<<<dim3((2 * DINNER) / 128, M / 128, 1), 256, 0, stream>>>(
            t_h, t_l, winh_i, winl_i, xz, nullptr, M, 2 * DINNER, DMODEL);
        // xc = silu(conv(xs)) fused with x_proj split-K=8 partials
        conv_xproj_kernel<<<dim3(1, M / 64, NSPLIT), 256, 0, stream>>>(
            xz, cw, cb, xpW, xc, xdbl_p, DINNER / NSPLIT);
        reduce_splitk<<<(M * 64 + 255) / 256, 256, 0, stream>>>(
            xdbl_p, xdbl, M * 64, NSPLIT);
        // dt = softplus(x_dbl[:, :32] @ dtW^T + dtB)   (K=32)  [fp32 vector]
        gemm_nt<<<dim3(DINNER / 64, M / 64), 256, 0, stream>>>(
            xdbl, 64, dtW, dtbuf, DINNER, dtB, M, DINNER, RRANK, 1);
        // selective scan + D skip + silu(z); emits y as bf16 hi/lo
        scan_kernel<<<dim3(DINNER / 64, BATCHN), 256, 0, stream>>>(
            xc, dtbuf, xdbl, Ali, Di, xz, y_h, y_l);
        // yout = y @ outW^T   (6272 x 512, K=1024)  [MFMA, split-K=2]
        // (yout aliases dtbuf — dt is dead after scan_kernel)
        gemm_mfma3<<<dim3(DMODEL / 128, M / 128, 2), 256, 0, stream>>>(
            y_h, y_l, wouth_i, woutl_i, yout, nullptr, M, DMODEL, DINNER);
        // t = LN(yout0 + yout1 + t), plus hi/lo split for next in_proj
        ln_kernel<<<M, 256, 0, stream>>>(yout, yout + (size_t)M * DMODEL, t,
                                         bg, bb, t, t_h, t_l, DMODEL);
    }

    // --- pool + head ---
    pool_kernel<<<(BATCHN * DMODEL) / 256, 256, 0, stream>>>(t, pooled);
    head_kernel<<<1, 320, 0, stream>>>(pooled, W_head, b_head, (float*)d_out);
}